// Round 7
// baseline (811.963 us; speedup 1.0000x reference)
//
#include <hip/hip_runtime.h>
#include <hip/hip_bf16.h>
#include <math.h>

// Problem constants
#define BB 2
#define SS 2048
#define DD 2048
#define HH 16
#define CONVC 6144
#define MM (BB*SS)   // 4096 tokens

// chunked delta-rule constants
#define CH 64        // chunk length
#define NCH 32       // chunks per sequence
#define CD_KTS 0
#define CD_TV  16384
#define CD_TP  32768
#define CD_AQ  40960
#define CD_PV  49152
#define CD_PC  49408
#define CD_STRIDE 49664

typedef __bf16 bf16_t;
typedef __bf16 bf16x8 __attribute__((ext_vector_type(8)));
typedef __bf16 bf16x4 __attribute__((ext_vector_type(4)));
typedef float  f32x4  __attribute__((ext_vector_type(4)));

#define GLOBAL_AS __attribute__((address_space(1)))
#define LDS_AS    __attribute__((address_space(3)))

#define MFMA16(a,b,c) __builtin_amdgcn_mfma_f32_16x16x32_bf16((a),(b),(c),0,0,0)

// ---------------------------------------------------------------------------
// Cast kernels
// ---------------------------------------------------------------------------
__global__ __launch_bounds__(256) void cast_x_kernel(
    const float* __restrict__ in, const float* __restrict__ mask,
    bf16_t* __restrict__ out, long n)
{
  long n4 = n >> 2;
  for (long i = (long)blockIdx.x*256 + threadIdx.x; i < n4; i += (long)gridDim.x*256) {
    float4 v = ((const float4*)in)[i];
    float m = mask[(i*4) / DD];
    bf16x4 o4;
    o4[0]=(bf16_t)(v.x*m); o4[1]=(bf16_t)(v.y*m);
    o4[2]=(bf16_t)(v.z*m); o4[3]=(bf16_t)(v.w*m);
    ((bf16x4*)out)[i] = o4;
  }
}

__global__ __launch_bounds__(256) void cast_w_kernel(
    const float* __restrict__ in, bf16_t* __restrict__ out, long n)
{
  long n4 = n >> 2;
  for (long i = (long)blockIdx.x*256 + threadIdx.x; i < n4; i += (long)gridDim.x*256) {
    float4 v = ((const float4*)in)[i];
    bf16x4 o4;
    o4[0]=(bf16_t)v.x; o4[1]=(bf16_t)v.y; o4[2]=(bf16_t)v.z; o4[3]=(bf16_t)v.w;
    ((bf16x4*)out)[i] = o4;
  }
}

// ---------------------------------------------------------------------------
// bf16 MFMA GEMM: C[M,N] = A[M,K] * B[N,K]^T   (m97-style 128x128 tile, BK=32)
// ---------------------------------------------------------------------------
template<bool OUT_BF16>
__global__ __launch_bounds__(256) void gemm_bt(
    const bf16_t* __restrict__ A, const bf16_t* __restrict__ Bm,
    void* __restrict__ Cp, int M, int N, int K)
{
  __shared__ __align__(16) bf16_t lA[128*32];
  __shared__ __align__(16) bf16_t lB[128*32];
  const int t    = threadIdx.x;
  const int lane = t & 63;
  const int w    = t >> 6;       // wave 0..3
  const int wm   = w >> 1, wn = w & 1;
  const int fr   = lane & 15, fq = lane >> 4;
  const long bm  = blockIdx.x, bn = blockIdx.y;

  f32x4 acc[4][4];
  #pragma unroll
  for (int i=0;i<4;i++)
    #pragma unroll
    for (int jj=0;jj<4;jj++) acc[i][jj] = (f32x4){0.f,0.f,0.f,0.f};

  const int r1 = t >> 2;
  const int kb = (t & 3) << 3;
  const bf16_t* a0 = A  + (bm*128 + r1)*(long)K + kb;
  const bf16_t* a1 = a0 + 64*(long)K;
  const bf16_t* b0 = Bm + (bn*128 + r1)*(long)K + kb;
  const bf16_t* b1 = b0 + 64*(long)K;
  bf16_t* lA0 = lA + (w*64)*8;        // wave-uniform LDS bases
  bf16_t* lA1 = lA + (256 + w*64)*8;
  bf16_t* lB0 = lB + (w*64)*8;
  bf16_t* lB1 = lB + (256 + w*64)*8;

  for (int k0 = 0; k0 < K; k0 += 32) {
    __builtin_amdgcn_global_load_lds((const GLOBAL_AS void*)(a0 + k0), (LDS_AS void*)lA0, 16, 0, 0);
    __builtin_amdgcn_global_load_lds((const GLOBAL_AS void*)(a1 + k0), (LDS_AS void*)lA1, 16, 0, 0);
    __builtin_amdgcn_global_load_lds((const GLOBAL_AS void*)(b0 + k0), (LDS_AS void*)lB0, 16, 0, 0);
    __builtin_amdgcn_global_load_lds((const GLOBAL_AS void*)(b1 + k0), (LDS_AS void*)lB1, 16, 0, 0);
    __syncthreads();   // drains vmcnt before reads

    bf16x8 af[4], bfr[4];
    #pragma unroll
    for (int mi=0;mi<4;mi++)
      af[mi] = *(const bf16x8*)(lA + (wm*64 + mi*16 + fr)*32 + fq*8);
    #pragma unroll
    for (int ni=0;ni<4;ni++)
      bfr[ni] = *(const bf16x8*)(lB + (wn*64 + ni*16 + fr)*32 + fq*8);
    #pragma unroll
    for (int mi=0;mi<4;mi++)
      #pragma unroll
      for (int ni=0;ni<4;ni++)
        acc[mi][ni] = MFMA16(af[mi], bfr[ni], acc[mi][ni]);
    __syncthreads();   // protect LDS before next stage
  }

  #pragma unroll
  for (int mi=0;mi<4;mi++) {
    #pragma unroll
    for (int ni=0;ni<4;ni++) {
      long row = bm*128 + wm*64 + mi*16 + fq*4;
      long col = bn*128 + wn*64 + ni*16 + fr;
      #pragma unroll
      for (int r=0;r<4;r++) {
        float v = acc[mi][ni][r];
        if (OUT_BF16) ((bf16_t*)Cp)[(row+r)*(long)N + col] = (bf16_t)v;
        else          ((float*)Cp)[(row+r)*(long)N + col] = v;
      }
    }
  }
}

// ---------------------------------------------------------------------------
// beta / g:  per token, 16 dots with W_b rows and 16 with W_a rows (K=2048)
// writes gb_t[bh][s] = {g (log decay), beta}
// ---------------------------------------------------------------------------
__global__ __launch_bounds__(64) void betag_kernel(
    const bf16_t* __restrict__ xbf, const float* __restrict__ W_b,
    const float* __restrict__ W_a, const float* __restrict__ dt_bias,
    const float* __restrict__ A_log, float2* __restrict__ gb_t)
{
  const int row  = blockIdx.x;        // token b*S+s
  const int lane = threadIdx.x;
  const int b = row / SS, s = row % SS;

  float xv[32];
  {
    const bf16x8* xr = (const bf16x8*)(xbf + (long)row*DD + lane*32);
    #pragma unroll
    for (int c8=0;c8<4;c8++) {
      bf16x8 v = xr[c8];
      #pragma unroll
      for (int e=0;e<8;e++) xv[c8*8+e] = (float)v[e];
    }
  }

  for (int h=0; h<HH; ++h) {
    const float4* wb4 = (const float4*)(W_b + (long)h*DD + lane*32);
    const float4* wa4 = (const float4*)(W_a + (long)h*DD + lane*32);
    float pb = 0.f, pa = 0.f;
    #pragma unroll
    for (int c4=0;c4<8;c4++) {
      float4 wb = wb4[c4], wa = wa4[c4];
      pb += xv[c4*4+0]*wb.x + xv[c4*4+1]*wb.y + xv[c4*4+2]*wb.z + xv[c4*4+3]*wb.w;
      pa += xv[c4*4+0]*wa.x + xv[c4*4+1]*wa.y + xv[c4*4+2]*wa.z + xv[c4*4+3]*wa.w;
    }
    #pragma unroll
    for (int off=32; off>=1; off>>=1) { pb += __shfl_xor(pb, off); pa += __shfl_xor(pa, off); }
    if (lane == h) {
      float beta = 1.f/(1.f+expf(-pb));
      float tt = pa + dt_bias[h];
      float sp = (tt > 20.f) ? tt : log1pf(expf(tt));
      float g  = -expf(A_log[h]) * sp;
      gb_t[((long)b*HH + h)*SS + s] = make_float2(g, beta);
    }
  }
}

// ---------------------------------------------------------------------------
// conv(K=4 causal depthwise) + bias + silu + q/k l2norm + transpose to [B,H,S,128]
// ---------------------------------------------------------------------------
__global__ __launch_bounds__(128) void conv_norm_kernel(
    const bf16_t* __restrict__ mixed, const float* __restrict__ cw,
    const float* __restrict__ cb, bf16_t* __restrict__ q_t,
    bf16_t* __restrict__ k_t, bf16_t* __restrict__ v_t)
{
  const int blk = blockIdx.x;           // (b*H+h)*S + s
  const int s = blk & (SS-1);
  const int h = (blk >> 11) & (HH-1);
  const int b = blk >> 15;
  const int d = threadIdx.x;

  const int cq = h*128 + d;
  const int ck = 2048 + cq;
  const int cv = 4096 + cq;
  float aq = cb[cq], ak = cb[ck], av = cb[cv];
  const float* wq = cw + (long)cq*4;
  const float* wk = cw + (long)ck*4;
  const float* wv = cw + (long)cv*4;
  #pragma unroll
  for (int tp=0; tp<4; ++tp) {
    int s2 = s - 3 + tp;
    if (s2 >= 0) {
      const bf16_t* rowp = mixed + ((long)b*SS + s2)*CONVC;
      aq += (float)rowp[cq] * wq[tp];
      ak += (float)rowp[ck] * wk[tp];
      av += (float)rowp[cv] * wv[tp];
    }
  }
  aq = aq * (1.f/(1.f+expf(-aq)));
  ak = ak * (1.f/(1.f+expf(-ak)));
  av = av * (1.f/(1.f+expf(-av)));

  float sq = aq*aq, sk = ak*ak;
  #pragma unroll
  for (int off=32; off>=1; off>>=1) { sq += __shfl_xor(sq, off); sk += __shfl_xor(sk, off); }
  __shared__ float red[4];
  const int wv2 = d >> 6;
  if ((d & 63) == 0) { red[wv2*2] = sq; red[wv2*2+1] = sk; }
  __syncthreads();
  float sumq = red[0] + red[2];
  float sumk = red[1] + red[3];

  const long obase = ((long)(b*HH + h)*SS + s)*128 + d;
  q_t[obase] = (bf16_t)(aq * rsqrtf(sumq + 1e-6f) * 0.08838834764831845f);  // * DK^-0.5
  k_t[obase] = (bf16_t)(ak * rsqrtf(sumk + 1e-6f));
  v_t[obase] = (bf16_t)av;
}

// ---------------------------------------------------------------------------
// Phase A (per bh,chunk): build Tp/Aq/TV/KTs/pv/PC into cdata.
// LDS 69.9KB (lQ/lVT time-share) -> 2 blocks/CU. Staggered V^T writes.
// ---------------------------------------------------------------------------
__global__ __launch_bounds__(256) void chunkA_kernel(
    const bf16_t* __restrict__ q_t, const bf16_t* __restrict__ k_t,
    const bf16_t* __restrict__ v_t, const float2* __restrict__ gb_t,
    char* __restrict__ cdata)
{
  extern __shared__ char smem[];
  bf16_t* lK  = (bf16_t*)(smem);            // [64][136]
  bf16_t* lQV = (bf16_t*)(smem + 17408);    // lQ [64][136], later lVT [128][72]
  float*  lLf = (float*)(smem + 35840);     // [64][65]
  float*  lXf = (float*)(smem + 52480);     // [64][65]
  float*  gcv = (float*)(smem + 69120);     // [64]
  float*  pvv = (float*)(smem + 69376);     // [64]
  float*  bvv = (float*)(smem + 69632);     // [64]

  const int cd = blockIdx.x;
  const int bh = cd >> 5, c = cd & 31;
  const int t = threadIdx.x;
  const int lane = t & 63, w = t >> 6;
  const int fr = lane & 15, fq = lane >> 4;

  const bf16_t* kg = k_t + ((long)bh*SS + c*CH)*128;
  const bf16_t* qg = q_t + ((long)bh*SS + c*CH)*128;
  const bf16_t* vg = v_t + ((long)bh*SS + c*CH)*128;
  char* cdp = cdata + (long)cd*CD_STRIDE;

  // stage K, Q (lQV as lQ)
  #pragma unroll
  for (int ib=0; ib<4; ib++) {
    int e0 = (t + 256*ib)*8;
    int r = e0 >> 7, cc = e0 & 127;
    *(bf16x8*)&lK[r*136+cc]  = *(const bf16x8*)(kg + e0);
    *(bf16x8*)&lQV[r*136+cc] = *(const bf16x8*)(qg + e0);
  }
  if (t < 64) {
    float2 gb = gb_t[(long)bh*SS + c*CH + t];
    gcv[t] = gb.x;
    bvv[t] = gb.y;
  }
  __syncthreads();
  // wave-parallel inclusive scan of gcv (wave 0)
  if (t < 64) {
    float g = gcv[t];
    #pragma unroll
    for (int off=1; off<64; off<<=1) {
      float n = __shfl_up(g, off);
      if (lane >= off) g += n;
    }
    gcv[t] = g;
  }
  __syncthreads();
  if (t < 64) pvv[t] = expf(gcv[t]);

  // G = K K^T, Gq = Q K^T  (wave strip rows 16w)
  {
    f32x4 accG[4], accQ[4];
    #pragma unroll
    for (int tn=0;tn<4;tn++){ accG[tn]=(f32x4){0,0,0,0}; accQ[tn]=(f32x4){0,0,0,0}; }
    #pragma unroll
    for (int ks=0;ks<4;ks++) {
      bf16x8 aK = *(const bf16x8*)&lK[(w*16+fr)*136 + fq*8 + ks*32];
      bf16x8 aQ = *(const bf16x8*)&lQV[(w*16+fr)*136 + fq*8 + ks*32];
      #pragma unroll
      for (int tn=0;tn<4;tn++) {
        bf16x8 bK = *(const bf16x8*)&lK[(tn*16+fr)*136 + fq*8 + ks*32];
        accG[tn] = MFMA16(aK, bK, accG[tn]);
        accQ[tn] = MFMA16(aQ, bK, accQ[tn]);
      }
    }
    bf16_t* aqg = (bf16_t*)(cdp + CD_AQ);
    #pragma unroll
    for (int tn=0;tn<4;tn++) {
      #pragma unroll
      for (int r=0;r<4;r++) {
        int tt = w*16 + fq*4 + r;
        int ii = tn*16 + fr;
        float er = expf(gcv[tt] - gcv[ii]);
        lLf[tt*65 + ii] = (ii < tt) ? bvv[tt]*er*accG[tn][r] : 0.f;
        aqg[tt*64 + ii] = (bf16_t)((ii <= tt) ? er*accQ[tn][r] : 0.f);
      }
    }
  }
  #pragma unroll
  for (int ib=0; ib<16; ib++) {
    int idx = t + ib*256; int r = idx>>6, cc = idx&63;
    lXf[r*65+cc] = (r==cc) ? bvv[r] : 0.f;
  }
  __syncthreads();   // lLf/lXf ready; lQ reads done -> reuse as lVT

  // stage V^T into lQV with staggered element order (kills 16-way conflicts)
  bf16_t* lVT = lQV;   // [128][72]
  {
    const int m = t & 15;
    #pragma unroll
    for (int ib=0; ib<4; ib++) {
      int e0 = (t + 256*ib)*8;
      int r = e0 >> 7, cc = e0 & 127;
      bf16x8 v8 = *(const bf16x8*)(vg + e0);
      #pragma unroll
      for (int e=0;e<8;e++) {
        int ee = (e + m) & 7;
        lVT[(cc+ee)*72 + r] = v8[ee];
      }
    }
  }

  // forward elimination: X[t] -= Lf[t][i] * X[i]
  {
    const int jj = t & 63, rg = t >> 6;
    for (int i=0; i<CH-1; i++) {
      float xi = lXf[i*65 + jj];
      for (int tr = i+1+rg; tr < CH; tr += 4)
        lXf[tr*65 + jj] = fmaf(-lLf[tr*65 + i], xi, lXf[tr*65 + jj]);
      __syncthreads();
    }
  }

  // Tp store + bf16 copy of Tmat (reuse lLf region)
  bf16_t* lXb = (bf16_t*)lLf;   // [64][72]
  {
    bf16_t* tpg = (bf16_t*)(cdp + CD_TP);
    #pragma unroll
    for (int ib=0; ib<16; ib++) {
      int idx = t + ib*256; int r = idx>>6, cc = idx&63;
      float xv = lXf[r*65+cc];
      tpg[r*64+cc] = (bf16_t)(xv * pvv[cc]);
      lXb[r*72+cc] = (bf16_t)xv;
    }
  }
  __syncthreads();

  // TV = Tmat @ V : C[t][dv] = sum_i Xb[t][i] * VT[dv][i]
  {
    f32x4 acc[8];
    #pragma unroll
    for (int tn=0;tn<8;tn++) acc[tn]=(f32x4){0,0,0,0};
    #pragma unroll
    for (int ks=0;ks<2;ks++) {
      bf16x8 aX = *(const bf16x8*)&lXb[(w*16+fr)*72 + fq*8 + ks*32];
      #pragma unroll
      for (int tn=0;tn<8;tn++) {
        bf16x8 bV = *(const bf16x8*)&lVT[(tn*16+fr)*72 + fq*8 + ks*32];
        acc[tn] = MFMA16(aX, bV, acc[tn]);
      }
    }
    bf16_t* tvg = (bf16_t*)(cdp + CD_TV);
    #pragma unroll
    for (int tn=0;tn<8;tn++)
      #pragma unroll
      for (int r=0;r<4;r++) {
        int tt = w*16 + fq*4 + r, dv = tn*16 + fr;
        tvg[tt*128 + dv] = (bf16_t)acc[tn][r];
      }
  }

  // KTs[dk][i] = K[i][dk] * exp(gc_C - gc_i)
  {
    bf16_t* ktg = (bf16_t*)(cdp + CD_KTS);
    int dk = t >> 1, c0 = (t & 1)*32;
    float g63 = gcv[63];
    bf16_t tmp[32];
    #pragma unroll
    for (int i2=0;i2<32;i2++) {
      int i = c0 + i2;
      tmp[i2] = (bf16_t)((float)lK[i*136 + dk] * expf(g63 - gcv[i]));
    }
    #pragma unroll
    for (int s8=0;s8<4;s8++)
      *(bf16x8*)&ktg[dk*64 + c0 + s8*8] = *(bf16x8*)&tmp[s8*8];
  }
  if (t < 64) ((float*)(cdp + CD_PV))[t] = pvv[t];
  if (t == 0) *((float*)(cdp + CD_PC)) = expf(gcv[63]);
}

// ---------------------------------------------------------------------------
// Phase S (serial over 32 chunks per (bh, dv-split of 32)):
//   X=K S; Xq=Q S (store); D = TV - Tp X (store D^T); S = PC*S + KTs D
// ---------------------------------------------------------------------------
__global__ __launch_bounds__(256) void chunkS_kernel(
    const bf16_t* __restrict__ q_t, const bf16_t* __restrict__ k_t,
    const char* __restrict__ cdata, bf16_t* __restrict__ gD,
    bf16_t* __restrict__ gXq)
{
  extern __shared__ char smem[];
  float*  lS   = (float*)(smem);             // [32][132]  S[dv][dk]
  bf16_t* lSb  = (bf16_t*)(smem + 16896);    // [32][136]
  bf16_t* lK   = (bf16_t*)(smem + 25600);    // [64][136]
  bf16_t* lQ   = (bf16_t*)(smem + 43008);    // [64][136]
  bf16_t* lTp  = (bf16_t*)(smem + 60416);    // [64][72]
  bf16_t* lKT  = (bf16_t*)(smem + 69632);    // [128][72]
  bf16_t* lXT  = (bf16_t*)(smem + 88064);    // [32][72]
  bf16_t* lDT  = (bf16_t*)(smem + 92672);    // [32][72]
  float*  lPC  = (float*)(smem + 97280);

  const int bid = blockIdx.x;
  const int lb  = (bid & 7)*16 + (bid >> 3);   // same-bh blocks on one XCD
  const int bh = lb >> 2, sp = lb & 3;
  const int dv0 = sp*32;
  const int t = threadIdx.x, lane = t & 63, w = t >> 6;
  const int fr = lane & 15, fq = lane >> 4;

  #pragma unroll
  for (int ib=0; ib<16; ib++) {
    int idx = t + ib*256; int r = idx>>7, cc = idx&127;
    lS[r*132+cc] = 0.f;
    lSb[r*136+cc] = (bf16_t)0.f;
  }

  const bf16_t* kg = k_t + (long)bh*SS*128;
  const bf16_t* qg = q_t + (long)bh*SS*128;

  for (int c=0; c<NCH; c++) {
    const int cd = bh*NCH + c;
    const char* cdp = cdata + (long)cd*CD_STRIDE;
    #pragma unroll
    for (int ib=0; ib<4; ib++) {
      int e0 = (t + 256*ib)*8;
      int r = e0 >> 7, cc = e0 & 127;
      *(bf16x8*)&lK[r*136+cc] = *(const bf16x8*)(kg + (long)c*CH*128 + e0);
      *(bf16x8*)&lQ[r*136+cc] = *(const bf16x8*)(qg + (long)c*CH*128 + e0);
    }
    #pragma unroll
    for (int ib=0; ib<2; ib++) {
      int e0 = (t + 256*ib)*8;
      int r = e0 >> 6, cc = e0 & 63;
      *(bf16x8*)&lTp[r*72+cc] = *(const bf16x8*)((const bf16_t*)(cdp+CD_TP) + e0);
    }
    #pragma unroll
    for (int ib=0; ib<4; ib++) {
      int e0 = (t + 256*ib)*8;
      int r = e0 >> 6, cc = e0 & 63;
      *(bf16x8*)&lKT[r*72+cc] = *(const bf16x8*)((const bf16_t*)(cdp+CD_KTS) + e0);
    }
    if (t == 0) *lPC = *(const float*)(cdp+CD_PC);
    __syncthreads();

    // X = K Sb, Xq = Q Sb  (M=64 strip/wave, N=32, K=128)
    f32x4 aX[2], aXq[2];
    aX[0]=aX[1]=aXq[0]=aXq[1]=(f32x4){0,0,0,0};
    #pragma unroll
    for (int ks=0; ks<4; ks++) {
      bf16x8 aK = *(const bf16x8*)&lK[(w*16+fr)*136 + fq*8 + ks*32];
      bf16x8 aQ = *(const bf16x8*)&lQ[(w*16+fr)*136 + fq*8 + ks*32];
      #pragma unroll
      for (int tn=0; tn<2; tn++) {
        bf16x8 bS = *(const bf16x8*)&lSb[(tn*16+fr)*136 + fq*8 + ks*32];
        aX[tn]  = MFMA16(aK, bS, aX[tn]);
        aXq[tn] = MFMA16(aQ, bS, aXq[tn]);
      }
    }
    #pragma unroll
    for (int tn=0; tn<2; tn++)
      #pragma unroll
      for (int r=0; r<4; r++) {
        int tt = w*16+fq*4+r;
        lXT[(tn*16+fr)*72 + tt] = (bf16_t)aX[tn][r];
        gXq[((long)cd*CH + tt)*128 + dv0 + tn*16+fr] = (bf16_t)aXq[tn][r];
      }
    __syncthreads();

    // D = TV - Tp X   -> lDT[dv][t] bf16
    {
      f32x4 aD[2]; aD[0]=aD[1]=(f32x4){0,0,0,0};
      #pragma unroll
      for (int ks=0; ks<2; ks++) {
        bf16x8 aT = *(const bf16x8*)&lTp[(w*16+fr)*72 + fq*8 + ks*32];
        #pragma unroll
        for (int tn=0; tn<2; tn++) {
          bf16x8 bX = *(const bf16x8*)&lXT[(tn*16+fr)*72 + fq*8 + ks*32];
          aD[tn] = MFMA16(aT, bX, aD[tn]);
        }
      }
      const bf16_t* tvp = (const bf16_t*)(cdp + CD_TV);
      #pragma unroll
      for (int tn=0; tn<2; tn++)
        #pragma unroll
        for (int r=0; r<4; r++) {
          int tt = w*16+fq*4+r, dv = tn*16+fr;
          float dval = (float)tvp[tt*128 + dv0 + dv] - aD[tn][r];
          lDT[dv*72 + tt] = (bf16_t)dval;
        }
    }
    // scale S by PC (before the barrier; RMW adds happen after it)
    {
      float pc = *lPC;
      #pragma unroll
      for (int ib=0; ib<16; ib++) {
        int idx = t + ib*256; int r = idx>>7, cc = idx&127;
        lS[r*132+cc] *= pc;
      }
    }
    __syncthreads();

    // S += KTs D ; also store D^T to global
    {
      f32x4 aS[2][2];
      aS[0][0]=aS[0][1]=aS[1][0]=aS[1][1]=(f32x4){0,0,0,0};
      #pragma unroll
      for (int ks=0; ks<2; ks++) {
        bf16x8 bD0 = *(const bf16x8*)&lDT[(0*16+fr)*72 + fq*8 + ks*32];
        bf16x8 bD1 = *(const bf16x8*)&lDT[(1*16+fr)*72 + fq*8 + ks*32];
        #pragma unroll
        for (int mt=0; mt<2; mt++) {
          bf16x8 aK2 = *(const bf16x8*)&lKT[(w*32+mt*16+fr)*72 + fq*8 + ks*32];
          aS[mt][0] = MFMA16(aK2, bD0, aS[mt][0]);
          aS[mt][1] = MFMA16(aK2, bD1, aS[mt][1]);
        }
      }
      // D^T copy: 32x64 elems, one bf16x8 per thread
      {
        int dvl = t >> 3, off = (t & 7)*8;
        *(bf16x8*)(gD + ((long)cd*128 + dv0 + dvl)*64 + off) =
            *(const bf16x8*)&lDT[dvl*72 + off];
      }
      #pragma unroll
      for (int mt=0; mt<2; mt++)
        #pragma unroll
        for (int tn=0; tn<2; tn++)
          #pragma unroll
          for (int r=0; r<4; r++) {
            int dk = w*32+mt*16+fq*4+r, dv = tn*16+fr;
            lS[dv*132 + dk] += aS[mt][tn][r];
          }
    }
    __syncthreads();
    #pragma unroll
    for (int ib=0; ib<16; ib++) {
      int idx = t + ib*256; int r = idx>>7, cc = idx&127;
      lSb[r*136+cc] = (bf16_t)lS[r*132+cc];
    }
    __syncthreads();
  }
}

// ---------------------------------------------------------------------------
// Phase O (parallel, per chunk): O = diag(p) Xq + Aq D  -> obuf
// No LDS; fragments read straight from global (L2-resident).
// ---------------------------------------------------------------------------
__global__ __launch_bounds__(256) void chunkO_kernel(
    const char* __restrict__ cdata, const bf16_t* __restrict__ gD,
    const bf16_t* __restrict__ gXq, bf16_t* __restrict__ obuf)
{
  const int cd = blockIdx.x;
  const int bh = cd >> 5, c = cd & 31;
  const int b = bh >> 4, h = bh & 15;
  const int t = threadIdx.x, lane = t & 63, w = t >> 6;
  const int fr = lane & 15, fq = lane >> 4;

  const char* cdp = cdata + (long)cd*CD_STRIDE;
  const bf16_t* aqp = (const bf16_t*)(cdp + CD_AQ);   // [64][64]
  const bf16_t* dp  = gD + (long)cd*128*64;           // [128 dv][64 t]
  const float*  pvp = (const float*)(cdp + CD_PV);

  f32x4 acc[8];
  #pragma unroll
  for (int tn=0;tn<8;tn++) acc[tn]=(f32x4){0,0,0,0};
  #pragma unroll
  for (int ks=0;ks<2;ks++) {
    bf16x8 aA = *(const bf16x8*)(aqp + (w*16+fr)*64 + fq*8 + ks*32);
    #pragma unroll
    for (int tn=0;tn<8;tn++) {
      bf16x8 bD = *(const bf16x8*)(dp + (tn*16+fr)*64 + fq*8 + ks*32);
      acc[tn] = MFMA16(aA, bD, acc[tn]);
    }
  }
  #pragma unroll
  for (int tn=0;tn<8;tn++)
    #pragma unroll
    for (int r=0;r<4;r++) {
      int tt = w*16+fq*4+r, dv = tn*16+fr;
      float ov = pvp[tt]*(float)gXq[((long)cd*CH + tt)*128 + dv] + acc[tn][r];
      obuf[((long)(b*SS + c*CH + tt)*HH + h)*128 + dv] = (bf16_t)ov;
    }
}

// ---------------------------------------------------------------------------
// RMSNorm over DV + (1+nw) + silu(z) gate; writes bf16 for final GEMM
// ---------------------------------------------------------------------------
__global__ __launch_bounds__(128) void norm_gate_kernel(
    const bf16_t* __restrict__ o, const bf16_t* __restrict__ z,
    const float* __restrict__ nw, bf16_t* __restrict__ og)
{
  const long row = blockIdx.x;      // (b*S+s)*H + h
  const int d = threadIdx.x;
  float x = (float)o[row*128 + d];
  float ss = x*x;
  #pragma unroll
  for (int off=32; off>=1; off>>=1) ss += __shfl_xor(ss, off);
  __shared__ float red[2];
  if ((d & 63) == 0) red[d>>6] = ss;
  __syncthreads();
  float mean = (red[0] + red[1]) * (1.f/128.f);
  float zn = (float)z[row*128 + d];
  float val = x * rsqrtf(mean + 1e-6f) * (1.f + nw[d]) * (zn * (1.f/(1.f+expf(-zn))));
  og[row*128 + d] = (bf16_t)val;
}

// ---------------------------------------------------------------------------
extern "C" void kernel_launch(void* const* d_in, const int* in_sizes, int n_in,
                              void* d_out, int out_size, void* d_ws, size_t ws_size,
                              hipStream_t stream)
{
  const float* hs    = (const float*)d_in[0];
  const float* amask = (const float*)d_in[1];
  const float* Wqkv  = (const float*)d_in[2];
  const float* convw = (const float*)d_in[3];
  const float* convb = (const float*)d_in[4];
  const float* Wz    = (const float*)d_in[5];
  const float* Wb    = (const float*)d_in[6];
  const float* Wa    = (const float*)d_in[7];
  const float* dtb   = (const float*)d_in[8];
  const float* Alog  = (const float*)d_in[9];
  const float* nw    = (const float*)d_in[10];
  const float* Wout  = (const float*)d_in[11];

  const size_t MB = 1024*1024;
  char* p = (char*)d_ws;
  auto alloc = [&](size_t bytes) { char* r = p; p += (bytes + 255) & ~(size_t)255; return r; };
  bf16_t* x_bf   = (bf16_t*)alloc(16*MB);   // x_bf; later gD [1024][128][64]
  char*   bigreg = alloc(72*MB);            // wqkv@0, mixed@24MB; later cdata@0, obuf@52MB
  bf16_t* wz_bf  = (bf16_t*)alloc(8*MB);    // Wz; later Wout
  bf16_t* zbuf   = (bf16_t*)alloc(16*MB);   // z; og in-place later
  bf16_t* q_t    = (bf16_t*)alloc(16*MB);
  bf16_t* k_t    = (bf16_t*)alloc(16*MB);
  bf16_t* v_t    = (bf16_t*)alloc(16*MB);   // v; later gXq [1024][64][128]
  float2* gb_t   = (float2*)alloc((size_t)BB*HH*SS*8);
  size_t need = (size_t)(p - (char*)d_ws);
  if (ws_size < need) return;   // clean fail (absmax = poison)

  bf16_t* wqkv_bf = (bf16_t*)bigreg;
  bf16_t* mixed   = (bf16_t*)(bigreg + 24*MB);
  char*   cdata   = bigreg;                       // after GEMM1+conv consumed
  bf16_t* obuf    = (bf16_t*)(bigreg + 52*MB);    // cdata ends at ~48.5MB
  bf16_t* wout_bf = wz_bf;                        // cast after z-GEMM
  bf16_t* gD      = x_bf;                         // after z-GEMM consumed x_bf
  bf16_t* gXq     = v_t;                          // after chunkA consumed v_t
  bf16_t* og      = zbuf;                         // in-place gate

  cast_x_kernel<<<2048, 256, 0, stream>>>(hs, amask, x_bf, (long)MM*DD);
  cast_w_kernel<<<2048, 256, 0, stream>>>(Wqkv, wqkv_bf, (long)CONVC*DD);
  cast_w_kernel<<<1024, 256, 0, stream>>>(Wz,   wz_bf,   (long)DD*DD);

  betag_kernel<<<MM, 64, 0, stream>>>(x_bf, Wb, Wa, dtb, Alog, gb_t);

  gemm_bt<true><<<dim3(32,48), 256, 0, stream>>>(x_bf, wqkv_bf, mixed, MM, CONVC, DD);

  conv_norm_kernel<<<BB*HH*SS, 128, 0, stream>>>(mixed, convw, convb, q_t, k_t, v_t);

  gemm_bt<true><<<dim3(32,16), 256, 0, stream>>>(x_bf, wz_bf, zbuf, MM, DD, DD);
  cast_w_kernel<<<1024, 256, 0, stream>>>(Wout, wout_bf, (long)DD*DD);

  chunkA_kernel<<<BB*HH*NCH, 256, 69888, stream>>>(q_t, k_t, v_t, gb_t, cdata);
  chunkS_kernel<<<BB*HH*4, 256, 97536, stream>>>(q_t, k_t, cdata, gD, gXq);
  chunkO_kernel<<<BB*HH*NCH, 256, 0, stream>>>(cdata, gD, gXq, obuf);

  norm_gate_kernel<<<MM*HH, 128, 0, stream>>>(obuf, zbuf, nw, og);

  gemm_bt<false><<<dim3(32,16), 256, 0, stream>>>(og, wout_bf, d_out, MM, DD, DD);
}

// Round 8
// 693.649 us; speedup vs baseline: 1.1706x; 1.1706x over previous
//
#include <hip/hip_runtime.h>
#include <hip/hip_bf16.h>
#include <math.h>

// Problem constants
#define BB 2
#define SS 2048
#define DD 2048
#define HH 16
#define CONVC 6144
#define MM (BB*SS)   // 4096 tokens

// chunked delta-rule constants
#define CH 64        // chunk length
#define NCH 32       // chunks per sequence
#define CD_KTS 0
#define CD_TV  16384
#define CD_TP  32768
#define CD_AQ  40960
#define CD_PV  49152
#define CD_PC  49408
#define CD_STRIDE 49664

typedef __bf16 bf16_t;
typedef __bf16 bf16x8 __attribute__((ext_vector_type(8)));
typedef __bf16 bf16x4 __attribute__((ext_vector_type(4)));
typedef float  f32x4  __attribute__((ext_vector_type(4)));

#define GLOBAL_AS __attribute__((address_space(1)))
#define LDS_AS    __attribute__((address_space(3)))

#define MFMA16(a,b,c) __builtin_amdgcn_mfma_f32_16x16x32_bf16((a),(b),(c),0,0,0)

// ---------------------------------------------------------------------------
// Cast kernels
// ---------------------------------------------------------------------------
__global__ __launch_bounds__(256) void cast_x_kernel(
    const float* __restrict__ in, const float* __restrict__ mask,
    bf16_t* __restrict__ out, long n)
{
  long n4 = n >> 2;
  for (long i = (long)blockIdx.x*256 + threadIdx.x; i < n4; i += (long)gridDim.x*256) {
    float4 v = ((const float4*)in)[i];
    float m = mask[(i*4) / DD];
    bf16x4 o4;
    o4[0]=(bf16_t)(v.x*m); o4[1]=(bf16_t)(v.y*m);
    o4[2]=(bf16_t)(v.z*m); o4[3]=(bf16_t)(v.w*m);
    ((bf16x4*)out)[i] = o4;
  }
}

__global__ __launch_bounds__(256) void cast_w_kernel(
    const float* __restrict__ in, bf16_t* __restrict__ out, long n)
{
  long n4 = n >> 2;
  for (long i = (long)blockIdx.x*256 + threadIdx.x; i < n4; i += (long)gridDim.x*256) {
    float4 v = ((const float4*)in)[i];
    bf16x4 o4;
    o4[0]=(bf16_t)v.x; o4[1]=(bf16_t)v.y; o4[2]=(bf16_t)v.z; o4[3]=(bf16_t)v.w;
    ((bf16x4*)out)[i] = o4;
  }
}

// ---------------------------------------------------------------------------
// bf16 MFMA GEMM: C[M,N] = A[M,K] * B[N,K]^T   (m97-style 128x128 tile, BK=32)
// ---------------------------------------------------------------------------
template<bool OUT_BF16>
__global__ __launch_bounds__(256) void gemm_bt(
    const bf16_t* __restrict__ A, const bf16_t* __restrict__ Bm,
    void* __restrict__ Cp, int M, int N, int K)
{
  __shared__ __align__(16) bf16_t lA[128*32];
  __shared__ __align__(16) bf16_t lB[128*32];
  const int t    = threadIdx.x;
  const int lane = t & 63;
  const int w    = t >> 6;       // wave 0..3
  const int wm   = w >> 1, wn = w & 1;
  const int fr   = lane & 15, fq = lane >> 4;
  const long bm  = blockIdx.x, bn = blockIdx.y;

  f32x4 acc[4][4];
  #pragma unroll
  for (int i=0;i<4;i++)
    #pragma unroll
    for (int jj=0;jj<4;jj++) acc[i][jj] = (f32x4){0.f,0.f,0.f,0.f};

  const int r1 = t >> 2;
  const int kb = (t & 3) << 3;
  const bf16_t* a0 = A  + (bm*128 + r1)*(long)K + kb;
  const bf16_t* a1 = a0 + 64*(long)K;
  const bf16_t* b0 = Bm + (bn*128 + r1)*(long)K + kb;
  const bf16_t* b1 = b0 + 64*(long)K;
  bf16_t* lA0 = lA + (w*64)*8;        // wave-uniform LDS bases
  bf16_t* lA1 = lA + (256 + w*64)*8;
  bf16_t* lB0 = lB + (w*64)*8;
  bf16_t* lB1 = lB + (256 + w*64)*8;

  for (int k0 = 0; k0 < K; k0 += 32) {
    __builtin_amdgcn_global_load_lds((const GLOBAL_AS void*)(a0 + k0), (LDS_AS void*)lA0, 16, 0, 0);
    __builtin_amdgcn_global_load_lds((const GLOBAL_AS void*)(a1 + k0), (LDS_AS void*)lA1, 16, 0, 0);
    __builtin_amdgcn_global_load_lds((const GLOBAL_AS void*)(b0 + k0), (LDS_AS void*)lB0, 16, 0, 0);
    __builtin_amdgcn_global_load_lds((const GLOBAL_AS void*)(b1 + k0), (LDS_AS void*)lB1, 16, 0, 0);
    __syncthreads();   // drains vmcnt before reads

    bf16x8 af[4], bfr[4];
    #pragma unroll
    for (int mi=0;mi<4;mi++)
      af[mi] = *(const bf16x8*)(lA + (wm*64 + mi*16 + fr)*32 + fq*8);
    #pragma unroll
    for (int ni=0;ni<4;ni++)
      bfr[ni] = *(const bf16x8*)(lB + (wn*64 + ni*16 + fr)*32 + fq*8);
    #pragma unroll
    for (int mi=0;mi<4;mi++)
      #pragma unroll
      for (int ni=0;ni<4;ni++)
        acc[mi][ni] = MFMA16(af[mi], bfr[ni], acc[mi][ni]);
    __syncthreads();   // protect LDS before next stage
  }

  #pragma unroll
  for (int mi=0;mi<4;mi++) {
    #pragma unroll
    for (int ni=0;ni<4;ni++) {
      long row = bm*128 + wm*64 + mi*16 + fq*4;
      long col = bn*128 + wn*64 + ni*16 + fr;
      #pragma unroll
      for (int r=0;r<4;r++) {
        float v = acc[mi][ni][r];
        if (OUT_BF16) ((bf16_t*)Cp)[(row+r)*(long)N + col] = (bf16_t)v;
        else          ((float*)Cp)[(row+r)*(long)N + col] = v;
      }
    }
  }
}

// ---------------------------------------------------------------------------
// beta / g:  per token, 16 dots with W_b rows and 16 with W_a rows (K=2048)
// writes gb_t[bh][s] = {g (log decay), beta}
// ---------------------------------------------------------------------------
__global__ __launch_bounds__(64) void betag_kernel(
    const bf16_t* __restrict__ xbf, const float* __restrict__ W_b,
    const float* __restrict__ W_a, const float* __restrict__ dt_bias,
    const float* __restrict__ A_log, float2* __restrict__ gb_t)
{
  const int row  = blockIdx.x;        // token b*S+s
  const int lane = threadIdx.x;
  const int b = row / SS, s = row % SS;

  float xv[32];
  {
    const bf16x8* xr = (const bf16x8*)(xbf + (long)row*DD + lane*32);
    #pragma unroll
    for (int c8=0;c8<4;c8++) {
      bf16x8 v = xr[c8];
      #pragma unroll
      for (int e=0;e<8;e++) xv[c8*8+e] = (float)v[e];
    }
  }

  for (int h=0; h<HH; ++h) {
    const float4* wb4 = (const float4*)(W_b + (long)h*DD + lane*32);
    const float4* wa4 = (const float4*)(W_a + (long)h*DD + lane*32);
    float pb = 0.f, pa = 0.f;
    #pragma unroll
    for (int c4=0;c4<8;c4++) {
      float4 wb = wb4[c4], wa = wa4[c4];
      pb += xv[c4*4+0]*wb.x + xv[c4*4+1]*wb.y + xv[c4*4+2]*wb.z + xv[c4*4+3]*wb.w;
      pa += xv[c4*4+0]*wa.x + xv[c4*4+1]*wa.y + xv[c4*4+2]*wa.z + xv[c4*4+3]*wa.w;
    }
    #pragma unroll
    for (int off=32; off>=1; off>>=1) { pb += __shfl_xor(pb, off); pa += __shfl_xor(pa, off); }
    if (lane == h) {
      float beta = 1.f/(1.f+expf(-pb));
      float tt = pa + dt_bias[h];
      float sp = (tt > 20.f) ? tt : log1pf(expf(tt));
      float g  = -expf(A_log[h]) * sp;
      gb_t[((long)b*HH + h)*SS + s] = make_float2(g, beta);
    }
  }
}

// ---------------------------------------------------------------------------
// conv(K=4 causal depthwise) + bias + silu + q/k l2norm + transpose to [B,H,S,128]
// ---------------------------------------------------------------------------
__global__ __launch_bounds__(128) void conv_norm_kernel(
    const bf16_t* __restrict__ mixed, const float* __restrict__ cw,
    const float* __restrict__ cb, bf16_t* __restrict__ q_t,
    bf16_t* __restrict__ k_t, bf16_t* __restrict__ v_t)
{
  const int blk = blockIdx.x;           // (b*H+h)*S + s
  const int s = blk & (SS-1);
  const int h = (blk >> 11) & (HH-1);
  const int b = blk >> 15;
  const int d = threadIdx.x;

  const int cq = h*128 + d;
  const int ck = 2048 + cq;
  const int cv = 4096 + cq;
  float aq = cb[cq], ak = cb[ck], av = cb[cv];
  const float* wq = cw + (long)cq*4;
  const float* wk = cw + (long)ck*4;
  const float* wv = cw + (long)cv*4;
  #pragma unroll
  for (int tp=0; tp<4; ++tp) {
    int s2 = s - 3 + tp;
    if (s2 >= 0) {
      const bf16_t* rowp = mixed + ((long)b*SS + s2)*CONVC;
      aq += (float)rowp[cq] * wq[tp];
      ak += (float)rowp[ck] * wk[tp];
      av += (float)rowp[cv] * wv[tp];
    }
  }
  aq = aq * (1.f/(1.f+expf(-aq)));
  ak = ak * (1.f/(1.f+expf(-ak)));
  av = av * (1.f/(1.f+expf(-av)));

  float sq = aq*aq, sk = ak*ak;
  #pragma unroll
  for (int off=32; off>=1; off>>=1) { sq += __shfl_xor(sq, off); sk += __shfl_xor(sk, off); }
  __shared__ float red[4];
  const int wv2 = d >> 6;
  if ((d & 63) == 0) { red[wv2*2] = sq; red[wv2*2+1] = sk; }
  __syncthreads();
  float sumq = red[0] + red[2];
  float sumk = red[1] + red[3];

  const long obase = ((long)(b*HH + h)*SS + s)*128 + d;
  q_t[obase] = (bf16_t)(aq * rsqrtf(sumq + 1e-6f) * 0.08838834764831845f);  // * DK^-0.5
  k_t[obase] = (bf16_t)(ak * rsqrtf(sumk + 1e-6f));
  v_t[obase] = (bf16_t)av;
}

// ---------------------------------------------------------------------------
// Phase A (per bh,chunk): build Tp/Aq/TV/KTs/pv/PC into cdata.
// LDS 69.9KB (lQ/lVT time-share) -> 2 blocks/CU. Staggered V^T writes.
// ---------------------------------------------------------------------------
__global__ __launch_bounds__(256) void chunkA_kernel(
    const bf16_t* __restrict__ q_t, const bf16_t* __restrict__ k_t,
    const bf16_t* __restrict__ v_t, const float2* __restrict__ gb_t,
    char* __restrict__ cdata)
{
  extern __shared__ char smem[];
  bf16_t* lK  = (bf16_t*)(smem);            // [64][136]
  bf16_t* lQV = (bf16_t*)(smem + 17408);    // lQ [64][136], later lVT [128][72]
  float*  lLf = (float*)(smem + 35840);     // [64][65]
  float*  lXf = (float*)(smem + 52480);     // [64][65]
  float*  gcv = (float*)(smem + 69120);     // [64]
  float*  pvv = (float*)(smem + 69376);     // [64]
  float*  bvv = (float*)(smem + 69632);     // [64]

  const int cd = blockIdx.x;
  const int bh = cd >> 5, c = cd & 31;
  const int t = threadIdx.x;
  const int lane = t & 63, w = t >> 6;
  const int fr = lane & 15, fq = lane >> 4;

  const bf16_t* kg = k_t + ((long)bh*SS + c*CH)*128;
  const bf16_t* qg = q_t + ((long)bh*SS + c*CH)*128;
  const bf16_t* vg = v_t + ((long)bh*SS + c*CH)*128;
  char* cdp = cdata + (long)cd*CD_STRIDE;

  // stage K, Q (lQV as lQ)
  #pragma unroll
  for (int ib=0; ib<4; ib++) {
    int e0 = (t + 256*ib)*8;
    int r = e0 >> 7, cc = e0 & 127;
    *(bf16x8*)&lK[r*136+cc]  = *(const bf16x8*)(kg + e0);
    *(bf16x8*)&lQV[r*136+cc] = *(const bf16x8*)(qg + e0);
  }
  if (t < 64) {
    float2 gb = gb_t[(long)bh*SS + c*CH + t];
    gcv[t] = gb.x;
    bvv[t] = gb.y;
  }
  __syncthreads();
  // wave-parallel inclusive scan of gcv (wave 0)
  if (t < 64) {
    float g = gcv[t];
    #pragma unroll
    for (int off=1; off<64; off<<=1) {
      float n = __shfl_up(g, off);
      if (lane >= off) g += n;
    }
    gcv[t] = g;
  }
  __syncthreads();
  if (t < 64) pvv[t] = expf(gcv[t]);

  // G = K K^T, Gq = Q K^T  (wave strip rows 16w)
  {
    f32x4 accG[4], accQ[4];
    #pragma unroll
    for (int tn=0;tn<4;tn++){ accG[tn]=(f32x4){0,0,0,0}; accQ[tn]=(f32x4){0,0,0,0}; }
    #pragma unroll
    for (int ks=0;ks<4;ks++) {
      bf16x8 aK = *(const bf16x8*)&lK[(w*16+fr)*136 + fq*8 + ks*32];
      bf16x8 aQ = *(const bf16x8*)&lQV[(w*16+fr)*136 + fq*8 + ks*32];
      #pragma unroll
      for (int tn=0;tn<4;tn++) {
        bf16x8 bK = *(const bf16x8*)&lK[(tn*16+fr)*136 + fq*8 + ks*32];
        accG[tn] = MFMA16(aK, bK, accG[tn]);
        accQ[tn] = MFMA16(aQ, bK, accQ[tn]);
      }
    }
    bf16_t* aqg = (bf16_t*)(cdp + CD_AQ);
    #pragma unroll
    for (int tn=0;tn<4;tn++) {
      #pragma unroll
      for (int r=0;r<4;r++) {
        int tt = w*16 + fq*4 + r;
        int ii = tn*16 + fr;
        float er = expf(gcv[tt] - gcv[ii]);
        lLf[tt*65 + ii] = (ii < tt) ? bvv[tt]*er*accG[tn][r] : 0.f;
        aqg[tt*64 + ii] = (bf16_t)((ii <= tt) ? er*accQ[tn][r] : 0.f);
      }
    }
  }
  #pragma unroll
  for (int ib=0; ib<16; ib++) {
    int idx = t + ib*256; int r = idx>>6, cc = idx&63;
    lXf[r*65+cc] = (r==cc) ? bvv[r] : 0.f;
  }
  __syncthreads();   // lLf/lXf ready; lQ reads done -> reuse as lVT

  // stage V^T into lQV with staggered element order (kills 16-way conflicts)
  bf16_t* lVT = lQV;   // [128][72]
  {
    const int m = t & 15;
    #pragma unroll
    for (int ib=0; ib<4; ib++) {
      int e0 = (t + 256*ib)*8;
      int r = e0 >> 7, cc = e0 & 127;
      bf16x8 v8 = *(const bf16x8*)(vg + e0);
      #pragma unroll
      for (int e=0;e<8;e++) {
        int ee = (e + m) & 7;
        lVT[(cc+ee)*72 + r] = v8[ee];
      }
    }
  }

  // forward elimination: X[t] -= Lf[t][i] * X[i]
  {
    const int jj = t & 63, rg = t >> 6;
    for (int i=0; i<CH-1; i++) {
      float xi = lXf[i*65 + jj];
      for (int tr = i+1+rg; tr < CH; tr += 4)
        lXf[tr*65 + jj] = fmaf(-lLf[tr*65 + i], xi, lXf[tr*65 + jj]);
      __syncthreads();
    }
  }

  // Tp store + bf16 copy of Tmat (reuse lLf region)
  bf16_t* lXb = (bf16_t*)lLf;   // [64][72]
  {
    bf16_t* tpg = (bf16_t*)(cdp + CD_TP);
    #pragma unroll
    for (int ib=0; ib<16; ib++) {
      int idx = t + ib*256; int r = idx>>6, cc = idx&63;
      float xv = lXf[r*65+cc];
      tpg[r*64+cc] = (bf16_t)(xv * pvv[cc]);
      lXb[r*72+cc] = (bf16_t)xv;
    }
  }
  __syncthreads();

  // TV = Tmat @ V : C[t][dv] = sum_i Xb[t][i] * VT[dv][i]
  {
    f32x4 acc[8];
    #pragma unroll
    for (int tn=0;tn<8;tn++) acc[tn]=(f32x4){0,0,0,0};
    #pragma unroll
    for (int ks=0;ks<2;ks++) {
      bf16x8 aX = *(const bf16x8*)&lXb[(w*16+fr)*72 + fq*8 + ks*32];
      #pragma unroll
      for (int tn=0;tn<8;tn++) {
        bf16x8 bV = *(const bf16x8*)&lVT[(tn*16+fr)*72 + fq*8 + ks*32];
        acc[tn] = MFMA16(aX, bV, acc[tn]);
      }
    }
    bf16_t* tvg = (bf16_t*)(cdp + CD_TV);
    #pragma unroll
    for (int tn=0;tn<8;tn++)
      #pragma unroll
      for (int r=0;r<4;r++) {
        int tt = w*16 + fq*4 + r, dv = tn*16 + fr;
        tvg[tt*128 + dv] = (bf16_t)acc[tn][r];
      }
  }

  // KTs[dk][i] = K[i][dk] * exp(gc_C - gc_i)
  {
    bf16_t* ktg = (bf16_t*)(cdp + CD_KTS);
    int dk = t >> 1, c0 = (t & 1)*32;
    float g63 = gcv[63];
    bf16_t tmp[32];
    #pragma unroll
    for (int i2=0;i2<32;i2++) {
      int i = c0 + i2;
      tmp[i2] = (bf16_t)((float)lK[i*136 + dk] * expf(g63 - gcv[i]));
    }
    #pragma unroll
    for (int s8=0;s8<4;s8++)
      *(bf16x8*)&ktg[dk*64 + c0 + s8*8] = *(bf16x8*)&tmp[s8*8];
  }
  if (t < 64) ((float*)(cdp + CD_PV))[t] = pvv[t];
  if (t == 0) *((float*)(cdp + CD_PC)) = expf(gcv[63]);
}

// ---------------------------------------------------------------------------
// Phase S (serial over 32 chunks; 256 blocks = 32 bh x 8 dv-splits of 16):
//   X=K S; Xq=Q S (store); D = TV - Tp X (store D^T); S = PC*S + KTs D
// Pipelined: chunk c+1's K/Q/Tp/KTs are loaded to regs at top of chunk c
// and written to LDS in the tail phase (staging off the serial path).
// ---------------------------------------------------------------------------
__global__ __launch_bounds__(256) void chunkS_kernel(
    const bf16_t* __restrict__ q_t, const bf16_t* __restrict__ k_t,
    const char* __restrict__ cdata, bf16_t* __restrict__ gD,
    bf16_t* __restrict__ gXq)
{
  extern __shared__ char smem[];
  float*  lS  = (float*)(smem);              // [16][129] f32  S^T slice [dv][dk]
  bf16_t* lSb = (bf16_t*)(smem + 8320);      // [16][136] bf16
  bf16_t* lK  = (bf16_t*)(smem + 12672);     // [64][136]
  bf16_t* lQ  = (bf16_t*)(smem + 30080);     // [64][136]
  bf16_t* lTp = (bf16_t*)(smem + 47488);     // [64][72]
  bf16_t* lKT = (bf16_t*)(smem + 56704);     // [128][72]
  bf16_t* lXT = (bf16_t*)(smem + 75136);     // [16][88]  X^T [dv][t]
  bf16_t* lDT = (bf16_t*)(smem + 77952);     // [16][88]  D^T [dv][t]

  const int bid = blockIdx.x;
  const int lb  = (bid & 7)*32 + (bid >> 3);   // same-bh blocks on one XCD
  const int bh = lb >> 3, sp = lb & 7;
  const int dv0 = sp*16;
  const int t = threadIdx.x, lane = t & 63, w = t >> 6;
  const int fr = lane & 15, fq = lane >> 4;

  #pragma unroll
  for (int ib=0; ib<8; ib++) {
    int idx = t + ib*256; int r = idx>>7, cc = idx&127;
    lS[r*129+cc] = 0.f;
    lSb[r*136+cc] = (bf16_t)0.f;
  }

  const bf16_t* kg = k_t + (long)bh*SS*128;
  const bf16_t* qg = q_t + (long)bh*SS*128;

  bf16x8 kr0,kr1,kr2,kr3, qr0,qr1,qr2,qr3, kt0,kt1,kt2,kt3, tp0,tp1;

#define STAGE_LOAD(CSRC)                                                       \
  {                                                                            \
    const char* cdl = cdata + (long)(bh*NCH + (CSRC))*CD_STRIDE;               \
    const bf16_t* kl = kg + (long)(CSRC)*CH*128;                               \
    const bf16_t* ql = qg + (long)(CSRC)*CH*128;                               \
    const bf16_t* ktl = (const bf16_t*)(cdl + CD_KTS);                         \
    const bf16_t* tpl = (const bf16_t*)(cdl + CD_TP);                          \
    int e0 = t*8, e1 = (t+256)*8, e2 = (t+512)*8, e3 = (t+768)*8;              \
    kr0 = *(const bf16x8*)(kl + e0); kr1 = *(const bf16x8*)(kl + e1);          \
    kr2 = *(const bf16x8*)(kl + e2); kr3 = *(const bf16x8*)(kl + e3);          \
    qr0 = *(const bf16x8*)(ql + e0); qr1 = *(const bf16x8*)(ql + e1);          \
    qr2 = *(const bf16x8*)(ql + e2); qr3 = *(const bf16x8*)(ql + e3);          \
    kt0 = *(const bf16x8*)(ktl + e0); kt1 = *(const bf16x8*)(ktl + e1);        \
    kt2 = *(const bf16x8*)(ktl + e2); kt3 = *(const bf16x8*)(ktl + e3);        \
    tp0 = *(const bf16x8*)(tpl + e0); tp1 = *(const bf16x8*)(tpl + e1);        \
  }

#define STAGE_WRITE()                                                          \
  {                                                                            \
    int e0 = t*8, e1 = (t+256)*8, e2 = (t+512)*8, e3 = (t+768)*8;              \
    *(bf16x8*)&lK[(e0>>7)*136 + (e0&127)] = kr0;                               \
    *(bf16x8*)&lK[(e1>>7)*136 + (e1&127)] = kr1;                               \
    *(bf16x8*)&lK[(e2>>7)*136 + (e2&127)] = kr2;                               \
    *(bf16x8*)&lK[(e3>>7)*136 + (e3&127)] = kr3;                               \
    *(bf16x8*)&lQ[(e0>>7)*136 + (e0&127)] = qr0;                               \
    *(bf16x8*)&lQ[(e1>>7)*136 + (e1&127)] = qr1;                               \
    *(bf16x8*)&lQ[(e2>>7)*136 + (e2&127)] = qr2;                               \
    *(bf16x8*)&lQ[(e3>>7)*136 + (e3&127)] = qr3;                               \
    *(bf16x8*)&lKT[(e0>>6)*72 + (e0&63)] = kt0;                                \
    *(bf16x8*)&lKT[(e1>>6)*72 + (e1&63)] = kt1;                                \
    *(bf16x8*)&lKT[(e2>>6)*72 + (e2&63)] = kt2;                                \
    *(bf16x8*)&lKT[(e3>>6)*72 + (e3&63)] = kt3;                                \
    *(bf16x8*)&lTp[(e0>>6)*72 + (e0&63)] = tp0;                                \
    *(bf16x8*)&lTp[(e1>>6)*72 + (e1&63)] = tp1;                                \
  }

  STAGE_LOAD(0);
  STAGE_WRITE();
  __syncthreads();

  for (int c=0; c<NCH; c++) {
    const int cd = bh*NCH + c;
    const char* cdp = cdata + (long)cd*CD_STRIDE;

    // TV quad + PC for current chunk (issued FIRST so their wait doesn't
    // drain the prefetch queue)
    float tvq0, tvq1, tvq2, tvq3, pc;
    {
      const bf16_t* tvp = (const bf16_t*)(cdp + CD_TV);
      tvq0 = (float)tvp[(w*16+fq*4+0)*128 + dv0 + fr];
      tvq1 = (float)tvp[(w*16+fq*4+1)*128 + dv0 + fr];
      tvq2 = (float)tvp[(w*16+fq*4+2)*128 + dv0 + fr];
      tvq3 = (float)tvp[(w*16+fq*4+3)*128 + dv0 + fr];
      pc = *(const float*)(cdp + CD_PC);
    }
    // issue prefetch of chunk c+1 (clamped) into regs
    const int cn = (c+1 < NCH) ? c+1 : c;
    STAGE_LOAD(cn);

    // X = K S^T-slice, Xq = Q S^T-slice  (M=64, N=16, K=128)
    f32x4 aX = {0,0,0,0}, aXq = {0,0,0,0};
    #pragma unroll
    for (int ks=0; ks<4; ks++) {
      bf16x8 bS = *(const bf16x8*)&lSb[fr*136 + fq*8 + ks*32];
      bf16x8 aK = *(const bf16x8*)&lK[(w*16+fr)*136 + fq*8 + ks*32];
      bf16x8 aQ = *(const bf16x8*)&lQ[(w*16+fr)*136 + fq*8 + ks*32];
      aX  = MFMA16(aK, bS, aX);
      aXq = MFMA16(aQ, bS, aXq);
    }
    #pragma unroll
    for (int r=0;r<4;r++)
      lXT[fr*88 + (w*16+fq*4+r)] = (bf16_t)aX[r];
    __syncthreads();   // A

    // D = TV - Tp X  (M=64, N=16, K=64); also scale lS by PC
    {
      f32x4 aD = {0,0,0,0};
      #pragma unroll
      for (int ks=0; ks<2; ks++) {
        bf16x8 aT = *(const bf16x8*)&lTp[(w*16+fr)*72 + fq*8 + ks*32];
        bf16x8 bX = *(const bf16x8*)&lXT[fr*88 + fq*8 + ks*32];
        aD = MFMA16(aT, bX, aD);
      }
      lDT[fr*88 + (w*16+fq*4+0)] = (bf16_t)(tvq0 - aD[0]);
      lDT[fr*88 + (w*16+fq*4+1)] = (bf16_t)(tvq1 - aD[1]);
      lDT[fr*88 + (w*16+fq*4+2)] = (bf16_t)(tvq2 - aD[2]);
      lDT[fr*88 + (w*16+fq*4+3)] = (bf16_t)(tvq3 - aD[3]);
    }
    #pragma unroll
    for (int ib=0; ib<8; ib++) {
      int idx = t + ib*256; int r = idx>>7, cc = idx&127;
      lS[r*129+cc] *= pc;
    }
    __syncthreads();   // B

    // S^T += D^T KTs^T : C[dv][dk] = sum_i D^T[dv][i]*KTs[dk][i]
    {
      f32x4 aS0 = {0,0,0,0}, aS1 = {0,0,0,0};
      #pragma unroll
      for (int ks=0; ks<2; ks++) {
        bf16x8 aDd = *(const bf16x8*)&lDT[fr*88 + fq*8 + ks*32];
        bf16x8 bK0 = *(const bf16x8*)&lKT[(w*32+fr)*72 + fq*8 + ks*32];
        bf16x8 bK1 = *(const bf16x8*)&lKT[(w*32+16+fr)*72 + fq*8 + ks*32];
        aS0 = MFMA16(aDd, bK0, aS0);
        aS1 = MFMA16(aDd, bK1, aS1);
      }
      #pragma unroll
      for (int r=0;r<4;r++) {
        lS[(fq*4+r)*129 + w*32 + fr]      += aS0[r];
        lS[(fq*4+r)*129 + w*32 + 16 + fr] += aS1[r];
      }
    }
    // global stores: Xq and D^T
    #pragma unroll
    for (int r=0;r<4;r++)
      gXq[((long)cd*CH + w*16+fq*4+r)*128 + dv0 + fr] = (bf16_t)aXq[r];
    {
      int dvl = t >> 4, off = (t & 15)*4;
      *(bf16x4*)(gD + ((long)cd*128 + dv0 + dvl)*64 + off) =
          *(const bf16x4*)&lDT[dvl*88 + off];
    }
    __syncthreads();   // C

    // write staged c+1 into LDS; cast lSb = bf16(lS)
    STAGE_WRITE();
    #pragma unroll
    for (int ib=0; ib<8; ib++) {
      int idx = t + ib*256; int r = idx>>7, cc = idx&127;
      lSb[r*136+cc] = (bf16_t)lS[r*129+cc];
    }
    __syncthreads();   // D
  }
#undef STAGE_LOAD
#undef STAGE_WRITE
}

// ---------------------------------------------------------------------------
// Phase O (parallel, per chunk): O = diag(p) Xq + Aq D  -> obuf
// ---------------------------------------------------------------------------
__global__ __launch_bounds__(256) void chunkO_kernel(
    const char* __restrict__ cdata, const bf16_t* __restrict__ gD,
    const bf16_t* __restrict__ gXq, bf16_t* __restrict__ obuf)
{
  const int cd = blockIdx.x;
  const int bh = cd >> 5, c = cd & 31;
  const int b = bh >> 4, h = bh & 15;
  const int t = threadIdx.x, lane = t & 63, w = t >> 6;
  const int fr = lane & 15, fq = lane >> 4;

  const char* cdp = cdata + (long)cd*CD_STRIDE;
  const bf16_t* aqp = (const bf16_t*)(cdp + CD_AQ);   // [64][64]
  const bf16_t* dp  = gD + (long)cd*128*64;           // [128 dv][64 t]
  const float*  pvp = (const float*)(cdp + CD_PV);

  f32x4 acc[8];
  #pragma unroll
  for (int tn=0;tn<8;tn++) acc[tn]=(f32x4){0,0,0,0};
  #pragma unroll
  for (int ks=0;ks<2;ks++) {
    bf16x8 aA = *(const bf16x8*)(aqp + (w*16+fr)*64 + fq*8 + ks*32);
    #pragma unroll
    for (int tn=0;tn<8;tn++) {
      bf16x8 bD = *(const bf16x8*)(dp + (tn*16+fr)*64 + fq*8 + ks*32);
      acc[tn] = MFMA16(aA, bD, acc[tn]);
    }
  }
  #pragma unroll
  for (int tn=0;tn<8;tn++)
    #pragma unroll
    for (int r=0;r<4;r++) {
      int tt = w*16+fq*4+r, dv = tn*16+fr;
      float ov = pvp[tt]*(float)gXq[((long)cd*CH + tt)*128 + dv] + acc[tn][r];
      obuf[((long)(b*SS + c*CH + tt)*HH + h)*128 + dv] = (bf16_t)ov;
    }
}

// ---------------------------------------------------------------------------
// RMSNorm over DV + (1+nw) + silu(z) gate; writes bf16 for final GEMM
// ---------------------------------------------------------------------------
__global__ __launch_bounds__(128) void norm_gate_kernel(
    const bf16_t* __restrict__ o, const bf16_t* __restrict__ z,
    const float* __restrict__ nw, bf16_t* __restrict__ og)
{
  const long row = blockIdx.x;      // (b*S+s)*H + h
  const int d = threadIdx.x;
  float x = (float)o[row*128 + d];
  float ss = x*x;
  #pragma unroll
  for (int off=32; off>=1; off>>=1) ss += __shfl_xor(ss, off);
  __shared__ float red[2];
  if ((d & 63) == 0) red[d>>6] = ss;
  __syncthreads();
  float mean = (red[0] + red[1]) * (1.f/128.f);
  float zn = (float)z[row*128 + d];
  float val = x * rsqrtf(mean + 1e-6f) * (1.f + nw[d]) * (zn * (1.f/(1.f+expf(-zn))));
  og[row*128 + d] = (bf16_t)val;
}

// ---------------------------------------------------------------------------
extern "C" void kernel_launch(void* const* d_in, const int* in_sizes, int n_in,
                              void* d_out, int out_size, void* d_ws, size_t ws_size,
                              hipStream_t stream)
{
  const float* hs    = (const float*)d_in[0];
  const float* amask = (const float*)d_in[1];
  const float* Wqkv  = (const float*)d_in[2];
  const float* convw = (const float*)d_in[3];
  const float* convb = (const float*)d_in[4];
  const float* Wz    = (const float*)d_in[5];
  const float* Wb    = (const float*)d_in[6];
  const float* Wa    = (const float*)d_in[7];
  const float* dtb   = (const float*)d_in[8];
  const float* Alog  = (const float*)d_in[9];
  const float* nw    = (const float*)d_in[10];
  const float* Wout  = (const float*)d_in[11];

  const size_t MB = 1024*1024;
  char* p = (char*)d_ws;
  auto alloc = [&](size_t bytes) { char* r = p; p += (bytes + 255) & ~(size_t)255; return r; };
  bf16_t* x_bf   = (bf16_t*)alloc(16*MB);   // x_bf; later gD [1024][128][64]
  char*   bigreg = alloc(72*MB);            // wqkv@0, mixed@24MB; later cdata@0, obuf@52MB
  bf16_t* wz_bf  = (bf16_t*)alloc(8*MB);    // Wz; later Wout
  bf16_t* zbuf   = (bf16_t*)alloc(16*MB);   // z; og in-place later
  bf16_t* q_t    = (bf16_t*)alloc(16*MB);
  bf16_t* k_t    = (bf16_t*)alloc(16*MB);
  bf16_t* v_t    = (bf16_t*)alloc(16*MB);   // v; later gXq [1024][64][128]
  float2* gb_t   = (float2*)alloc((size_t)BB*HH*SS*8);
  size_t need = (size_t)(p - (char*)d_ws);
  if (ws_size < need) return;   // clean fail (absmax = poison)

  bf16_t* wqkv_bf = (bf16_t*)bigreg;
  bf16_t* mixed   = (bf16_t*)(bigreg + 24*MB);
  char*   cdata   = bigreg;                       // after GEMM1+conv consumed
  bf16_t* obuf    = (bf16_t*)(bigreg + 52*MB);    // cdata ends at ~48.5MB
  bf16_t* wout_bf = wz_bf;                        // cast after z-GEMM
  bf16_t* gD      = x_bf;                         // after z-GEMM consumed x_bf
  bf16_t* gXq     = v_t;                          // after chunkA consumed v_t
  bf16_t* og      = zbuf;                         // in-place gate

  cast_x_kernel<<<2048, 256, 0, stream>>>(hs, amask, x_bf, (long)MM*DD);
  cast_w_kernel<<<2048, 256, 0, stream>>>(Wqkv, wqkv_bf, (long)CONVC*DD);
  cast_w_kernel<<<1024, 256, 0, stream>>>(Wz,   wz_bf,   (long)DD*DD);

  betag_kernel<<<MM, 64, 0, stream>>>(x_bf, Wb, Wa, dtb, Alog, gb_t);

  gemm_bt<true><<<dim3(32,48), 256, 0, stream>>>(x_bf, wqkv_bf, mixed, MM, CONVC, DD);

  conv_norm_kernel<<<BB*HH*SS, 128, 0, stream>>>(mixed, convw, convb, q_t, k_t, v_t);

  gemm_bt<true><<<dim3(32,16), 256, 0, stream>>>(x_bf, wz_bf, zbuf, MM, DD, DD);
  cast_w_kernel<<<1024, 256, 0, stream>>>(Wout, wout_bf, (long)DD*DD);

  chunkA_kernel<<<BB*HH*NCH, 256, 69888, stream>>>(q_t, k_t, v_t, gb_t, cdata);
  chunkS_kernel<<<BB*HH*8, 256, 80768, stream>>>(q_t, k_t, cdata, gD, gXq);
  chunkO_kernel<<<BB*HH*NCH, 256, 0, stream>>>(cdata, gD, gXq, obuf);

  norm_gate_kernel<<<MM*HH, 128, 0, stream>>>(obuf, zbuf, nw, og);

  gemm_bt<false><<<dim3(32,16), 256, 0, stream>>>(og, wout_bf, d_out, MM, DD, DD);
}

// Round 9
// 680.180 us; speedup vs baseline: 1.1937x; 1.0198x over previous
//
#include <hip/hip_runtime.h>
#include <hip/hip_bf16.h>
#include <math.h>

// Problem constants
#define BB 2
#define SS 2048
#define DD 2048
#define HH 16
#define CONVC 6144
#define MM (BB*SS)   // 4096 tokens

// chunked delta-rule constants
#define CH 64        // chunk length
#define NCH 32       // chunks per sequence
#define CD_KTS 0
#define CD_TV  16384
#define CD_TP  32768
#define CD_AQ  40960
#define CD_PV  49152
#define CD_PC  49408
#define CD_STRIDE 49664

typedef __bf16 bf16_t;
typedef __bf16 bf16x8 __attribute__((ext_vector_type(8)));
typedef __bf16 bf16x4 __attribute__((ext_vector_type(4)));
typedef float  f32x4  __attribute__((ext_vector_type(4)));

#define GLOBAL_AS __attribute__((address_space(1)))
#define LDS_AS    __attribute__((address_space(3)))

#define MFMA16(a,b,c) __builtin_amdgcn_mfma_f32_16x16x32_bf16((a),(b),(c),0,0,0)

// ---------------------------------------------------------------------------
// Cast kernels
// ---------------------------------------------------------------------------
__global__ __launch_bounds__(256) void cast_x_kernel(
    const float* __restrict__ in, const float* __restrict__ mask,
    bf16_t* __restrict__ out, long n)
{
  long n4 = n >> 2;
  for (long i = (long)blockIdx.x*256 + threadIdx.x; i < n4; i += (long)gridDim.x*256) {
    float4 v = ((const float4*)in)[i];
    float m = mask[(i*4) / DD];
    bf16x4 o4;
    o4[0]=(bf16_t)(v.x*m); o4[1]=(bf16_t)(v.y*m);
    o4[2]=(bf16_t)(v.z*m); o4[3]=(bf16_t)(v.w*m);
    ((bf16x4*)out)[i] = o4;
  }
}

__global__ __launch_bounds__(256) void cast_w_kernel(
    const float* __restrict__ in, bf16_t* __restrict__ out, long n)
{
  long n4 = n >> 2;
  for (long i = (long)blockIdx.x*256 + threadIdx.x; i < n4; i += (long)gridDim.x*256) {
    float4 v = ((const float4*)in)[i];
    bf16x4 o4;
    o4[0]=(bf16_t)v.x; o4[1]=(bf16_t)v.y; o4[2]=(bf16_t)v.z; o4[3]=(bf16_t)v.w;
    ((bf16x4*)out)[i] = o4;
  }
}

// ---------------------------------------------------------------------------
// 256x256 8-phase bf16 GEMM: C[M,N] = A[M,K] * B[N,K]^T
// BK=64, 512 threads (8 waves 2Mx4N), 128KiB LDS double-buffer.
// Per K-tile: 4 phases (kh0/m-lo, kh0/m-hi, kh1/m-lo, kh1/m-hi); each phase
// stages one half-tile (A-kh0,B-kh0,A-kh1,B-kh1) of tile kt+1 into buf^1.
// Counted vmcnt(4) at phases 0/2 only; raw s_barrier (no vmcnt drain).
// st_16x32 swizzle: linear gload_lds dest + inverse-swizzled global source +
// swizzled ds_read (same involution both sides).
// LDS layout per operand buffer: [kh(2)][subrow(16)][16][32] bf16 subtiles.
// ---------------------------------------------------------------------------
template<bool OUT_BF16>
__global__ __launch_bounds__(512) void gemm256(
    const bf16_t* __restrict__ A, const bf16_t* __restrict__ Bm,
    void* __restrict__ Cp, int M, int N, int K, int nbn)
{
  extern __shared__ char gsm[];   // A: buf0@0, buf1@32768; B: +65536
  const int t    = threadIdx.x;
  const int lane = t & 63;
  const int wid  = t >> 6;
  const int wm   = wid >> 2, wn = wid & 3;
  const int fr   = lane & 15, fq = lane >> 4;

  // XCD-aware swizzle (grid is a multiple of 8)
  const int nwg = gridDim.x;
  const int wg  = ((int)blockIdx.x & 7)*(nwg >> 3) + ((int)blockIdx.x >> 3);
  const long bm = wg / nbn, bn = wg % nbn;

  // staging decode: thread's 2 linear 16B chunks -> (row,col) via inverse swizzle
  int rowS[2], colS[2];
  #pragma unroll
  for (int i=0;i<2;i++) {
    int L  = (i*512 + t)*16;
    int Ls = L ^ (((L>>9)&1)<<5);
    rowS[i] = (Ls>>10)*16 + ((Ls&1023)>>6);
    colS[i] = (Ls&63)>>1;
  }
  const bf16_t* Ab = A  + (bm*256)*(long)K;
  const bf16_t* Bb = Bm + (bn*256)*(long)K;

  f32x4 acc[8][4];
  #pragma unroll
  for (int i=0;i<8;i++)
    #pragma unroll
    for (int j=0;j<4;j++) acc[i][j] = (f32x4){0.f,0.f,0.f,0.f};

  const int aoff = fr*64 + ((fq*16) ^ ((fr&8)<<2));  // swizzled frag byte offset

  auto stage = [&](int buf, int oper, int kh, int kt) {
    const bf16_t* srcb = oper ? Bb : Ab;
    char* dst0 = gsm + oper*65536 + buf*32768 + kh*16384 + t*16;
    #pragma unroll
    for (int i=0;i<2;i++) {
      const bf16_t* src = srcb + (long)rowS[i]*K + kt*64 + kh*32 + colS[i];
      __builtin_amdgcn_global_load_lds((const GLOBAL_AS void*)src,
          (LDS_AS void*)(dst0 + i*8192), 16, 0, 0);
    }
  };

  // prologue: stage tile 0 into buffer 0 (8 loads in canonical order)
  stage(0,0,0,0); stage(0,1,0,0); stage(0,0,1,0); stage(0,1,1,0);

  bf16x8 bfr[4];
  int cb = 0;
  const int KT = K >> 6;
  for (int kt=0; kt<KT; ++kt) {
    const int ktn = (kt+1 < KT) ? kt+1 : kt;
    const char* abuf = gsm + cb*32768;
    const char* bbuf = gsm + 65536 + cb*32768;
    bf16x8 af[4];

    // ---- phase 0: kh0, m-half 0 (reload B kh0 frags) ----
    asm volatile("s_waitcnt vmcnt(4)" ::: "memory");
    __builtin_amdgcn_sched_barrier(0);
    __builtin_amdgcn_s_barrier();
    #pragma unroll
    for (int j=0;j<4;j++)
      af[j] = *(const bf16x8*)(abuf + (wm*8+j)*1024 + aoff);
    #pragma unroll
    for (int n=0;n<4;n++)
      bfr[n] = *(const bf16x8*)(bbuf + (wn*4+n)*1024 + aoff);
    stage(cb^1, 0, 0, ktn);
    __builtin_amdgcn_s_setprio(1);
    #pragma unroll
    for (int j=0;j<4;j++)
      #pragma unroll
      for (int n=0;n<4;n++)
        acc[j][n] = MFMA16(af[j], bfr[n], acc[j][n]);
    __builtin_amdgcn_s_setprio(0);

    // ---- phase 1: kh0, m-half 1 ----
    __builtin_amdgcn_s_barrier();
    #pragma unroll
    for (int j=0;j<4;j++)
      af[j] = *(const bf16x8*)(abuf + (wm*8+4+j)*1024 + aoff);
    stage(cb^1, 1, 0, ktn);
    __builtin_amdgcn_s_setprio(1);
    #pragma unroll
    for (int j=0;j<4;j++)
      #pragma unroll
      for (int n=0;n<4;n++)
        acc[4+j][n] = MFMA16(af[j], bfr[n], acc[4+j][n]);
    __builtin_amdgcn_s_setprio(0);

    // ---- phase 2: kh1, m-half 0 (reload B kh1 frags) ----
    asm volatile("s_waitcnt vmcnt(4)" ::: "memory");
    __builtin_amdgcn_sched_barrier(0);
    __builtin_amdgcn_s_barrier();
    #pragma unroll
    for (int j=0;j<4;j++)
      af[j] = *(const bf16x8*)(abuf + 16384 + (wm*8+j)*1024 + aoff);
    #pragma unroll
    for (int n=0;n<4;n++)
      bfr[n] = *(const bf16x8*)(bbuf + 16384 + (wn*4+n)*1024 + aoff);
    stage(cb^1, 0, 1, ktn);
    __builtin_amdgcn_s_setprio(1);
    #pragma unroll
    for (int j=0;j<4;j++)
      #pragma unroll
      for (int n=0;n<4;n++)
        acc[j][n] = MFMA16(af[j], bfr[n], acc[j][n]);
    __builtin_amdgcn_s_setprio(0);

    // ---- phase 3: kh1, m-half 1 ----
    __builtin_amdgcn_s_barrier();
    #pragma unroll
    for (int j=0;j<4;j++)
      af[j] = *(const bf16x8*)(abuf + 16384 + (wm*8+4+j)*1024 + aoff);
    stage(cb^1, 1, 1, ktn);
    __builtin_amdgcn_s_setprio(1);
    #pragma unroll
    for (int j=0;j<4;j++)
      #pragma unroll
      for (int n=0;n<4;n++)
        acc[4+j][n] = MFMA16(af[j], bfr[n], acc[4+j][n]);
    __builtin_amdgcn_s_setprio(0);

    cb ^= 1;
  }
  __syncthreads();   // drain outstanding staging before exit

  #pragma unroll
  for (int mi=0;mi<8;mi++) {
    #pragma unroll
    for (int ni=0;ni<4;ni++) {
      long row = bm*256 + wm*128 + mi*16 + fq*4;
      long col = bn*256 + wn*64 + ni*16 + fr;
      #pragma unroll
      for (int r=0;r<4;r++) {
        float v = acc[mi][ni][r];
        if (OUT_BF16) ((bf16_t*)Cp)[(row+r)*(long)N + col] = (bf16_t)v;
        else          ((float*)Cp)[(row+r)*(long)N + col] = v;
      }
    }
  }
}

// ---------------------------------------------------------------------------
// beta / g:  per token, 16 dots with W_b rows and 16 with W_a rows (K=2048)
// writes gb_t[bh][s] = {g (log decay), beta}
// ---------------------------------------------------------------------------
__global__ __launch_bounds__(64) void betag_kernel(
    const bf16_t* __restrict__ xbf, const float* __restrict__ W_b,
    const float* __restrict__ W_a, const float* __restrict__ dt_bias,
    const float* __restrict__ A_log, float2* __restrict__ gb_t)
{
  const int row  = blockIdx.x;        // token b*S+s
  const int lane = threadIdx.x;
  const int b = row / SS, s = row % SS;

  float xv[32];
  {
    const bf16x8* xr = (const bf16x8*)(xbf + (long)row*DD + lane*32);
    #pragma unroll
    for (int c8=0;c8<4;c8++) {
      bf16x8 v = xr[c8];
      #pragma unroll
      for (int e=0;e<8;e++) xv[c8*8+e] = (float)v[e];
    }
  }

  for (int h=0; h<HH; ++h) {
    const float4* wb4 = (const float4*)(W_b + (long)h*DD + lane*32);
    const float4* wa4 = (const float4*)(W_a + (long)h*DD + lane*32);
    float pb = 0.f, pa = 0.f;
    #pragma unroll
    for (int c4=0;c4<8;c4++) {
      float4 wb = wb4[c4], wa = wa4[c4];
      pb += xv[c4*4+0]*wb.x + xv[c4*4+1]*wb.y + xv[c4*4+2]*wb.z + xv[c4*4+3]*wb.w;
      pa += xv[c4*4+0]*wa.x + xv[c4*4+1]*wa.y + xv[c4*4+2]*wa.z + xv[c4*4+3]*wa.w;
    }
    #pragma unroll
    for (int off=32; off>=1; off>>=1) { pb += __shfl_xor(pb, off); pa += __shfl_xor(pa, off); }
    if (lane == h) {
      float beta = 1.f/(1.f+expf(-pb));
      float tt = pa + dt_bias[h];
      float sp = (tt > 20.f) ? tt : log1pf(expf(tt));
      float g  = -expf(A_log[h]) * sp;
      gb_t[((long)b*HH + h)*SS + s] = make_float2(g, beta);
    }
  }
}

// ---------------------------------------------------------------------------
// conv(K=4 causal depthwise) + bias + silu + q/k l2norm + transpose to [B,H,S,128]
// ---------------------------------------------------------------------------
__global__ __launch_bounds__(128) void conv_norm_kernel(
    const bf16_t* __restrict__ mixed, const float* __restrict__ cw,
    const float* __restrict__ cb, bf16_t* __restrict__ q_t,
    bf16_t* __restrict__ k_t, bf16_t* __restrict__ v_t)
{
  const int blk = blockIdx.x;           // (b*H+h)*S + s
  const int s = blk & (SS-1);
  const int h = (blk >> 11) & (HH-1);
  const int b = blk >> 15;
  const int d = threadIdx.x;

  const int cq = h*128 + d;
  const int ck = 2048 + cq;
  const int cv = 4096 + cq;
  float aq = cb[cq], ak = cb[ck], av = cb[cv];
  const float* wq = cw + (long)cq*4;
  const float* wk = cw + (long)ck*4;
  const float* wv = cw + (long)cv*4;
  #pragma unroll
  for (int tp=0; tp<4; ++tp) {
    int s2 = s - 3 + tp;
    if (s2 >= 0) {
      const bf16_t* rowp = mixed + ((long)b*SS + s2)*CONVC;
      aq += (float)rowp[cq] * wq[tp];
      ak += (float)rowp[ck] * wk[tp];
      av += (float)rowp[cv] * wv[tp];
    }
  }
  aq = aq * (1.f/(1.f+expf(-aq)));
  ak = ak * (1.f/(1.f+expf(-ak)));
  av = av * (1.f/(1.f+expf(-av)));

  float sq = aq*aq, sk = ak*ak;
  #pragma unroll
  for (int off=32; off>=1; off>>=1) { sq += __shfl_xor(sq, off); sk += __shfl_xor(sk, off); }
  __shared__ float red[4];
  const int wv2 = d >> 6;
  if ((d & 63) == 0) { red[wv2*2] = sq; red[wv2*2+1] = sk; }
  __syncthreads();
  float sumq = red[0] + red[2];
  float sumk = red[1] + red[3];

  const long obase = ((long)(b*HH + h)*SS + s)*128 + d;
  q_t[obase] = (bf16_t)(aq * rsqrtf(sumq + 1e-6f) * 0.08838834764831845f);  // * DK^-0.5
  k_t[obase] = (bf16_t)(ak * rsqrtf(sumk + 1e-6f));
  v_t[obase] = (bf16_t)av;
}

// ---------------------------------------------------------------------------
// Phase A (per bh,chunk): build Tp/Aq/TV/KTs/pv/PC into cdata.
// ---------------------------------------------------------------------------
__global__ __launch_bounds__(256) void chunkA_kernel(
    const bf16_t* __restrict__ q_t, const bf16_t* __restrict__ k_t,
    const bf16_t* __restrict__ v_t, const float2* __restrict__ gb_t,
    char* __restrict__ cdata)
{
  extern __shared__ char smem[];
  bf16_t* lK  = (bf16_t*)(smem);            // [64][136]
  bf16_t* lQV = (bf16_t*)(smem + 17408);    // lQ [64][136], later lVT [128][72]
  float*  lLf = (float*)(smem + 35840);     // [64][65]
  float*  lXf = (float*)(smem + 52480);     // [64][65]
  float*  gcv = (float*)(smem + 69120);     // [64]
  float*  pvv = (float*)(smem + 69376);     // [64]
  float*  bvv = (float*)(smem + 69632);     // [64]

  const int cd = blockIdx.x;
  const int bh = cd >> 5, c = cd & 31;
  const int t = threadIdx.x;
  const int lane = t & 63, w = t >> 6;
  const int fr = lane & 15, fq = lane >> 4;

  const bf16_t* kg = k_t + ((long)bh*SS + c*CH)*128;
  const bf16_t* qg = q_t + ((long)bh*SS + c*CH)*128;
  const bf16_t* vg = v_t + ((long)bh*SS + c*CH)*128;
  char* cdp = cdata + (long)cd*CD_STRIDE;

  // stage K, Q (lQV as lQ)
  #pragma unroll
  for (int ib=0; ib<4; ib++) {
    int e0 = (t + 256*ib)*8;
    int r = e0 >> 7, cc = e0 & 127;
    *(bf16x8*)&lK[r*136+cc]  = *(const bf16x8*)(kg + e0);
    *(bf16x8*)&lQV[r*136+cc] = *(const bf16x8*)(qg + e0);
  }
  if (t < 64) {
    float2 gb = gb_t[(long)bh*SS + c*CH + t];
    gcv[t] = gb.x;
    bvv[t] = gb.y;
  }
  __syncthreads();
  // wave-parallel inclusive scan of gcv (wave 0)
  if (t < 64) {
    float g = gcv[t];
    #pragma unroll
    for (int off=1; off<64; off<<=1) {
      float n = __shfl_up(g, off);
      if (lane >= off) g += n;
    }
    gcv[t] = g;
  }
  __syncthreads();
  if (t < 64) pvv[t] = expf(gcv[t]);

  // G = K K^T, Gq = Q K^T  (wave strip rows 16w)
  {
    f32x4 accG[4], accQ[4];
    #pragma unroll
    for (int tn=0;tn<4;tn++){ accG[tn]=(f32x4){0,0,0,0}; accQ[tn]=(f32x4){0,0,0,0}; }
    #pragma unroll
    for (int ks=0;ks<4;ks++) {
      bf16x8 aK = *(const bf16x8*)&lK[(w*16+fr)*136 + fq*8 + ks*32];
      bf16x8 aQ = *(const bf16x8*)&lQV[(w*16+fr)*136 + fq*8 + ks*32];
      #pragma unroll
      for (int tn=0;tn<4;tn++) {
        bf16x8 bK = *(const bf16x8*)&lK[(tn*16+fr)*136 + fq*8 + ks*32];
        accG[tn] = MFMA16(aK, bK, accG[tn]);
        accQ[tn] = MFMA16(aQ, bK, accQ[tn]);
      }
    }
    bf16_t* aqg = (bf16_t*)(cdp + CD_AQ);
    #pragma unroll
    for (int tn=0;tn<4;tn++) {
      #pragma unroll
      for (int r=0;r<4;r++) {
        int tt = w*16 + fq*4 + r;
        int ii = tn*16 + fr;
        float er = expf(gcv[tt] - gcv[ii]);
        lLf[tt*65 + ii] = (ii < tt) ? bvv[tt]*er*accG[tn][r] : 0.f;
        aqg[tt*64 + ii] = (bf16_t)((ii <= tt) ? er*accQ[tn][r] : 0.f);
      }
    }
  }
  #pragma unroll
  for (int ib=0; ib<16; ib++) {
    int idx = t + ib*256; int r = idx>>6, cc = idx&63;
    lXf[r*65+cc] = (r==cc) ? bvv[r] : 0.f;
  }
  __syncthreads();   // lLf/lXf ready; lQ reads done -> reuse as lVT

  // stage V^T into lQV with staggered element order (kills 16-way conflicts)
  bf16_t* lVT = lQV;   // [128][72]
  {
    const int m = t & 15;
    #pragma unroll
    for (int ib=0; ib<4; ib++) {
      int e0 = (t + 256*ib)*8;
      int r = e0 >> 7, cc = e0 & 127;
      bf16x8 v8 = *(const bf16x8*)(vg + e0);
      #pragma unroll
      for (int e=0;e<8;e++) {
        int ee = (e + m) & 7;
        lVT[(cc+ee)*72 + r] = v8[ee];
      }
    }
  }

  // forward elimination: X[t] -= Lf[t][i] * X[i]
  {
    const int jj = t & 63, rg = t >> 6;
    for (int i=0; i<CH-1; i++) {
      float xi = lXf[i*65 + jj];
      for (int tr = i+1+rg; tr < CH; tr += 4)
        lXf[tr*65 + jj] = fmaf(-lLf[tr*65 + i], xi, lXf[tr*65 + jj]);
      __syncthreads();
    }
  }

  // Tp store + bf16 copy of Tmat (reuse lLf region)
  bf16_t* lXb = (bf16_t*)lLf;   // [64][72]
  {
    bf16_t* tpg = (bf16_t*)(cdp + CD_TP);
    #pragma unroll
    for (int ib=0; ib<16; ib++) {
      int idx = t + ib*256; int r = idx>>6, cc = idx&63;
      float xv = lXf[r*65+cc];
      tpg[r*64+cc] = (bf16_t)(xv * pvv[cc]);
      lXb[r*72+cc] = (bf16_t)xv;
    }
  }
  __syncthreads();

  // TV = Tmat @ V : C[t][dv] = sum_i Xb[t][i] * VT[dv][i]
  {
    f32x4 acc[8];
    #pragma unroll
    for (int tn=0;tn<8;tn++) acc[tn]=(f32x4){0,0,0,0};
    #pragma unroll
    for (int ks=0;ks<2;ks++) {
      bf16x8 aX = *(const bf16x8*)&lXb[(w*16+fr)*72 + fq*8 + ks*32];
      #pragma unroll
      for (int tn=0;tn<8;tn++) {
        bf16x8 bV = *(const bf16x8*)&lVT[(tn*16+fr)*72 + fq*8 + ks*32];
        acc[tn] = MFMA16(aX, bV, acc[tn]);
      }
    }
    bf16_t* tvg = (bf16_t*)(cdp + CD_TV);
    #pragma unroll
    for (int tn=0;tn<8;tn++)
      #pragma unroll
      for (int r=0;r<4;r++) {
        int tt = w*16 + fq*4 + r, dv = tn*16 + fr;
        tvg[tt*128 + dv] = (bf16_t)acc[tn][r];
      }
  }

  // KTs[dk][i] = K[i][dk] * exp(gc_C - gc_i)
  {
    bf16_t* ktg = (bf16_t*)(cdp + CD_KTS);
    int dk = t >> 1, c0 = (t & 1)*32;
    float g63 = gcv[63];
    bf16_t tmp[32];
    #pragma unroll
    for (int i2=0;i2<32;i2++) {
      int i = c0 + i2;
      tmp[i2] = (bf16_t)((float)lK[i*136 + dk] * expf(g63 - gcv[i]));
    }
    #pragma unroll
    for (int s8=0;s8<4;s8++)
      *(bf16x8*)&ktg[dk*64 + c0 + s8*8] = *(bf16x8*)&tmp[s8*8];
  }
  if (t < 64) ((float*)(cdp + CD_PV))[t] = pvv[t];
  if (t == 0) *((float*)(cdp + CD_PC)) = expf(gcv[63]);
}

// ---------------------------------------------------------------------------
// Phase S (serial over 32 chunks; 256 blocks = 32 bh x 8 dv-splits of 16):
//   X=K S; Xq=Q S (store); D = TV - Tp X (store D^T); S = PC*S + KTs D
// Pipelined: chunk c+1's K/Q/Tp/KTs loaded to regs at top of chunk c,
// written to LDS in the tail phase (staging off the serial path).
// ---------------------------------------------------------------------------
__global__ __launch_bounds__(256) void chunkS_kernel(
    const bf16_t* __restrict__ q_t, const bf16_t* __restrict__ k_t,
    const char* __restrict__ cdata, bf16_t* __restrict__ gD,
    bf16_t* __restrict__ gXq)
{
  extern __shared__ char smem[];
  float*  lS  = (float*)(smem);              // [16][129] f32  S^T slice [dv][dk]
  bf16_t* lSb = (bf16_t*)(smem + 8320);      // [16][136] bf16
  bf16_t* lK  = (bf16_t*)(smem + 12672);     // [64][136]
  bf16_t* lQ  = (bf16_t*)(smem + 30080);     // [64][136]
  bf16_t* lTp = (bf16_t*)(smem + 47488);     // [64][72]
  bf16_t* lKT = (bf16_t*)(smem + 56704);     // [128][72]
  bf16_t* lXT = (bf16_t*)(smem + 75136);     // [16][88]  X^T [dv][t]
  bf16_t* lDT = (bf16_t*)(smem + 77952);     // [16][88]  D^T [dv][t]

  const int bid = blockIdx.x;
  const int lb  = (bid & 7)*32 + (bid >> 3);   // same-bh blocks on one XCD
  const int bh = lb >> 3, sp = lb & 7;
  const int dv0 = sp*16;
  const int t = threadIdx.x, lane = t & 63, w = t >> 6;
  const int fr = lane & 15, fq = lane >> 4;

  #pragma unroll
  for (int ib=0; ib<8; ib++) {
    int idx = t + ib*256; int r = idx>>7, cc = idx&127;
    lS[r*129+cc] = 0.f;
    lSb[r*136+cc] = (bf16_t)0.f;
  }

  const bf16_t* kg = k_t + (long)bh*SS*128;
  const bf16_t* qg = q_t + (long)bh*SS*128;

  bf16x8 kr0,kr1,kr2,kr3, qr0,qr1,qr2,qr3, kt0,kt1,kt2,kt3, tp0,tp1;

#define STAGE_LOAD(CSRC)                                                       \
  {                                                                            \
    const char* cdl = cdata + (long)(bh*NCH + (CSRC))*CD_STRIDE;               \
    const bf16_t* kl = kg + (long)(CSRC)*CH*128;                               \
    const bf16_t* ql = qg + (long)(CSRC)*CH*128;                               \
    const bf16_t* ktl = (const bf16_t*)(cdl + CD_KTS);                         \
    const bf16_t* tpl = (const bf16_t*)(cdl + CD_TP);                          \
    int e0 = t*8, e1 = (t+256)*8, e2 = (t+512)*8, e3 = (t+768)*8;              \
    kr0 = *(const bf16x8*)(kl + e0); kr1 = *(const bf16x8*)(kl + e1);          \
    kr2 = *(const bf16x8*)(kl + e2); kr3 = *(const bf16x8*)(kl + e3);          \
    qr0 = *(const bf16x8*)(ql + e0); qr1 = *(const bf16x8*)(ql + e1);          \
    qr2 = *(const bf16x8*)(ql + e2); qr3 = *(const bf16x8*)(ql + e3);          \
    kt0 = *(const bf16x8*)(ktl + e0); kt1 = *(const bf16x8*)(ktl + e1);        \
    kt2 = *(const bf16x8*)(ktl + e2); kt3 = *(const bf16x8*)(ktl + e3);        \
    tp0 = *(const bf16x8*)(tpl + e0); tp1 = *(const bf16x8*)(tpl + e1);        \
  }

#define STAGE_WRITE()                                                          \
  {                                                                            \
    int e0 = t*8, e1 = (t+256)*8, e2 = (t+512)*8, e3 = (t+768)*8;              \
    *(bf16x8*)&lK[(e0>>7)*136 + (e0&127)] = kr0;                               \
    *(bf16x8*)&lK[(e1>>7)*136 + (e1&127)] = kr1;                               \
    *(bf16x8*)&lK[(e2>>7)*136 + (e2&127)] = kr2;                               \
    *(bf16x8*)&lK[(e3>>7)*136 + (e3&127)] = kr3;                               \
    *(bf16x8*)&lQ[(e0>>7)*136 + (e0&127)] = qr0;                               \
    *(bf16x8*)&lQ[(e1>>7)*136 + (e1&127)] = qr1;                               \
    *(bf16x8*)&lQ[(e2>>7)*136 + (e2&127)] = qr2;                               \
    *(bf16x8*)&lQ[(e3>>7)*136 + (e3&127)] = qr3;                               \
    *(bf16x8*)&lKT[(e0>>6)*72 + (e0&63)] = kt0;                                \
    *(bf16x8*)&lKT[(e1>>6)*72 + (e1&63)] = kt1;                                \
    *(bf16x8*)&lKT[(e2>>6)*72 + (e2&63)] = kt2;                                \
    *(bf16x8*)&lKT[(e3>>6)*72 + (e3&63)] = kt3;                                \
    *(bf16x8*)&lTp[(e0>>6)*72 + (e0&63)] = tp0;                                \
    *(bf16x8*)&lTp[(e1>>6)*72 + (e1&63)] = tp1;                                \
  }

  STAGE_LOAD(0);
  STAGE_WRITE();
  __syncthreads();

  for (int c=0; c<NCH; c++) {
    const int cd = bh*NCH + c;
    const char* cdp = cdata + (long)cd*CD_STRIDE;

    // TV quad + PC for current chunk (issued FIRST so their wait doesn't
    // drain the prefetch queue)
    float tvq0, tvq1, tvq2, tvq3, pc;
    {
      const bf16_t* tvp = (const bf16_t*)(cdp + CD_TV);
      tvq0 = (float)tvp[(w*16+fq*4+0)*128 + dv0 + fr];
      tvq1 = (float)tvp[(w*16+fq*4+1)*128 + dv0 + fr];
      tvq2 = (float)tvp[(w*16+fq*4+2)*128 + dv0 + fr];
      tvq3 = (float)tvp[(w*16+fq*4+3)*128 + dv0 + fr];
      pc = *(const float*)(cdp + CD_PC);
    }
    // issue prefetch of chunk c+1 (clamped) into regs
    const int cn = (c+1 < NCH) ? c+1 : c;
    STAGE_LOAD(cn);

    // X = K S^T-slice, Xq = Q S^T-slice  (M=64, N=16, K=128)
    f32x4 aX = {0,0,0,0}, aXq = {0,0,0,0};
    #pragma unroll
    for (int ks=0; ks<4; ks++) {
      bf16x8 bS = *(const bf16x8*)&lSb[fr*136 + fq*8 + ks*32];
      bf16x8 aK = *(const bf16x8*)&lK[(w*16+fr)*136 + fq*8 + ks*32];
      bf16x8 aQ = *(const bf16x8*)&lQ[(w*16+fr)*136 + fq*8 + ks*32];
      aX  = MFMA16(aK, bS, aX);
      aXq = MFMA16(aQ, bS, aXq);
    }
    #pragma unroll
    for (int r=0;r<4;r++)
      lXT[fr*88 + (w*16+fq*4+r)] = (bf16_t)aX[r];
    __syncthreads();   // A

    // D = TV - Tp X  (M=64, N=16, K=64); also scale lS by PC
    {
      f32x4 aD = {0,0,0,0};
      #pragma unroll
      for (int ks=0; ks<2; ks++) {
        bf16x8 aT = *(const bf16x8*)&lTp[(w*16+fr)*72 + fq*8 + ks*32];
        bf16x8 bX = *(const bf16x8*)&lXT[fr*88 + fq*8 + ks*32];
        aD = MFMA16(aT, bX, aD);
      }
      lDT[fr*88 + (w*16+fq*4+0)] = (bf16_t)(tvq0 - aD[0]);
      lDT[fr*88 + (w*16+fq*4+1)] = (bf16_t)(tvq1 - aD[1]);
      lDT[fr*88 + (w*16+fq*4+2)] = (bf16_t)(tvq2 - aD[2]);
      lDT[fr*88 + (w*16+fq*4+3)] = (bf16_t)(tvq3 - aD[3]);
    }
    #pragma unroll
    for (int ib=0; ib<8; ib++) {
      int idx = t + ib*256; int r = idx>>7, cc = idx&127;
      lS[r*129+cc] *= pc;
    }
    __syncthreads();   // B

    // S^T += D^T KTs^T : C[dv][dk] = sum_i D^T[dv][i]*KTs[dk][i]
    {
      f32x4 aS0 = {0,0,0,0}, aS1 = {0,0,0,0};
      #pragma unroll
      for (int ks=0; ks<2; ks++) {
        bf16x8 aDd = *(const bf16x8*)&lDT[fr*88 + fq*8 + ks*32];
        bf16x8 bK0 = *(const bf16x8*)&lKT[(w*32+fr)*72 + fq*8 + ks*32];
        bf16x8 bK1 = *(const bf16x8*)&lKT[(w*32+16+fr)*72 + fq*8 + ks*32];
        aS0 = MFMA16(aDd, bK0, aS0);
        aS1 = MFMA16(aDd, bK1, aS1);
      }
      #pragma unroll
      for (int r=0;r<4;r++) {
        lS[(fq*4+r)*129 + w*32 + fr]      += aS0[r];
        lS[(fq*4+r)*129 + w*32 + 16 + fr] += aS1[r];
      }
    }
    // global stores: Xq and D^T
    #pragma unroll
    for (int r=0;r<4;r++)
      gXq[((long)cd*CH + w*16+fq*4+r)*128 + dv0 + fr] = (bf16_t)aXq[r];
    {
      int dvl = t >> 4, off = (t & 15)*4;
      *(bf16x4*)(gD + ((long)cd*128 + dv0 + dvl)*64 + off) =
          *(const bf16x4*)&lDT[dvl*88 + off];
    }
    __syncthreads();   // C

    // write staged c+1 into LDS; cast lSb = bf16(lS)
    STAGE_WRITE();
    #pragma unroll
    for (int ib=0; ib<8; ib++) {
      int idx = t + ib*256; int r = idx>>7, cc = idx&127;
      lSb[r*136+cc] = (bf16_t)lS[r*129+cc];
    }
    __syncthreads();   // D
  }
#undef STAGE_LOAD
#undef STAGE_WRITE
}

// ---------------------------------------------------------------------------
// Phase O (parallel, per chunk): O = diag(p) Xq + Aq D  -> obuf
// ---------------------------------------------------------------------------
__global__ __launch_bounds__(256) void chunkO_kernel(
    const char* __restrict__ cdata, const bf16_t* __restrict__ gD,
    const bf16_t* __restrict__ gXq, bf16_t* __restrict__ obuf)
{
  const int cd = blockIdx.x;
  const int bh = cd >> 5, c = cd & 31;
  const int b = bh >> 4, h = bh & 15;
  const int t = threadIdx.x, lane = t & 63, w = t >> 6;
  const int fr = lane & 15, fq = lane >> 4;

  const char* cdp = cdata + (long)cd*CD_STRIDE;
  const bf16_t* aqp = (const bf16_t*)(cdp + CD_AQ);   // [64][64]
  const bf16_t* dp  = gD + (long)cd*128*64;           // [128 dv][64 t]
  const float*  pvp = (const float*)(cdp + CD_PV);

  f32x4 acc[8];
  #pragma unroll
  for (int tn=0;tn<8;tn++) acc[tn]=(f32x4){0,0,0,0};
  #pragma unroll
  for (int ks=0;ks<2;ks++) {
    bf16x8 aA = *(const bf16x8*)(aqp + (w*16+fr)*64 + fq*8 + ks*32);
    #pragma unroll
    for (int tn=0;tn<8;tn++) {
      bf16x8 bD = *(const bf16x8*)(dp + (tn*16+fr)*64 + fq*8 + ks*32);
      acc[tn] = MFMA16(aA, bD, acc[tn]);
    }
  }
  #pragma unroll
  for (int tn=0;tn<8;tn++)
    #pragma unroll
    for (int r=0;r<4;r++) {
      int tt = w*16+fq*4+r, dv = tn*16+fr;
      float ov = pvp[tt]*(float)gXq[((long)cd*CH + tt)*128 + dv] + acc[tn][r];
      obuf[((long)(b*SS + c*CH + tt)*HH + h)*128 + dv] = (bf16_t)ov;
    }
}

// ---------------------------------------------------------------------------
// RMSNorm over DV + (1+nw) + silu(z) gate; writes bf16 for final GEMM
// ---------------------------------------------------------------------------
__global__ __launch_bounds__(128) void norm_gate_kernel(
    const bf16_t* __restrict__ o, const bf16_t* __restrict__ z,
    const float* __restrict__ nw, bf16_t* __restrict__ og)
{
  const long row = blockIdx.x;      // (b*S+s)*H + h
  const int d = threadIdx.x;
  float x = (float)o[row*128 + d];
  float ss = x*x;
  #pragma unroll
  for (int off=32; off>=1; off>>=1) ss += __shfl_xor(ss, off);
  __shared__ float red[2];
  if ((d & 63) == 0) red[d>>6] = ss;
  __syncthreads();
  float mean = (red[0] + red[1]) * (1.f/128.f);
  float zn = (float)z[row*128 + d];
  float val = x * rsqrtf(mean + 1e-6f) * (1.f + nw[d]) * (zn * (1.f/(1.f+expf(-zn))));
  og[row*128 + d] = (bf16_t)val;
}

// ---------------------------------------------------------------------------
extern "C" void kernel_launch(void* const* d_in, const int* in_sizes, int n_in,
                              void* d_out, int out_size, void* d_ws, size_t ws_size,
                              hipStream_t stream)
{
  const float* hs    = (const float*)d_in[0];
  const float* amask = (const float*)d_in[1];
  const float* Wqkv  = (const float*)d_in[2];
  const float* convw = (const float*)d_in[3];
  const float* convb = (const float*)d_in[4];
  const float* Wz    = (const float*)d_in[5];
  const float* Wb    = (const float*)d_in[6];
  const float* Wa    = (const float*)d_in[7];
  const float* dtb   = (const float*)d_in[8];
  const float* Alog  = (const float*)d_in[9];
  const float* nw    = (const float*)d_in[10];
  const float* Wout  = (const float*)d_in[11];

  const size_t MB = 1024*1024;
  char* p = (char*)d_ws;
  auto alloc = [&](size_t bytes) { char* r = p; p += (bytes + 255) & ~(size_t)255; return r; };
  bf16_t* x_bf   = (bf16_t*)alloc(16*MB);   // x_bf; later gD [1024][128][64]
  char*   bigreg = alloc(72*MB);            // wqkv@0, mixed@24MB; later cdata@0, obuf@52MB
  bf16_t* wz_bf  = (bf16_t*)alloc(8*MB);    // Wz; later Wout
  bf16_t* zbuf   = (bf16_t*)alloc(16*MB);   // z; og in-place later
  bf16_t* q_t    = (bf16_t*)alloc(16*MB);
  bf16_t* k_t    = (bf16_t*)alloc(16*MB);
  bf16_t* v_t    = (bf16_t*)alloc(16*MB);   // v; later gXq [1024][64][128]
  float2* gb_t   = (float2*)alloc((size_t)BB*HH*SS*8);
  size_t need = (size_t)(p - (char*)d_ws);
  if (ws_size < need) return;   // clean fail (absmax = poison)

  bf16_t* wqkv_bf = (bf16_t*)bigreg;
  bf16_t* mixed   = (bf16_t*)(bigreg + 24*MB);
  char*   cdata   = bigreg;                       // after GEMM1+conv consumed
  bf16_t* obuf    = (bf16_t*)(bigreg + 52*MB);    // cdata ends at ~48.5MB
  bf16_t* wout_bf = wz_bf;                        // cast after z-GEMM
  bf16_t* gD      = x_bf;                         // after z-GEMM consumed x_bf
  bf16_t* gXq     = v_t;                          // after chunkA consumed v_t
  bf16_t* og      = zbuf;                         // in-place gate

  cast_x_kernel<<<2048, 256, 0, stream>>>(hs, amask, x_bf, (long)MM*DD);
  cast_w_kernel<<<2048, 256, 0, stream>>>(Wqkv, wqkv_bf, (long)CONVC*DD);
  cast_w_kernel<<<1024, 256, 0, stream>>>(Wz,   wz_bf,   (long)DD*DD);

  betag_kernel<<<MM, 64, 0, stream>>>(x_bf, Wb, Wa, dtb, Alog, gb_t);

  gemm256<true><<<384, 512, 131072, stream>>>(x_bf, wqkv_bf, mixed, MM, CONVC, DD, 24);

  conv_norm_kernel<<<BB*HH*SS, 128, 0, stream>>>(mixed, convw, convb, q_t, k_t, v_t);

  gemm256<true><<<128, 512, 131072, stream>>>(x_bf, wz_bf, zbuf, MM, DD, DD, 8);
  cast_w_kernel<<<1024, 256, 0, stream>>>(Wout, wout_bf, (long)DD*DD);

  chunkA_kernel<<<BB*HH*NCH, 256, 69888, stream>>>(q_t, k_t, v_t, gb_t, cdata);
  chunkS_kernel<<<BB*HH*8, 256, 80768, stream>>>(q_t, k_t, cdata, gD, gXq);
  chunkO_kernel<<<BB*HH*NCH, 256, 0, stream>>>(cdata, gD, gXq, obuf);

  norm_gate_kernel<<<MM*HH, 128, 0, stream>>>(obuf, zbuf, nw, og);

  gemm256<false><<<128, 512, 131072, stream>>>(og, wout_bf, d_out, MM, DD, DD, 8);
}

// Round 10
// 571.918 us; speedup vs baseline: 1.4197x; 1.1893x over previous
//
#include <hip/hip_runtime.h>
#include <hip/hip_bf16.h>
#include <math.h>

// Problem constants
#define BB 2
#define SS 2048
#define DD 2048
#define HH 16
#define CONVC 6144
#define MM (BB*SS)   // 4096 tokens
#define ZN 2304      // z-GEMM N: 2048 z cols + 16 W_b + 16 W_a + 224 pad

// chunked delta-rule constants
#define CH 64        // chunk length
#define NCH 32       // chunks per sequence
#define CD_KTS 0
#define CD_TV  16384
#define CD_TP  32768
#define CD_AQ  40960
#define CD_PV  49152
#define CD_PC  49408
#define CD_STRIDE 49664

typedef __bf16 bf16_t;
typedef __bf16 bf16x8 __attribute__((ext_vector_type(8)));
typedef __bf16 bf16x4 __attribute__((ext_vector_type(4)));
typedef float  f32x4  __attribute__((ext_vector_type(4)));

#define GLOBAL_AS __attribute__((address_space(1)))
#define LDS_AS    __attribute__((address_space(3)))

#define MFMA16(a,b,c) __builtin_amdgcn_mfma_f32_16x16x32_bf16((a),(b),(c),0,0,0)

// ---------------------------------------------------------------------------
// Cast kernels
// ---------------------------------------------------------------------------
__global__ __launch_bounds__(256) void cast_x_kernel(
    const float* __restrict__ in, const float* __restrict__ mask,
    bf16_t* __restrict__ out, long n)
{
  long n4 = n >> 2;
  for (long i = (long)blockIdx.x*256 + threadIdx.x; i < n4; i += (long)gridDim.x*256) {
    float4 v = ((const float4*)in)[i];
    float m = mask[(i*4) / DD];
    bf16x4 o4;
    o4[0]=(bf16_t)(v.x*m); o4[1]=(bf16_t)(v.y*m);
    o4[2]=(bf16_t)(v.z*m); o4[3]=(bf16_t)(v.w*m);
    ((bf16x4*)out)[i] = o4;
  }
}

__global__ __launch_bounds__(256) void cast_w_kernel(
    const float* __restrict__ in, bf16_t* __restrict__ out, long n)
{
  long n4 = n >> 2;
  for (long i = (long)blockIdx.x*256 + threadIdx.x; i < n4; i += (long)gridDim.x*256) {
    float4 v = ((const float4*)in)[i];
    bf16x4 o4;
    o4[0]=(bf16_t)v.x; o4[1]=(bf16_t)v.y; o4[2]=(bf16_t)v.z; o4[3]=(bf16_t)v.w;
    ((bf16x4*)out)[i] = o4;
  }
}

// append W_b (16x2048) then W_a (16x2048) as bf16 rows after the Wz rows
__global__ __launch_bounds__(256) void cast_ba_kernel(
    const float* __restrict__ Wb, const float* __restrict__ Wa,
    bf16_t* __restrict__ out)   // out = wz_bf + 2048*2048
{
  int i = blockIdx.x*256 + threadIdx.x;   // 16384 threads, 4 elems each
  int j = i*4;
  const float* src = (j < 32768) ? (Wb + j) : (Wa + j - 32768);
  float4 v = *(const float4*)src;
  bf16x4 o4;
  o4[0]=(bf16_t)v.x; o4[1]=(bf16_t)v.y; o4[2]=(bf16_t)v.z; o4[3]=(bf16_t)v.w;
  *(bf16x4*)(out + j) = o4;
}

// ---------------------------------------------------------------------------
// 256x256 8-phase bf16 GEMM: C[M,N] = A[M,K] * B[N,K]^T   (T2+T3+T4+T5)
// ---------------------------------------------------------------------------
template<bool OUT_BF16>
__global__ __launch_bounds__(512) void gemm256(
    const bf16_t* __restrict__ A, const bf16_t* __restrict__ Bm,
    void* __restrict__ Cp, int M, int N, int K, int nbn)
{
  extern __shared__ char gsm[];   // A: buf0@0, buf1@32768; B: +65536
  const int t    = threadIdx.x;
  const int lane = t & 63;
  const int wid  = t >> 6;
  const int wm   = wid >> 2, wn = wid & 3;
  const int fr   = lane & 15, fq = lane >> 4;

  // XCD-aware swizzle (grid is a multiple of 8)
  const int nwg = gridDim.x;
  const int wg  = ((int)blockIdx.x & 7)*(nwg >> 3) + ((int)blockIdx.x >> 3);
  const long bm = wg / nbn, bn = wg % nbn;

  // staging decode: thread's 2 linear 16B chunks -> (row,col) via inverse swizzle
  int rowS[2], colS[2];
  #pragma unroll
  for (int i=0;i<2;i++) {
    int L  = (i*512 + t)*16;
    int Ls = L ^ (((L>>9)&1)<<5);
    rowS[i] = (Ls>>10)*16 + ((Ls&1023)>>6);
    colS[i] = (Ls&63)>>1;
  }
  const bf16_t* Ab = A  + (bm*256)*(long)K;
  const bf16_t* Bb = Bm + (bn*256)*(long)K;

  f32x4 acc[8][4];
  #pragma unroll
  for (int i=0;i<8;i++)
    #pragma unroll
    for (int j=0;j<4;j++) acc[i][j] = (f32x4){0.f,0.f,0.f,0.f};

  const int aoff = fr*64 + ((fq*16) ^ ((fr&8)<<2));  // swizzled frag byte offset

  auto stage = [&](int buf, int oper, int kh, int kt) {
    const bf16_t* srcb = oper ? Bb : Ab;
    char* dst0 = gsm + oper*65536 + buf*32768 + kh*16384 + t*16;
    #pragma unroll
    for (int i=0;i<2;i++) {
      const bf16_t* src = srcb + (long)rowS[i]*K + kt*64 + kh*32 + colS[i];
      __builtin_amdgcn_global_load_lds((const GLOBAL_AS void*)src,
          (LDS_AS void*)(dst0 + i*8192), 16, 0, 0);
    }
  };

  // prologue: stage tile 0 into buffer 0
  stage(0,0,0,0); stage(0,1,0,0); stage(0,0,1,0); stage(0,1,1,0);

  bf16x8 bfr[4];
  int cb = 0;
  const int KT = K >> 6;
  for (int kt=0; kt<KT; ++kt) {
    const int ktn = (kt+1 < KT) ? kt+1 : kt;
    const char* abuf = gsm + cb*32768;
    const char* bbuf = gsm + 65536 + cb*32768;
    bf16x8 af[4];

    // ---- phase 0: kh0, m-half 0 ----
    asm volatile("s_waitcnt vmcnt(4)" ::: "memory");
    __builtin_amdgcn_sched_barrier(0);
    __builtin_amdgcn_s_barrier();
    #pragma unroll
    for (int j=0;j<4;j++)
      af[j] = *(const bf16x8*)(abuf + (wm*8+j)*1024 + aoff);
    #pragma unroll
    for (int n=0;n<4;n++)
      bfr[n] = *(const bf16x8*)(bbuf + (wn*4+n)*1024 + aoff);
    stage(cb^1, 0, 0, ktn);
    __builtin_amdgcn_s_setprio(1);
    #pragma unroll
    for (int j=0;j<4;j++)
      #pragma unroll
      for (int n=0;n<4;n++)
        acc[j][n] = MFMA16(af[j], bfr[n], acc[j][n]);
    __builtin_amdgcn_s_setprio(0);

    // ---- phase 1: kh0, m-half 1 ----
    __builtin_amdgcn_s_barrier();
    #pragma unroll
    for (int j=0;j<4;j++)
      af[j] = *(const bf16x8*)(abuf + (wm*8+4+j)*1024 + aoff);
    stage(cb^1, 1, 0, ktn);
    __builtin_amdgcn_s_setprio(1);
    #pragma unroll
    for (int j=0;j<4;j++)
      #pragma unroll
      for (int n=0;n<4;n++)
        acc[4+j][n] = MFMA16(af[j], bfr[n], acc[4+j][n]);
    __builtin_amdgcn_s_setprio(0);

    // ---- phase 2: kh1, m-half 0 ----
    asm volatile("s_waitcnt vmcnt(4)" ::: "memory");
    __builtin_amdgcn_sched_barrier(0);
    __builtin_amdgcn_s_barrier();
    #pragma unroll
    for (int j=0;j<4;j++)
      af[j] = *(const bf16x8*)(abuf + 16384 + (wm*8+j)*1024 + aoff);
    #pragma unroll
    for (int n=0;n<4;n++)
      bfr[n] = *(const bf16x8*)(bbuf + 16384 + (wn*4+n)*1024 + aoff);
    stage(cb^1, 0, 1, ktn);
    __builtin_amdgcn_s_setprio(1);
    #pragma unroll
    for (int j=0;j<4;j++)
      #pragma unroll
      for (int n=0;n<4;n++)
        acc[j][n] = MFMA16(af[j], bfr[n], acc[j][n]);
    __builtin_amdgcn_s_setprio(0);

    // ---- phase 3: kh1, m-half 1 ----
    __builtin_amdgcn_s_barrier();
    #pragma unroll
    for (int j=0;j<4;j++)
      af[j] = *(const bf16x8*)(abuf + 16384 + (wm*8+4+j)*1024 + aoff);
    stage(cb^1, 1, 1, ktn);
    __builtin_amdgcn_s_setprio(1);
    #pragma unroll
    for (int j=0;j<4;j++)
      #pragma unroll
      for (int n=0;n<4;n++)
        acc[4+j][n] = MFMA16(af[j], bfr[n], acc[4+j][n]);
    __builtin_amdgcn_s_setprio(0);

    cb ^= 1;
  }
  __syncthreads();   // drain outstanding staging before exit

  #pragma unroll
  for (int mi=0;mi<8;mi++) {
    #pragma unroll
    for (int ni=0;ni<4;ni++) {
      long row = bm*256 + wm*128 + mi*16 + fq*4;
      long col = bn*256 + wn*64 + ni*16 + fr;
      #pragma unroll
      for (int r=0;r<4;r++) {
        float v = acc[mi][ni][r];
        if (OUT_BF16) ((bf16_t*)Cp)[(row+r)*(long)N + col] = (bf16_t)v;
        else          ((float*)Cp)[(row+r)*(long)N + col] = v;
      }
    }
  }
}

// ---------------------------------------------------------------------------
// betag2: read pb/pa from zbuf cols 2048..2079, compute {g, beta}
// ---------------------------------------------------------------------------
__global__ __launch_bounds__(256) void betag2_kernel(
    const bf16_t* __restrict__ zfull, const float* __restrict__ dt_bias,
    const float* __restrict__ A_log, float2* __restrict__ gb_t)
{
  int idx = blockIdx.x*256 + threadIdx.x;   // 65536 = 4096 tokens * 16 heads
  int h = idx & 15, tok = idx >> 4;
  int b = tok >> 11, s = tok & (SS-1);
  float pb = (float)zfull[(long)tok*ZN + 2048 + h];
  float pa = (float)zfull[(long)tok*ZN + 2064 + h];
  float beta = 1.f/(1.f+expf(-pb));
  float tt = pa + dt_bias[h];
  float sp = (tt > 20.f) ? tt : log1pf(expf(tt));
  float g  = -expf(A_log[h]) * sp;
  gb_t[((long)b*HH + h)*SS + s] = make_float2(g, beta);
}

// ---------------------------------------------------------------------------
// conv(K=4 causal depthwise) + bias + silu + q/k l2norm + transpose to [B,H,S,128]
// ---------------------------------------------------------------------------
__global__ __launch_bounds__(128) void conv_norm_kernel(
    const bf16_t* __restrict__ mixed, const float* __restrict__ cw,
    const float* __restrict__ cb, bf16_t* __restrict__ q_t,
    bf16_t* __restrict__ k_t, bf16_t* __restrict__ v_t)
{
  const int blk = blockIdx.x;           // (b*H+h)*S + s
  const int s = blk & (SS-1);
  const int h = (blk >> 11) & (HH-1);
  const int b = blk >> 15;
  const int d = threadIdx.x;

  const int cq = h*128 + d;
  const int ck = 2048 + cq;
  const int cv = 4096 + cq;
  float aq = cb[cq], ak = cb[ck], av = cb[cv];
  const float* wq = cw + (long)cq*4;
  const float* wk = cw + (long)ck*4;
  const float* wv = cw + (long)cv*4;
  #pragma unroll
  for (int tp=0; tp<4; ++tp) {
    int s2 = s - 3 + tp;
    if (s2 >= 0) {
      const bf16_t* rowp = mixed + ((long)b*SS + s2)*CONVC;
      aq += (float)rowp[cq] * wq[tp];
      ak += (float)rowp[ck] * wk[tp];
      av += (float)rowp[cv] * wv[tp];
    }
  }
  aq = aq * (1.f/(1.f+expf(-aq)));
  ak = ak * (1.f/(1.f+expf(-ak)));
  av = av * (1.f/(1.f+expf(-av)));

  float sq = aq*aq, sk = ak*ak;
  #pragma unroll
  for (int off=32; off>=1; off>>=1) { sq += __shfl_xor(sq, off); sk += __shfl_xor(sk, off); }
  __shared__ float red[4];
  const int wv2 = d >> 6;
  if ((d & 63) == 0) { red[wv2*2] = sq; red[wv2*2+1] = sk; }
  __syncthreads();
  float sumq = red[0] + red[2];
  float sumk = red[1] + red[3];

  const long obase = ((long)(b*HH + h)*SS + s)*128 + d;
  q_t[obase] = (bf16_t)(aq * rsqrtf(sumq + 1e-6f) * 0.08838834764831845f);  // * DK^-0.5
  k_t[obase] = (bf16_t)(ak * rsqrtf(sumk + 1e-6f));
  v_t[obase] = (bf16_t)av;
}

// ---------------------------------------------------------------------------
// Phase A (per bh,chunk): build Tp/Aq/TV/KTs/pv/PC into cdata.
// ---------------------------------------------------------------------------
__global__ __launch_bounds__(256) void chunkA_kernel(
    const bf16_t* __restrict__ q_t, const bf16_t* __restrict__ k_t,
    const bf16_t* __restrict__ v_t, const float2* __restrict__ gb_t,
    char* __restrict__ cdata)
{
  extern __shared__ char smem[];
  bf16_t* lK  = (bf16_t*)(smem);            // [64][136]
  bf16_t* lQV = (bf16_t*)(smem + 17408);    // lQ [64][136], later lVT [128][72]
  float*  lLf = (float*)(smem + 35840);     // [64][65]
  float*  lXf = (float*)(smem + 52480);     // [64][65]
  float*  gcv = (float*)(smem + 69120);     // [64]
  float*  pvv = (float*)(smem + 69376);     // [64]
  float*  bvv = (float*)(smem + 69632);     // [64]

  const int cd = blockIdx.x;
  const int bh = cd >> 5, c = cd & 31;
  const int t = threadIdx.x;
  const int lane = t & 63, w = t >> 6;
  const int fr = lane & 15, fq = lane >> 4;

  const bf16_t* kg = k_t + ((long)bh*SS + c*CH)*128;
  const bf16_t* qg = q_t + ((long)bh*SS + c*CH)*128;
  const bf16_t* vg = v_t + ((long)bh*SS + c*CH)*128;
  char* cdp = cdata + (long)cd*CD_STRIDE;

  // stage K, Q (lQV as lQ)
  #pragma unroll
  for (int ib=0; ib<4; ib++) {
    int e0 = (t + 256*ib)*8;
    int r = e0 >> 7, cc = e0 & 127;
    *(bf16x8*)&lK[r*136+cc]  = *(const bf16x8*)(kg + e0);
    *(bf16x8*)&lQV[r*136+cc] = *(const bf16x8*)(qg + e0);
  }
  if (t < 64) {
    float2 gb = gb_t[(long)bh*SS + c*CH + t];
    gcv[t] = gb.x;
    bvv[t] = gb.y;
  }
  __syncthreads();
  // wave-parallel inclusive scan of gcv (wave 0)
  if (t < 64) {
    float g = gcv[t];
    #pragma unroll
    for (int off=1; off<64; off<<=1) {
      float n = __shfl_up(g, off);
      if (lane >= off) g += n;
    }
    gcv[t] = g;
  }
  __syncthreads();
  if (t < 64) pvv[t] = expf(gcv[t]);

  // G = K K^T, Gq = Q K^T  (wave strip rows 16w)
  {
    f32x4 accG[4], accQ[4];
    #pragma unroll
    for (int tn=0;tn<4;tn++){ accG[tn]=(f32x4){0,0,0,0}; accQ[tn]=(f32x4){0,0,0,0}; }
    #pragma unroll
    for (int ks=0;ks<4;ks++) {
      bf16x8 aK = *(const bf16x8*)&lK[(w*16+fr)*136 + fq*8 + ks*32];
      bf16x8 aQ = *(const bf16x8*)&lQV[(w*16+fr)*136 + fq*8 + ks*32];
      #pragma unroll
      for (int tn=0;tn<4;tn++) {
        bf16x8 bK = *(const bf16x8*)&lK[(tn*16+fr)*136 + fq*8 + ks*32];
        accG[tn] = MFMA16(aK, bK, accG[tn]);
        accQ[tn] = MFMA16(aQ, bK, accQ[tn]);
      }
    }
    bf16_t* aqg = (bf16_t*)(cdp + CD_AQ);
    #pragma unroll
    for (int tn=0;tn<4;tn++) {
      #pragma unroll
      for (int r=0;r<4;r++) {
        int tt = w*16 + fq*4 + r;
        int ii = tn*16 + fr;
        float er = expf(gcv[tt] - gcv[ii]);
        lLf[tt*65 + ii] = (ii < tt) ? bvv[tt]*er*accG[tn][r] : 0.f;
        aqg[tt*64 + ii] = (bf16_t)((ii <= tt) ? er*accQ[tn][r] : 0.f);
      }
    }
  }
  #pragma unroll
  for (int ib=0; ib<16; ib++) {
    int idx = t + ib*256; int r = idx>>6, cc = idx&63;
    lXf[r*65+cc] = (r==cc) ? bvv[r] : 0.f;
  }
  __syncthreads();   // lLf/lXf ready; lQ reads done -> reuse as lVT

  // stage V^T into lQV with staggered element order (kills 16-way conflicts)
  bf16_t* lVT = lQV;   // [128][72]
  {
    const int m = t & 15;
    #pragma unroll
    for (int ib=0; ib<4; ib++) {
      int e0 = (t + 256*ib)*8;
      int r = e0 >> 7, cc = e0 & 127;
      bf16x8 v8 = *(const bf16x8*)(vg + e0);
      #pragma unroll
      for (int e=0;e<8;e++) {
        int ee = (e + m) & 7;
        lVT[(cc+ee)*72 + r] = v8[ee];
      }
    }
  }

  // forward elimination: X[t] -= Lf[t][i] * X[i]
  {
    const int jj = t & 63, rg = t >> 6;
    for (int i=0; i<CH-1; i++) {
      float xi = lXf[i*65 + jj];
      for (int tr = i+1+rg; tr < CH; tr += 4)
        lXf[tr*65 + jj] = fmaf(-lLf[tr*65 + i], xi, lXf[tr*65 + jj]);
      __syncthreads();
    }
  }

  // Tp store + bf16 copy of Tmat (reuse lLf region)
  bf16_t* lXb = (bf16_t*)lLf;   // [64][72]
  {
    bf16_t* tpg = (bf16_t*)(cdp + CD_TP);
    #pragma unroll
    for (int ib=0; ib<16; ib++) {
      int idx = t + ib*256; int r = idx>>6, cc = idx&63;
      float xv = lXf[r*65+cc];
      tpg[r*64+cc] = (bf16_t)(xv * pvv[cc]);
      lXb[r*72+cc] = (bf16_t)xv;
    }
  }
  __syncthreads();

  // TV = Tmat @ V : C[t][dv] = sum_i Xb[t][i] * VT[dv][i]
  {
    f32x4 acc[8];
    #pragma unroll
    for (int tn=0;tn<8;tn++) acc[tn]=(f32x4){0,0,0,0};
    #pragma unroll
    for (int ks=0;ks<2;ks++) {
      bf16x8 aX = *(const bf16x8*)&lXb[(w*16+fr)*72 + fq*8 + ks*32];
      #pragma unroll
      for (int tn=0;tn<8;tn++) {
        bf16x8 bV = *(const bf16x8*)&lVT[(tn*16+fr)*72 + fq*8 + ks*32];
        acc[tn] = MFMA16(aX, bV, acc[tn]);
      }
    }
    bf16_t* tvg = (bf16_t*)(cdp + CD_TV);
    #pragma unroll
    for (int tn=0;tn<8;tn++)
      #pragma unroll
      for (int r=0;r<4;r++) {
        int tt = w*16 + fq*4 + r, dv = tn*16 + fr;
        tvg[tt*128 + dv] = (bf16_t)acc[tn][r];
      }
  }

  // KTs[dk][i] = K[i][dk] * exp(gc_C - gc_i)
  {
    bf16_t* ktg = (bf16_t*)(cdp + CD_KTS);
    int dk = t >> 1, c0 = (t & 1)*32;
    float g63 = gcv[63];
    bf16_t tmp[32];
    #pragma unroll
    for (int i2=0;i2<32;i2++) {
      int i = c0 + i2;
      tmp[i2] = (bf16_t)((float)lK[i*136 + dk] * expf(g63 - gcv[i]));
    }
    #pragma unroll
    for (int s8=0;s8<4;s8++)
      *(bf16x8*)&ktg[dk*64 + c0 + s8*8] = *(bf16x8*)&tmp[s8*8];
  }
  if (t < 64) ((float*)(cdp + CD_PV))[t] = pvv[t];
  if (t == 0) *((float*)(cdp + CD_PC)) = expf(gcv[63]);
}

// ---------------------------------------------------------------------------
// Phase S (serial over 32 chunks; 256 blocks = 32 bh x 8 dv-splits of 16):
//   X=K S; Xq=Q S (store); D = TV - Tp X (store D^T); S = PC*S + KTs D
// Pipelined: chunk c+1's K/Q/Tp/KTs loaded to regs at top of chunk c,
// written to LDS in the tail phase (staging off the serial path).
// ---------------------------------------------------------------------------
__global__ __launch_bounds__(256) void chunkS_kernel(
    const bf16_t* __restrict__ q_t, const bf16_t* __restrict__ k_t,
    const char* __restrict__ cdata, bf16_t* __restrict__ gD,
    bf16_t* __restrict__ gXq)
{
  extern __shared__ char smem[];
  float*  lS  = (float*)(smem);              // [16][129] f32  S^T slice [dv][dk]
  bf16_t* lSb = (bf16_t*)(smem + 8320);      // [16][136] bf16
  bf16_t* lK  = (bf16_t*)(smem + 12672);     // [64][136]
  bf16_t* lQ  = (bf16_t*)(smem + 30080);     // [64][136]
  bf16_t* lTp = (bf16_t*)(smem + 47488);     // [64][72]
  bf16_t* lKT = (bf16_t*)(smem + 56704);     // [128][72]
  bf16_t* lXT = (bf16_t*)(smem + 75136);     // [16][88]  X^T [dv][t]
  bf16_t* lDT = (bf16_t*)(smem + 77952);     // [16][88]  D^T [dv][t]

  const int bid = blockIdx.x;
  const int lb  = (bid & 7)*32 + (bid >> 3);   // same-bh blocks on one XCD
  const int bh = lb >> 3, sp = lb & 7;
  const int dv0 = sp*16;
  const int t = threadIdx.x, lane = t & 63, w = t >> 6;
  const int fr = lane & 15, fq = lane >> 4;

  #pragma unroll
  for (int ib=0; ib<8; ib++) {
    int idx = t + ib*256; int r = idx>>7, cc = idx&127;
    lS[r*129+cc] = 0.f;
    lSb[r*136+cc] = (bf16_t)0.f;
  }

  const bf16_t* kg = k_t + (long)bh*SS*128;
  const bf16_t* qg = q_t + (long)bh*SS*128;

  bf16x8 kr0,kr1,kr2,kr3, qr0,qr1,qr2,qr3, kt0,kt1,kt2,kt3, tp0,tp1;

#define STAGE_LOAD(CSRC)                                                       \
  {                                                                            \
    const char* cdl = cdata + (long)(bh*NCH + (CSRC))*CD_STRIDE;               \
    const bf16_t* kl = kg + (long)(CSRC)*CH*128;                               \
    const bf16_t* ql = qg + (long)(CSRC)*CH*128;                               \
    const bf16_t* ktl = (const bf16_t*)(cdl + CD_KTS);                         \
    const bf16_t* tpl = (const bf16_t*)(cdl + CD_TP);                          \
    int e0 = t*8, e1 = (t+256)*8, e2 = (t+512)*8, e3 = (t+768)*8;              \
    kr0 = *(const bf16x8*)(kl + e0); kr1 = *(const bf16x8*)(kl + e1);          \
    kr2 = *(const bf16x8*)(kl + e2); kr3 = *(const bf16x8*)(kl + e3);          \
    qr0 = *(const bf16x8*)(ql + e0); qr1 = *(const bf16x8*)(ql + e1);          \
    qr2 = *(const bf16x8*)(ql + e2); qr3 = *(const bf16x8*)(ql + e3);          \
    kt0 = *(const bf16x8*)(ktl + e0); kt1 = *(const bf16x8*)(ktl + e1);        \
    kt2 = *(const bf16x8*)(ktl + e2); kt3 = *(const bf16x8*)(ktl + e3);        \
    tp0 = *(const bf16x8*)(tpl + e0); tp1 = *(const bf16x8*)(tpl + e1);        \
  }

#define STAGE_WRITE()                                                          \
  {                                                                            \
    int e0 = t*8, e1 = (t+256)*8, e2 = (t+512)*8, e3 = (t+768)*8;              \
    *(bf16x8*)&lK[(e0>>7)*136 + (e0&127)] = kr0;                               \
    *(bf16x8*)&lK[(e1>>7)*136 + (e1&127)] = kr1;                               \
    *(bf16x8*)&lK[(e2>>7)*136 + (e2&127)] = kr2;                               \
    *(bf16x8*)&lK[(e3>>7)*136 + (e3&127)] = kr3;                               \
    *(bf16x8*)&lQ[(e0>>7)*136 + (e0&127)] = qr0;                               \
    *(bf16x8*)&lQ[(e1>>7)*136 + (e1&127)] = qr1;                               \
    *(bf16x8*)&lQ[(e2>>7)*136 + (e2&127)] = qr2;                               \
    *(bf16x8*)&lQ[(e3>>7)*136 + (e3&127)] = qr3;                               \
    *(bf16x8*)&lKT[(e0>>6)*72 + (e0&63)] = kt0;                                \
    *(bf16x8*)&lKT[(e1>>6)*72 + (e1&63)] = kt1;                                \
    *(bf16x8*)&lKT[(e2>>6)*72 + (e2&63)] = kt2;                                \
    *(bf16x8*)&lKT[(e3>>6)*72 + (e3&63)] = kt3;                                \
    *(bf16x8*)&lTp[(e0>>6)*72 + (e0&63)] = tp0;                                \
    *(bf16x8*)&lTp[(e1>>6)*72 + (e1&63)] = tp1;                                \
  }

  STAGE_LOAD(0);
  STAGE_WRITE();
  __syncthreads();

  for (int c=0; c<NCH; c++) {
    const int cd = bh*NCH + c;
    const char* cdp = cdata + (long)cd*CD_STRIDE;

    // TV quad + PC for current chunk (issued FIRST so their wait doesn't
    // drain the prefetch queue)
    float tvq0, tvq1, tvq2, tvq3, pc;
    {
      const bf16_t* tvp = (const bf16_t*)(cdp + CD_TV);
      tvq0 = (float)tvp[(w*16+fq*4+0)*128 + dv0 + fr];
      tvq1 = (float)tvp[(w*16+fq*4+1)*128 + dv0 + fr];
      tvq2 = (float)tvp[(w*16+fq*4+2)*128 + dv0 + fr];
      tvq3 = (float)tvp[(w*16+fq*4+3)*128 + dv0 + fr];
      pc = *(const float*)(cdp + CD_PC);
    }
    // issue prefetch of chunk c+1 (clamped) into regs
    const int cn = (c+1 < NCH) ? c+1 : c;
    STAGE_LOAD(cn);

    // X = K S^T-slice, Xq = Q S^T-slice  (M=64, N=16, K=128)
    f32x4 aX = {0,0,0,0}, aXq = {0,0,0,0};
    #pragma unroll
    for (int ks=0; ks<4; ks++) {
      bf16x8 bS = *(const bf16x8*)&lSb[fr*136 + fq*8 + ks*32];
      bf16x8 aK = *(const bf16x8*)&lK[(w*16+fr)*136 + fq*8 + ks*32];
      bf16x8 aQ = *(const bf16x8*)&lQ[(w*16+fr)*136 + fq*8 + ks*32];
      aX  = MFMA16(aK, bS, aX);
      aXq = MFMA16(aQ, bS, aXq);
    }
    #pragma unroll
    for (int r=0;r<4;r++)
      lXT[fr*88 + (w*16+fq*4+r)] = (bf16_t)aX[r];
    __syncthreads();   // A

    // D = TV - Tp X  (M=64, N=16, K=64); also scale lS by PC
    {
      f32x4 aD = {0,0,0,0};
      #pragma unroll
      for (int ks=0; ks<2; ks++) {
        bf16x8 aT = *(const bf16x8*)&lTp[(w*16+fr)*72 + fq*8 + ks*32];
        bf16x8 bX = *(const bf16x8*)&lXT[fr*88 + fq*8 + ks*32];
        aD = MFMA16(aT, bX, aD);
      }
      lDT[fr*88 + (w*16+fq*4+0)] = (bf16_t)(tvq0 - aD[0]);
      lDT[fr*88 + (w*16+fq*4+1)] = (bf16_t)(tvq1 - aD[1]);
      lDT[fr*88 + (w*16+fq*4+2)] = (bf16_t)(tvq2 - aD[2]);
      lDT[fr*88 + (w*16+fq*4+3)] = (bf16_t)(tvq3 - aD[3]);
    }
    #pragma unroll
    for (int ib=0; ib<8; ib++) {
      int idx = t + ib*256; int r = idx>>7, cc = idx&127;
      lS[r*129+cc] *= pc;
    }
    __syncthreads();   // B

    // S^T += D^T KTs^T : C[dv][dk] = sum_i D^T[dv][i]*KTs[dk][i]
    {
      f32x4 aS0 = {0,0,0,0}, aS1 = {0,0,0,0};
      #pragma unroll
      for (int ks=0; ks<2; ks++) {
        bf16x8 aDd = *(const bf16x8*)&lDT[fr*88 + fq*8 + ks*32];
        bf16x8 bK0 = *(const bf16x8*)&lKT[(w*32+fr)*72 + fq*8 + ks*32];
        bf16x8 bK1 = *(const bf16x8*)&lKT[(w*32+16+fr)*72 + fq*8 + ks*32];
        aS0 = MFMA16(aDd, bK0, aS0);
        aS1 = MFMA16(aDd, bK1, aS1);
      }
      #pragma unroll
      for (int r=0;r<4;r++) {
        lS[(fq*4+r)*129 + w*32 + fr]      += aS0[r];
        lS[(fq*4+r)*129 + w*32 + 16 + fr] += aS1[r];
      }
    }
    // global stores: Xq and D^T
    #pragma unroll
    for (int r=0;r<4;r++)
      gXq[((long)cd*CH + w*16+fq*4+r)*128 + dv0 + fr] = (bf16_t)aXq[r];
    {
      int dvl = t >> 4, off = (t & 15)*4;
      *(bf16x4*)(gD + ((long)cd*128 + dv0 + dvl)*64 + off) =
          *(const bf16x4*)&lDT[dvl*88 + off];
    }
    __syncthreads();   // C

    // write staged c+1 into LDS; cast lSb = bf16(lS)
    STAGE_WRITE();
    #pragma unroll
    for (int ib=0; ib<8; ib++) {
      int idx = t + ib*256; int r = idx>>7, cc = idx&127;
      lSb[r*136+cc] = (bf16_t)lS[r*129+cc];
    }
    __syncthreads();   // D
  }
#undef STAGE_LOAD
#undef STAGE_WRITE
}

// ---------------------------------------------------------------------------
// Phase O (parallel, per chunk): O = diag(p) Xq + Aq D  -> obuf
// ---------------------------------------------------------------------------
__global__ __launch_bounds__(256) void chunkO_kernel(
    const char* __restrict__ cdata, const bf16_t* __restrict__ gD,
    const bf16_t* __restrict__ gXq, bf16_t* __restrict__ obuf)
{
  const int cd = blockIdx.x;
  const int bh = cd >> 5, c = cd & 31;
  const int b = bh >> 4, h = bh & 15;
  const int t = threadIdx.x, lane = t & 63, w = t >> 6;
  const int fr = lane & 15, fq = lane >> 4;

  const char* cdp = cdata + (long)cd*CD_STRIDE;
  const bf16_t* aqp = (const bf16_t*)(cdp + CD_AQ);   // [64][64]
  const bf16_t* dp  = gD + (long)cd*128*64;           // [128 dv][64 t]
  const float*  pvp = (const float*)(cdp + CD_PV);

  f32x4 acc[8];
  #pragma unroll
  for (int tn=0;tn<8;tn++) acc[tn]=(f32x4){0,0,0,0};
  #pragma unroll
  for (int ks=0;ks<2;ks++) {
    bf16x8 aA = *(const bf16x8*)(aqp + (w*16+fr)*64 + fq*8 + ks*32);
    #pragma unroll
    for (int tn=0;tn<8;tn++) {
      bf16x8 bD = *(const bf16x8*)(dp + (tn*16+fr)*64 + fq*8 + ks*32);
      acc[tn] = MFMA16(aA, bD, acc[tn]);
    }
  }
  #pragma unroll
  for (int tn=0;tn<8;tn++)
    #pragma unroll
    for (int r=0;r<4;r++) {
      int tt = w*16+fq*4+r, dv = tn*16+fr;
      float ov = pvp[tt]*(float)gXq[((long)cd*CH + tt)*128 + dv] + acc[tn][r];
      obuf[((long)(b*SS + c*CH + tt)*HH + h)*128 + dv] = (bf16_t)ov;
    }
}

// ---------------------------------------------------------------------------
// RMSNorm over DV + (1+nw) + silu(z) gate; z from zbuf (stride ZN)
// ---------------------------------------------------------------------------
__global__ __launch_bounds__(128) void norm_gate_kernel(
    const bf16_t* __restrict__ o, const bf16_t* __restrict__ zfull,
    const float* __restrict__ nw, bf16_t* __restrict__ og)
{
  const long row = blockIdx.x;      // (b*S+s)*H + h
  const long tok = row >> 4;
  const int h = row & 15;
  const int d = threadIdx.x;
  float x = (float)o[row*128 + d];
  float ss = x*x;
  #pragma unroll
  for (int off=32; off>=1; off>>=1) ss += __shfl_xor(ss, off);
  __shared__ float red[2];
  if ((d & 63) == 0) red[d>>6] = ss;
  __syncthreads();
  float mean = (red[0] + red[1]) * (1.f/128.f);
  float zn = (float)zfull[tok*ZN + h*128 + d];
  float val = x * rsqrtf(mean + 1e-6f) * (1.f + nw[d]) * (zn * (1.f/(1.f+expf(-zn))));
  og[row*128 + d] = (bf16_t)val;
}

// ---------------------------------------------------------------------------
extern "C" void kernel_launch(void* const* d_in, const int* in_sizes, int n_in,
                              void* d_out, int out_size, void* d_ws, size_t ws_size,
                              hipStream_t stream)
{
  const float* hs    = (const float*)d_in[0];
  const float* amask = (const float*)d_in[1];
  const float* Wqkv  = (const float*)d_in[2];
  const float* convw = (const float*)d_in[3];
  const float* convb = (const float*)d_in[4];
  const float* Wz    = (const float*)d_in[5];
  const float* Wb    = (const float*)d_in[6];
  const float* Wa    = (const float*)d_in[7];
  const float* dtb   = (const float*)d_in[8];
  const float* Alog  = (const float*)d_in[9];
  const float* nw    = (const float*)d_in[10];
  const float* Wout  = (const float*)d_in[11];

  const size_t MB = 1024*1024;
  char* p = (char*)d_ws;
  auto alloc = [&](size_t bytes) { char* r = p; p += (bytes + 255) & ~(size_t)255; return r; };
  bf16_t* x_bf   = (bf16_t*)alloc(16*MB);   // x_bf; later gD [1024][128][64]
  char*   bigreg = alloc(72*MB);            // wqkv@0, mixed@24MB; later cdata@0, obuf@52MB
  bf16_t* wz_bf  = (bf16_t*)alloc(10*MB);   // Wz rows + W_b/W_a rows @8MB; later Wout@0
  bf16_t* zbuf   = (bf16_t*)alloc(19*MB);   // [4096][2304]
  bf16_t* q_t    = (bf16_t*)alloc(16*MB);   // q; later og
  bf16_t* k_t    = (bf16_t*)alloc(16*MB);
  bf16_t* v_t    = (bf16_t*)alloc(16*MB);   // v; later gXq [1024][64][128]
  float2* gb_t   = (float2*)alloc((size_t)BB*HH*SS*8);
  size_t need = (size_t)(p - (char*)d_ws);
  if (ws_size < need) return;   // clean fail (absmax = poison)

  bf16_t* wqkv_bf = (bf16_t*)bigreg;
  bf16_t* mixed   = (bf16_t*)(bigreg + 24*MB);
  char*   cdata   = bigreg;                       // after GEMM1+conv consumed
  bf16_t* obuf    = (bf16_t*)(bigreg + 52*MB);    // cdata ends at ~48.5MB
  bf16_t* wout_bf = wz_bf;                        // cast after z-GEMM (rows 0..2047 only)
  bf16_t* gD      = x_bf;                         // after z-GEMM consumed x_bf
  bf16_t* gXq     = v_t;                          // after chunkA consumed v_t
  bf16_t* og      = q_t;                          // after chunkS consumed q_t

  cast_x_kernel<<<2048, 256, 0, stream>>>(hs, amask, x_bf, (long)MM*DD);
  cast_w_kernel<<<2048, 256, 0, stream>>>(Wqkv, wqkv_bf, (long)CONVC*DD);
  cast_w_kernel<<<1024, 256, 0, stream>>>(Wz,   wz_bf,   (long)DD*DD);
  cast_ba_kernel<<<64, 256, 0, stream>>>(Wb, Wa, wz_bf + (size_t)DD*DD);

  gemm256<true><<<384, 512, 131072, stream>>>(x_bf, wqkv_bf, mixed, MM, CONVC, DD, 24);

  conv_norm_kernel<<<BB*HH*SS, 128, 0, stream>>>(mixed, convw, convb, q_t, k_t, v_t);

  gemm256<true><<<144, 512, 131072, stream>>>(x_bf, wz_bf, zbuf, MM, ZN, DD, 9);
  cast_w_kernel<<<1024, 256, 0, stream>>>(Wout, wout_bf, (long)DD*DD);
  betag2_kernel<<<256, 256, 0, stream>>>(zbuf, dtb, Alog, gb_t);

  chunkA_kernel<<<BB*HH*NCH, 256, 69888, stream>>>(q_t, k_t, v_t, gb_t, cdata);
  chunkS_kernel<<<BB*HH*8, 256, 80768, stream>>>(q_t, k_t, cdata, gD, gXq);
  chunkO_kernel<<<BB*HH*NCH, 256, 0, stream>>>(cdata, gD, gXq, obuf);

  norm_gate_kernel<<<MM*HH, 128, 0, stream>>>(obuf, zbuf, nw, og);

  gemm256<false><<<128, 512, 131072, stream>>>(og, wout_bf, d_out, MM, DD, DD, 8);
}

// Round 11
// 516.194 us; speedup vs baseline: 1.5730x; 1.1080x over previous
//
#include <hip/hip_runtime.h>
#include <hip/hip_bf16.h>
#include <math.h>

// Problem constants
#define BB 2
#define SS 2048
#define DD 2048
#define HH 16
#define CONVC 6144
#define MM (BB*SS)   // 4096 tokens
#define ZN 2304      // z-GEMM N: 2048 z cols + 16 W_b + 16 W_a + 224 pad

// chunked delta-rule constants
#define CH 64        // chunk length
#define NCH 32       // chunks per sequence
#define CD_KTS 0
#define CD_TV  16384
#define CD_TP  32768
#define CD_AQ  40960
#define CD_PV  49152
#define CD_PC  49408
#define CD_STRIDE 49664

typedef __bf16 bf16_t;
typedef __bf16 bf16x8 __attribute__((ext_vector_type(8)));
typedef __bf16 bf16x4 __attribute__((ext_vector_type(4)));
typedef float  f32x4  __attribute__((ext_vector_type(4)));

#define GLOBAL_AS __attribute__((address_space(1)))
#define LDS_AS    __attribute__((address_space(3)))

#define MFMA16(a,b,c) __builtin_amdgcn_mfma_f32_16x16x32_bf16((a),(b),(c),0,0,0)

// ---------------------------------------------------------------------------
// Cast kernels
// ---------------------------------------------------------------------------
__global__ __launch_bounds__(256) void cast_x_kernel(
    const float* __restrict__ in, const float* __restrict__ mask,
    bf16_t* __restrict__ out, long n)
{
  long n4 = n >> 2;
  for (long i = (long)blockIdx.x*256 + threadIdx.x; i < n4; i += (long)gridDim.x*256) {
    float4 v = ((const float4*)in)[i];
    float m = mask[(i*4) / DD];
    bf16x4 o4;
    o4[0]=(bf16_t)(v.x*m); o4[1]=(bf16_t)(v.y*m);
    o4[2]=(bf16_t)(v.z*m); o4[3]=(bf16_t)(v.w*m);
    ((bf16x4*)out)[i] = o4;
  }
}

__global__ __launch_bounds__(256) void cast_w_kernel(
    const float* __restrict__ in, bf16_t* __restrict__ out, long n)
{
  long n4 = n >> 2;
  for (long i = (long)blockIdx.x*256 + threadIdx.x; i < n4; i += (long)gridDim.x*256) {
    float4 v = ((const float4*)in)[i];
    bf16x4 o4;
    o4[0]=(bf16_t)v.x; o4[1]=(bf16_t)v.y; o4[2]=(bf16_t)v.z; o4[3]=(bf16_t)v.w;
    ((bf16x4*)out)[i] = o4;
  }
}

// append W_b (16x2048) then W_a (16x2048) as bf16 rows after the Wz rows
__global__ __launch_bounds__(256) void cast_ba_kernel(
    const float* __restrict__ Wb, const float* __restrict__ Wa,
    bf16_t* __restrict__ out)   // out = wz_bf + 2048*2048
{
  int i = blockIdx.x*256 + threadIdx.x;   // 16384 threads, 4 elems each
  int j = i*4;
  const float* src = (j < 32768) ? (Wb + j) : (Wa + j - 32768);
  float4 v = *(const float4*)src;
  bf16x4 o4;
  o4[0]=(bf16_t)v.x; o4[1]=(bf16_t)v.y; o4[2]=(bf16_t)v.z; o4[3]=(bf16_t)v.w;
  *(bf16x4*)(out + j) = o4;
}

// ---------------------------------------------------------------------------
// 256x256 8-phase bf16 GEMM: C[M,N] = A[M,K] * B[N,K]^T   (T2+T3+T4+T5)
// ---------------------------------------------------------------------------
template<bool OUT_BF16>
__global__ __launch_bounds__(512) void gemm256(
    const bf16_t* __restrict__ A, const bf16_t* __restrict__ Bm,
    void* __restrict__ Cp, int M, int N, int K, int nbn)
{
  extern __shared__ char gsm[];   // A: buf0@0, buf1@32768; B: +65536
  const int t    = threadIdx.x;
  const int lane = t & 63;
  const int wid  = t >> 6;
  const int wm   = wid >> 2, wn = wid & 3;
  const int fr   = lane & 15, fq = lane >> 4;

  // XCD-aware swizzle (grid is a multiple of 8)
  const int nwg = gridDim.x;
  const int wg  = ((int)blockIdx.x & 7)*(nwg >> 3) + ((int)blockIdx.x >> 3);
  const long bm = wg / nbn, bn = wg % nbn;

  // staging decode: thread's 2 linear 16B chunks -> (row,col) via inverse swizzle
  int rowS[2], colS[2];
  #pragma unroll
  for (int i=0;i<2;i++) {
    int L  = (i*512 + t)*16;
    int Ls = L ^ (((L>>9)&1)<<5);
    rowS[i] = (Ls>>10)*16 + ((Ls&1023)>>6);
    colS[i] = (Ls&63)>>1;
  }
  const bf16_t* Ab = A  + (bm*256)*(long)K;
  const bf16_t* Bb = Bm + (bn*256)*(long)K;

  f32x4 acc[8][4];
  #pragma unroll
  for (int i=0;i<8;i++)
    #pragma unroll
    for (int j=0;j<4;j++) acc[i][j] = (f32x4){0.f,0.f,0.f,0.f};

  const int aoff = fr*64 + ((fq*16) ^ ((fr&8)<<2));  // swizzled frag byte offset

  auto stage = [&](int buf, int oper, int kh, int kt) {
    const bf16_t* srcb = oper ? Bb : Ab;
    char* dst0 = gsm + oper*65536 + buf*32768 + kh*16384 + t*16;
    #pragma unroll
    for (int i=0;i<2;i++) {
      const bf16_t* src = srcb + (long)rowS[i]*K + kt*64 + kh*32 + colS[i];
      __builtin_amdgcn_global_load_lds((const GLOBAL_AS void*)src,
          (LDS_AS void*)(dst0 + i*8192), 16, 0, 0);
    }
  };

  // prologue: stage tile 0 into buffer 0
  stage(0,0,0,0); stage(0,1,0,0); stage(0,0,1,0); stage(0,1,1,0);

  bf16x8 bfr[4];
  int cb = 0;
  const int KT = K >> 6;
  for (int kt=0; kt<KT; ++kt) {
    const int ktn = (kt+1 < KT) ? kt+1 : kt;
    const char* abuf = gsm + cb*32768;
    const char* bbuf = gsm + 65536 + cb*32768;
    bf16x8 af[4];

    // ---- phase 0: kh0, m-half 0 ----
    asm volatile("s_waitcnt vmcnt(4)" ::: "memory");
    __builtin_amdgcn_sched_barrier(0);
    __builtin_amdgcn_s_barrier();
    #pragma unroll
    for (int j=0;j<4;j++)
      af[j] = *(const bf16x8*)(abuf + (wm*8+j)*1024 + aoff);
    #pragma unroll
    for (int n=0;n<4;n++)
      bfr[n] = *(const bf16x8*)(bbuf + (wn*4+n)*1024 + aoff);
    stage(cb^1, 0, 0, ktn);
    __builtin_amdgcn_s_setprio(1);
    #pragma unroll
    for (int j=0;j<4;j++)
      #pragma unroll
      for (int n=0;n<4;n++)
        acc[j][n] = MFMA16(af[j], bfr[n], acc[j][n]);
    __builtin_amdgcn_s_setprio(0);

    // ---- phase 1: kh0, m-half 1 ----
    __builtin_amdgcn_s_barrier();
    #pragma unroll
    for (int j=0;j<4;j++)
      af[j] = *(const bf16x8*)(abuf + (wm*8+4+j)*1024 + aoff);
    stage(cb^1, 1, 0, ktn);
    __builtin_amdgcn_s_setprio(1);
    #pragma unroll
    for (int j=0;j<4;j++)
      #pragma unroll
      for (int n=0;n<4;n++)
        acc[4+j][n] = MFMA16(af[j], bfr[n], acc[4+j][n]);
    __builtin_amdgcn_s_setprio(0);

    // ---- phase 2: kh1, m-half 0 ----
    asm volatile("s_waitcnt vmcnt(4)" ::: "memory");
    __builtin_amdgcn_sched_barrier(0);
    __builtin_amdgcn_s_barrier();
    #pragma unroll
    for (int j=0;j<4;j++)
      af[j] = *(const bf16x8*)(abuf + 16384 + (wm*8+j)*1024 + aoff);
    #pragma unroll
    for (int n=0;n<4;n++)
      bfr[n] = *(const bf16x8*)(bbuf + 16384 + (wn*4+n)*1024 + aoff);
    stage(cb^1, 0, 1, ktn);
    __builtin_amdgcn_s_setprio(1);
    #pragma unroll
    for (int j=0;j<4;j++)
      #pragma unroll
      for (int n=0;n<4;n++)
        acc[j][n] = MFMA16(af[j], bfr[n], acc[j][n]);
    __builtin_amdgcn_s_setprio(0);

    // ---- phase 3: kh1, m-half 1 ----
    __builtin_amdgcn_s_barrier();
    #pragma unroll
    for (int j=0;j<4;j++)
      af[j] = *(const bf16x8*)(abuf + 16384 + (wm*8+4+j)*1024 + aoff);
    stage(cb^1, 1, 1, ktn);
    __builtin_amdgcn_s_setprio(1);
    #pragma unroll
    for (int j=0;j<4;j++)
      #pragma unroll
      for (int n=0;n<4;n++)
        acc[4+j][n] = MFMA16(af[j], bfr[n], acc[4+j][n]);
    __builtin_amdgcn_s_setprio(0);

    cb ^= 1;
  }
  __syncthreads();   // drain outstanding staging before exit

  #pragma unroll
  for (int mi=0;mi<8;mi++) {
    #pragma unroll
    for (int ni=0;ni<4;ni++) {
      long row = bm*256 + wm*128 + mi*16 + fq*4;
      long col = bn*256 + wn*64 + ni*16 + fr;
      #pragma unroll
      for (int r=0;r<4;r++) {
        float v = acc[mi][ni][r];
        if (OUT_BF16) ((bf16_t*)Cp)[(row+r)*(long)N + col] = (bf16_t)v;
        else          ((float*)Cp)[(row+r)*(long)N + col] = v;
      }
    }
  }
}

// ---------------------------------------------------------------------------
// betag2: read pb/pa from zbuf cols 2048..2079, compute {g, beta}
// ---------------------------------------------------------------------------
__global__ __launch_bounds__(256) void betag2_kernel(
    const bf16_t* __restrict__ zfull, const float* __restrict__ dt_bias,
    const float* __restrict__ A_log, float2* __restrict__ gb_t)
{
  int idx = blockIdx.x*256 + threadIdx.x;   // 65536 = 4096 tokens * 16 heads
  int h = idx & 15, tok = idx >> 4;
  int b = tok >> 11, s = tok & (SS-1);
  float pb = (float)zfull[(long)tok*ZN + 2048 + h];
  float pa = (float)zfull[(long)tok*ZN + 2064 + h];
  float beta = 1.f/(1.f+expf(-pb));
  float tt = pa + dt_bias[h];
  float sp = (tt > 20.f) ? tt : log1pf(expf(tt));
  float g  = -expf(A_log[h]) * sp;
  gb_t[((long)b*HH + h)*SS + s] = make_float2(g, beta);
}

// ---------------------------------------------------------------------------
// conv(K=4 causal depthwise) + bias + silu + q/k l2norm + transpose to [B,H,S,128]
// ---------------------------------------------------------------------------
__global__ __launch_bounds__(128) void conv_norm_kernel(
    const bf16_t* __restrict__ mixed, const float* __restrict__ cw,
    const float* __restrict__ cb, bf16_t* __restrict__ q_t,
    bf16_t* __restrict__ k_t, bf16_t* __restrict__ v_t)
{
  const int blk = blockIdx.x;           // (b*H+h)*S + s
  const int s = blk & (SS-1);
  const int h = (blk >> 11) & (HH-1);
  const int b = blk >> 15;
  const int d = threadIdx.x;

  const int cq = h*128 + d;
  const int ck = 2048 + cq;
  const int cv = 4096 + cq;
  float aq = cb[cq], ak = cb[ck], av = cb[cv];
  const float* wq = cw + (long)cq*4;
  const float* wk = cw + (long)ck*4;
  const float* wv = cw + (long)cv*4;
  #pragma unroll
  for (int tp=0; tp<4; ++tp) {
    int s2 = s - 3 + tp;
    if (s2 >= 0) {
      const bf16_t* rowp = mixed + ((long)b*SS + s2)*CONVC;
      aq += (float)rowp[cq] * wq[tp];
      ak += (float)rowp[ck] * wk[tp];
      av += (float)rowp[cv] * wv[tp];
    }
  }
  aq = aq * (1.f/(1.f+expf(-aq)));
  ak = ak * (1.f/(1.f+expf(-ak)));
  av = av * (1.f/(1.f+expf(-av)));

  float sq = aq*aq, sk = ak*ak;
  #pragma unroll
  for (int off=32; off>=1; off>>=1) { sq += __shfl_xor(sq, off); sk += __shfl_xor(sk, off); }
  __shared__ float red[4];
  const int wv2 = d >> 6;
  if ((d & 63) == 0) { red[wv2*2] = sq; red[wv2*2+1] = sk; }
  __syncthreads();
  float sumq = red[0] + red[2];
  float sumk = red[1] + red[3];

  const long obase = ((long)(b*HH + h)*SS + s)*128 + d;
  q_t[obase] = (bf16_t)(aq * rsqrtf(sumq + 1e-6f) * 0.08838834764831845f);  // * DK^-0.5
  k_t[obase] = (bf16_t)(ak * rsqrtf(sumk + 1e-6f));
  v_t[obase] = (bf16_t)av;
}

// ---------------------------------------------------------------------------
// Phase A (per bh,chunk): build Tp/Aq/TV/KTs/pv/PC into cdata.
// Elimination replaced by block-triangular inversion:
//   diag 16x16 inverses wave-local (0 barriers), off-diag via 3 staged
//   f32 block products (6 barriers total vs 63).
// ---------------------------------------------------------------------------
__global__ __launch_bounds__(256) void chunkA_kernel(
    const bf16_t* __restrict__ q_t, const bf16_t* __restrict__ k_t,
    const bf16_t* __restrict__ v_t, const float2* __restrict__ gb_t,
    char* __restrict__ cdata)
{
  extern __shared__ char smem[];
  bf16_t* lK  = (bf16_t*)(smem);            // [64][136]
  bf16_t* lQV = (bf16_t*)(smem + 17408);    // lQ [64][136], later lVT [128][72]
  float*  lLf = (float*)(smem + 35840);     // [64][65]   M = I + Lf (strict-lower stored)
  float*  lXf = (float*)(smem + 52480);     // [64][65]   T' = M^{-1}
  float*  gcv = (float*)(smem + 69120);     // [64]
  float*  pvv = (float*)(smem + 69376);     // [64]
  float*  bvv = (float*)(smem + 69632);     // [64]
  float*  evv = (float*)(smem + 69888);     // [64] exp(gc_63 - gc_i)
  float*  lP  = (float*)(smem + 70144);     // [3][16][17] f32 scratch

  const int cd = blockIdx.x;
  const int bh = cd >> 5, c = cd & 31;
  const int t = threadIdx.x;
  const int lane = t & 63, w = t >> 6;
  const int fr = lane & 15, fq = lane >> 4;

  const bf16_t* kg = k_t + ((long)bh*SS + c*CH)*128;
  const bf16_t* qg = q_t + ((long)bh*SS + c*CH)*128;
  const bf16_t* vg = v_t + ((long)bh*SS + c*CH)*128;
  char* cdp = cdata + (long)cd*CD_STRIDE;

  // stage K, Q (lQV as lQ)
  #pragma unroll
  for (int ib=0; ib<4; ib++) {
    int e0 = (t + 256*ib)*8;
    int r = e0 >> 7, cc = e0 & 127;
    *(bf16x8*)&lK[r*136+cc]  = *(const bf16x8*)(kg + e0);
    *(bf16x8*)&lQV[r*136+cc] = *(const bf16x8*)(qg + e0);
  }
  if (t < 64) {
    float2 gb = gb_t[(long)bh*SS + c*CH + t];
    gcv[t] = gb.x;
    bvv[t] = gb.y;
  }
  __syncthreads();
  // wave-parallel inclusive scan of gcv (wave 0)
  if (t < 64) {
    float g = gcv[t];
    #pragma unroll
    for (int off=1; off<64; off<<=1) {
      float n = __shfl_up(g, off);
      if (lane >= off) g += n;
    }
    gcv[t] = g;
  }
  __syncthreads();
  if (t < 64) {
    pvv[t] = expf(gcv[t]);
    evv[t] = expf(gcv[63] - gcv[t]);
  }

  // G = K K^T, Gq = Q K^T  (wave strip rows 16w)
  {
    f32x4 accG[4], accQ[4];
    #pragma unroll
    for (int tn=0;tn<4;tn++){ accG[tn]=(f32x4){0,0,0,0}; accQ[tn]=(f32x4){0,0,0,0}; }
    #pragma unroll
    for (int ks=0;ks<4;ks++) {
      bf16x8 aK = *(const bf16x8*)&lK[(w*16+fr)*136 + fq*8 + ks*32];
      bf16x8 aQ = *(const bf16x8*)&lQV[(w*16+fr)*136 + fq*8 + ks*32];
      #pragma unroll
      for (int tn=0;tn<4;tn++) {
        bf16x8 bK = *(const bf16x8*)&lK[(tn*16+fr)*136 + fq*8 + ks*32];
        accG[tn] = MFMA16(aK, bK, accG[tn]);
        accQ[tn] = MFMA16(aQ, bK, accQ[tn]);
      }
    }
    bf16_t* aqg = (bf16_t*)(cdp + CD_AQ);
    #pragma unroll
    for (int tn=0;tn<4;tn++) {
      #pragma unroll
      for (int r=0;r<4;r++) {
        int tt = w*16 + fq*4 + r;
        int ii = tn*16 + fr;
        float er = expf(gcv[tt] - gcv[ii]);
        lLf[tt*65 + ii] = (ii < tt) ? bvv[tt]*er*accG[tn][r] : 0.f;
        aqg[tt*64 + ii] = (bf16_t)((ii <= tt) ? er*accQ[tn][r] : 0.f);
      }
    }
  }

  // ---- phase 1 (wave-local, NO barriers): diag 16x16 unit-lower inverse ----
  {
    const int a = w;
    float* Ub = lXf + (a*16)*65 + a*16;           // U_a[i*65 + c]
    const float* Lb = lLf + (a*16)*65 + a*16;     // M_aa (unit diag implied)
    if (lane < 16) Ub[lane] = (lane == 0) ? 1.f : 0.f;   // row 0 of identity
    // zero this wave's upper-right blocks of lXf (rows 16a.., cols 16(a+1)..63)
    for (int bb = a+1; bb < 4; bb++)
      for (int e = lane; e < 256; e += 64)
        lXf[(a*16 + (e>>4))*65 + bb*16 + (e&15)] = 0.f;
    if (lane < 16) {
      const int cc = lane;   // lane owns column cc — no cross-lane deps
      for (int i=1; i<16; i++) {
        float s = 0.f;
        for (int j=0; j<i; j++) s += Lb[i*65+j] * Ub[j*65+cc];
        Ub[i*65+cc] = ((i==cc)?1.f:0.f) - s;
      }
    }
  }
  __syncthreads();   // publish lLf strips, U_a, zeros; lQV reads done

  // stage V^T into lQV with staggered element order (kills 16-way conflicts)
  bf16_t* lVT = lQV;   // [128][72]
  {
    const int m = t & 15;
    #pragma unroll
    for (int ib=0; ib<4; ib++) {
      int e0 = (t + 256*ib)*8;
      int r = e0 >> 7, cc = e0 & 127;
      bf16x8 v8 = *(const bf16x8*)(vg + e0);
      #pragma unroll
      for (int e=0;e<8;e++) {
        int ee = (e + m) & 7;
        lVT[(cc+ee)*72 + r] = v8[ee];
      }
    }
  }

  // ---- phase 2: T_ab for a=b+1 : T = -U_a (M_ab U_b) ----
  {
    const int i = t >> 4, j = t & 15;
    #pragma unroll
    for (int bb=0; bb<3; bb++) {
      float s = 0.f;
      const float* Mrow = lLf + ((bb+1)*16 + i)*65 + bb*16;
      const float* Ucol = lXf + (bb*16)*65 + bb*16 + j;
      #pragma unroll
      for (int k=0;k<16;k++) s += Mrow[k] * Ucol[k*65];
      lP[bb*272 + i*17 + j] = s;
    }
  }
  __syncthreads();
  {
    const int i = t >> 4, j = t & 15;
    #pragma unroll
    for (int bb=0; bb<3; bb++) {
      float s = 0.f;
      const float* Urow = lXf + ((bb+1)*16 + i)*65 + (bb+1)*16;
      const float* Pcol = lP + bb*272 + j;
      #pragma unroll
      for (int k=0;k<16;k++) s += Urow[k] * Pcol[k*17];
      lXf[((bb+1)*16 + i)*65 + bb*16 + j] = -s;
    }
  }
  __syncthreads();
  // ---- phase 3: a=b+2 : T = -U_a (M_ab U_b + M_a,b+1 T_{b+1,b}) ----
  {
    const int i = t >> 4, j = t & 15;
    #pragma unroll
    for (int bb=0; bb<2; bb++) {
      float s = 0.f;
      const float* M0 = lLf + ((bb+2)*16 + i)*65 + bb*16;
      const float* U0 = lXf + (bb*16)*65 + bb*16 + j;
      const float* M1 = lLf + ((bb+2)*16 + i)*65 + (bb+1)*16;
      const float* T1 = lXf + ((bb+1)*16)*65 + bb*16 + j;
      #pragma unroll
      for (int k=0;k<16;k++) s += M0[k]*U0[k*65] + M1[k]*T1[k*65];
      lP[bb*272 + i*17 + j] = s;
    }
  }
  __syncthreads();
  {
    const int i = t >> 4, j = t & 15;
    #pragma unroll
    for (int bb=0; bb<2; bb++) {
      float s = 0.f;
      const float* Urow = lXf + ((bb+2)*16 + i)*65 + (bb+2)*16;
      const float* Pcol = lP + bb*272 + j;
      #pragma unroll
      for (int k=0;k<16;k++) s += Urow[k] * Pcol[k*17];
      lXf[((bb+2)*16 + i)*65 + bb*16 + j] = -s;
    }
  }
  __syncthreads();
  // ---- phase 4: (3,0) : T = -U_3 (M_30 U_0 + M_31 T_10 + M_32 T_20) ----
  {
    const int i = t >> 4, j = t & 15;
    float s = 0.f;
    const float* M0 = lLf + (48 + i)*65 + 0;
    const float* U0 = lXf + 0*65 + j;
    const float* M1 = lLf + (48 + i)*65 + 16;
    const float* T1 = lXf + 16*65 + j;
    const float* M2 = lLf + (48 + i)*65 + 32;
    const float* T2 = lXf + 32*65 + j;
    #pragma unroll
    for (int k=0;k<16;k++) s += M0[k]*U0[k*65] + M1[k]*T1[k*65] + M2[k]*T2[k*65];
    lP[i*17 + j] = s;
  }
  __syncthreads();
  {
    const int i = t >> 4, j = t & 15;
    float s = 0.f;
    const float* Urow = lXf + (48 + i)*65 + 48;
    const float* Pcol = lP + j;
    #pragma unroll
    for (int k=0;k<16;k++) s += Urow[k] * Pcol[k*17];
    lXf[(48 + i)*65 + j] = -s;
  }
  __syncthreads();

  // Tp store + bf16 copy of Tmat = T' diag(b)  (reuse lLf region)
  bf16_t* lXb = (bf16_t*)lLf;   // [64][72]
  {
    bf16_t* tpg = (bf16_t*)(cdp + CD_TP);
    #pragma unroll
    for (int ib=0; ib<16; ib++) {
      int idx = t + ib*256; int r = idx>>6, cc = idx&63;
      float xv = lXf[r*65+cc] * bvv[cc];
      tpg[r*64+cc] = (bf16_t)(xv * pvv[cc]);
      lXb[r*72+cc] = (bf16_t)xv;
    }
  }
  __syncthreads();

  // TV = Tmat @ V : C[t][dv] = sum_i Xb[t][i] * VT[dv][i]
  {
    f32x4 acc[8];
    #pragma unroll
    for (int tn=0;tn<8;tn++) acc[tn]=(f32x4){0,0,0,0};
    #pragma unroll
    for (int ks=0;ks<2;ks++) {
      bf16x8 aX = *(const bf16x8*)&lXb[(w*16+fr)*72 + fq*8 + ks*32];
      #pragma unroll
      for (int tn=0;tn<8;tn++) {
        bf16x8 bV = *(const bf16x8*)&lVT[(tn*16+fr)*72 + fq*8 + ks*32];
        acc[tn] = MFMA16(aX, bV, acc[tn]);
      }
    }
    bf16_t* tvg = (bf16_t*)(cdp + CD_TV);
    #pragma unroll
    for (int tn=0;tn<8;tn++)
      #pragma unroll
      for (int r=0;r<4;r++) {
        int tt = w*16 + fq*4 + r, dv = tn*16 + fr;
        tvg[tt*128 + dv] = (bf16_t)acc[tn][r];
      }
  }

  // KTs[dk][i] = K[i][dk] * exp(gc_C - gc_i)   (shared exp table)
  {
    bf16_t* ktg = (bf16_t*)(cdp + CD_KTS);
    int dk = t >> 1, c0 = (t & 1)*32;
    bf16_t tmp[32];
    #pragma unroll
    for (int i2=0;i2<32;i2++) {
      int i = c0 + i2;
      tmp[i2] = (bf16_t)((float)lK[i*136 + dk] * evv[i]);
    }
    #pragma unroll
    for (int s8=0;s8<4;s8++)
      *(bf16x8*)&ktg[dk*64 + c0 + s8*8] = *(bf16x8*)&tmp[s8*8];
  }
  if (t < 64) ((float*)(cdp + CD_PV))[t] = pvv[t];
  if (t == 0) *((float*)(cdp + CD_PC)) = expf(gcv[63]);
}

// ---------------------------------------------------------------------------
// Phase S (serial over 32 chunks; 256 blocks = 32 bh x 8 dv-splits of 16):
//   X=K S; Xq=Q S (store); D = TV - Tp X (store D^T); S = PC*S + KTs D
// Pipelined: chunk c+1's K/Q/Tp/KTs loaded to regs at top of chunk c,
// written to LDS in the tail phase (staging off the serial path).
// ---------------------------------------------------------------------------
__global__ __launch_bounds__(256) void chunkS_kernel(
    const bf16_t* __restrict__ q_t, const bf16_t* __restrict__ k_t,
    const char* __restrict__ cdata, bf16_t* __restrict__ gD,
    bf16_t* __restrict__ gXq)
{
  extern __shared__ char smem[];
  float*  lS  = (float*)(smem);              // [16][129] f32  S^T slice [dv][dk]
  bf16_t* lSb = (bf16_t*)(smem + 8320);      // [16][136] bf16
  bf16_t* lK  = (bf16_t*)(smem + 12672);     // [64][136]
  bf16_t* lQ  = (bf16_t*)(smem + 30080);     // [64][136]
  bf16_t* lTp = (bf16_t*)(smem + 47488);     // [64][72]
  bf16_t* lKT = (bf16_t*)(smem + 56704);     // [128][72]
  bf16_t* lXT = (bf16_t*)(smem + 75136);     // [16][88]  X^T [dv][t]
  bf16_t* lDT = (bf16_t*)(smem + 77952);     // [16][88]  D^T [dv][t]

  const int bid = blockIdx.x;
  const int lb  = (bid & 7)*32 + (bid >> 3);   // same-bh blocks on one XCD
  const int bh = lb >> 3, sp = lb & 7;
  const int dv0 = sp*16;
  const int t = threadIdx.x, lane = t & 63, w = t >> 6;
  const int fr = lane & 15, fq = lane >> 4;

  #pragma unroll
  for (int ib=0; ib<8; ib++) {
    int idx = t + ib*256; int r = idx>>7, cc = idx&127;
    lS[r*129+cc] = 0.f;
    lSb[r*136+cc] = (bf16_t)0.f;
  }

  const bf16_t* kg = k_t + (long)bh*SS*128;
  const bf16_t* qg = q_t + (long)bh*SS*128;

  bf16x8 kr0,kr1,kr2,kr3, qr0,qr1,qr2,qr3, kt0,kt1,kt2,kt3, tp0,tp1;

#define STAGE_LOAD(CSRC)                                                       \
  {                                                                            \
    const char* cdl = cdata + (long)(bh*NCH + (CSRC))*CD_STRIDE;               \
    const bf16_t* kl = kg + (long)(CSRC)*CH*128;                               \
    const bf16_t* ql = qg + (long)(CSRC)*CH*128;                               \
    const bf16_t* ktl = (const bf16_t*)(cdl + CD_KTS);                         \
    const bf16_t* tpl = (const bf16_t*)(cdl + CD_TP);                          \
    int e0 = t*8, e1 = (t+256)*8, e2 = (t+512)*8, e3 = (t+768)*8;              \
    kr0 = *(const bf16x8*)(kl + e0); kr1 = *(const bf16x8*)(kl + e1);          \
    kr2 = *(const bf16x8*)(kl + e2); kr3 = *(const bf16x8*)(kl + e3);          \
    qr0 = *(const bf16x8*)(ql + e0); qr1 = *(const bf16x8*)(ql + e1);          \
    qr2 = *(const bf16x8*)(ql + e2); qr3 = *(const bf16x8*)(ql + e3);          \
    kt0 = *(const bf16x8*)(ktl + e0); kt1 = *(const bf16x8*)(ktl + e1);        \
    kt2 = *(const bf16x8*)(ktl + e2); kt3 = *(const bf16x8*)(ktl + e3);        \
    tp0 = *(const bf16x8*)(tpl + e0); tp1 = *(const bf16x8*)(tpl + e1);        \
  }

#define STAGE_WRITE()                                                          \
  {                                                                            \
    int e0 = t*8, e1 = (t+256)*8, e2 = (t+512)*8, e3 = (t+768)*8;              \
    *(bf16x8*)&lK[(e0>>7)*136 + (e0&127)] = kr0;                               \
    *(bf16x8*)&lK[(e1>>7)*136 + (e1&127)] = kr1;                               \
    *(bf16x8*)&lK[(e2>>7)*136 + (e2&127)] = kr2;                               \
    *(bf16x8*)&lK[(e3>>7)*136 + (e3&127)] = kr3;                               \
    *(bf16x8*)&lQ[(e0>>7)*136 + (e0&127)] = qr0;                               \
    *(bf16x8*)&lQ[(e1>>7)*136 + (e1&127)] = qr1;                               \
    *(bf16x8*)&lQ[(e2>>7)*136 + (e2&127)] = qr2;                               \
    *(bf16x8*)&lQ[(e3>>7)*136 + (e3&127)] = qr3;                               \
    *(bf16x8*)&lKT[(e0>>6)*72 + (e0&63)] = kt0;                                \
    *(bf16x8*)&lKT[(e1>>6)*72 + (e1&63)] = kt1;                                \
    *(bf16x8*)&lKT[(e2>>6)*72 + (e2&63)] = kt2;                                \
    *(bf16x8*)&lKT[(e3>>6)*72 + (e3&63)] = kt3;                                \
    *(bf16x8*)&lTp[(e0>>6)*72 + (e0&63)] = tp0;                                \
    *(bf16x8*)&lTp[(e1>>6)*72 + (e1&63)] = tp1;                                \
  }

  STAGE_LOAD(0);
  STAGE_WRITE();
  __syncthreads();

  for (int c=0; c<NCH; c++) {
    const int cd = bh*NCH + c;
    const char* cdp = cdata + (long)cd*CD_STRIDE;

    // TV quad + PC for current chunk (issued FIRST so their wait doesn't
    // drain the prefetch queue)
    float tvq0, tvq1, tvq2, tvq3, pc;
    {
      const bf16_t* tvp = (const bf16_t*)(cdp + CD_TV);
      tvq0 = (float)tvp[(w*16+fq*4+0)*128 + dv0 + fr];
      tvq1 = (float)tvp[(w*16+fq*4+1)*128 + dv0 + fr];
      tvq2 = (float)tvp[(w*16+fq*4+2)*128 + dv0 + fr];
      tvq3 = (float)tvp[(w*16+fq*4+3)*128 + dv0 + fr];
      pc = *(const float*)(cdp + CD_PC);
    }
    // issue prefetch of chunk c+1 (clamped) into regs
    const int cn = (c+1 < NCH) ? c+1 : c;
    STAGE_LOAD(cn);

    // X = K S^T-slice, Xq = Q S^T-slice  (M=64, N=16, K=128)
    f32x4 aX = {0,0,0,0}, aXq = {0,0,0,0};
    #pragma unroll
    for (int ks=0; ks<4; ks++) {
      bf16x8 bS = *(const bf16x8*)&lSb[fr*136 + fq*8 + ks*32];
      bf16x8 aK = *(const bf16x8*)&lK[(w*16+fr)*136 + fq*8 + ks*32];
      bf16x8 aQ = *(const bf16x8*)&lQ[(w*16+fr)*136 + fq*8 + ks*32];
      aX  = MFMA16(aK, bS, aX);
      aXq = MFMA16(aQ, bS, aXq);
    }
    #pragma unroll
    for (int r=0;r<4;r++)
      lXT[fr*88 + (w*16+fq*4+r)] = (bf16_t)aX[r];
    __syncthreads();   // A

    // D = TV - Tp X  (M=64, N=16, K=64); also scale lS by PC
    {
      f32x4 aD = {0,0,0,0};
      #pragma unroll
      for (int ks=0; ks<2; ks++) {
        bf16x8 aT = *(const bf16x8*)&lTp[(w*16+fr)*72 + fq*8 + ks*32];
        bf16x8 bX = *(const bf16x8*)&lXT[fr*88 + fq*8 + ks*32];
        aD = MFMA16(aT, bX, aD);
      }
      lDT[fr*88 + (w*16+fq*4+0)] = (bf16_t)(tvq0 - aD[0]);
      lDT[fr*88 + (w*16+fq*4+1)] = (bf16_t)(tvq1 - aD[1]);
      lDT[fr*88 + (w*16+fq*4+2)] = (bf16_t)(tvq2 - aD[2]);
      lDT[fr*88 + (w*16+fq*4+3)] = (bf16_t)(tvq3 - aD[3]);
    }
    #pragma unroll
    for (int ib=0; ib<8; ib++) {
      int idx = t + ib*256; int r = idx>>7, cc = idx&127;
      lS[r*129+cc] *= pc;
    }
    __syncthreads();   // B

    // S^T += D^T KTs^T : C[dv][dk] = sum_i D^T[dv][i]*KTs[dk][i]
    {
      f32x4 aS0 = {0,0,0,0}, aS1 = {0,0,0,0};
      #pragma unroll
      for (int ks=0; ks<2; ks++) {
        bf16x8 aDd = *(const bf16x8*)&lDT[fr*88 + fq*8 + ks*32];
        bf16x8 bK0 = *(const bf16x8*)&lKT[(w*32+fr)*72 + fq*8 + ks*32];
        bf16x8 bK1 = *(const bf16x8*)&lKT[(w*32+16+fr)*72 + fq*8 + ks*32];
        aS0 = MFMA16(aDd, bK0, aS0);
        aS1 = MFMA16(aDd, bK1, aS1);
      }
      #pragma unroll
      for (int r=0;r<4;r++) {
        lS[(fq*4+r)*129 + w*32 + fr]      += aS0[r];
        lS[(fq*4+r)*129 + w*32 + 16 + fr] += aS1[r];
      }
    }
    // global stores: Xq and D^T
    #pragma unroll
    for (int r=0;r<4;r++)
      gXq[((long)cd*CH + w*16+fq*4+r)*128 + dv0 + fr] = (bf16_t)aXq[r];
    {
      int dvl = t >> 4, off = (t & 15)*4;
      *(bf16x4*)(gD + ((long)cd*128 + dv0 + dvl)*64 + off) =
          *(const bf16x4*)&lDT[dvl*88 + off];
    }
    __syncthreads();   // C

    // write staged c+1 into LDS; cast lSb = bf16(lS)
    STAGE_WRITE();
    #pragma unroll
    for (int ib=0; ib<8; ib++) {
      int idx = t + ib*256; int r = idx>>7, cc = idx&127;
      lSb[r*136+cc] = (bf16_t)lS[r*129+cc];
    }
    __syncthreads();   // D
  }
#undef STAGE_LOAD
#undef STAGE_WRITE
}

// ---------------------------------------------------------------------------
// Phase O (parallel, per chunk): O = diag(p) Xq + Aq D  -> obuf
// ---------------------------------------------------------------------------
__global__ __launch_bounds__(256) void chunkO_kernel(
    const char* __restrict__ cdata, const bf16_t* __restrict__ gD,
    const bf16_t* __restrict__ gXq, bf16_t* __restrict__ obuf)
{
  const int cd = blockIdx.x;
  const int bh = cd >> 5, c = cd & 31;
  const int b = bh >> 4, h = bh & 15;
  const int t = threadIdx.x, lane = t & 63, w = t >> 6;
  const int fr = lane & 15, fq = lane >> 4;

  const char* cdp = cdata + (long)cd*CD_STRIDE;
  const bf16_t* aqp = (const bf16_t*)(cdp + CD_AQ);   // [64][64]
  const bf16_t* dp  = gD + (long)cd*128*64;           // [128 dv][64 t]
  const float*  pvp = (const float*)(cdp + CD_PV);

  f32x4 acc[8];
  #pragma unroll
  for (int tn=0;tn<8;tn++) acc[tn]=(f32x4){0,0,0,0};
  #pragma unroll
  for (int ks=0;ks<2;ks++) {
    bf16x8 aA = *(const bf16x8*)(aqp + (w*16+fr)*64 + fq*8 + ks*32);
    #pragma unroll
    for (int tn=0;tn<8;tn++) {
      bf16x8 bD = *(const bf16x8*)(dp + (tn*16+fr)*64 + fq*8 + ks*32);
      acc[tn] = MFMA16(aA, bD, acc[tn]);
    }
  }
  #pragma unroll
  for (int tn=0;tn<8;tn++)
    #pragma unroll
    for (int r=0;r<4;r++) {
      int tt = w*16+fq*4+r, dv = tn*16+fr;
      float ov = pvp[tt]*(float)gXq[((long)cd*CH + tt)*128 + dv] + acc[tn][r];
      obuf[((long)(b*SS + c*CH + tt)*HH + h)*128 + dv] = (bf16_t)ov;
    }
}

// ---------------------------------------------------------------------------
// RMSNorm over DV + (1+nw) + silu(z) gate; z from zbuf (stride ZN)
// ---------------------------------------------------------------------------
__global__ __launch_bounds__(128) void norm_gate_kernel(
    const bf16_t* __restrict__ o, const bf16_t* __restrict__ zfull,
    const float* __restrict__ nw, bf16_t* __restrict__ og)
{
  const long row = blockIdx.x;      // (b*S+s)*H + h
  const long tok = row >> 4;
  const int h = row & 15;
  const int d = threadIdx.x;
  float x = (float)o[row*128 + d];
  float ss = x*x;
  #pragma unroll
  for (int off=32; off>=1; off>>=1) ss += __shfl_xor(ss, off);
  __shared__ float red[2];
  if ((d & 63) == 0) red[d>>6] = ss;
  __syncthreads();
  float mean = (red[0] + red[1]) * (1.f/128.f);
  float zn = (float)zfull[tok*ZN + h*128 + d];
  float val = x * rsqrtf(mean + 1e-6f) * (1.f + nw[d]) * (zn * (1.f/(1.f+expf(-zn))));
  og[row*128 + d] = (bf16_t)val;
}

// ---------------------------------------------------------------------------
extern "C" void kernel_launch(void* const* d_in, const int* in_sizes, int n_in,
                              void* d_out, int out_size, void* d_ws, size_t ws_size,
                              hipStream_t stream)
{
  const float* hs    = (const float*)d_in[0];
  const float* amask = (const float*)d_in[1];
  const float* Wqkv  = (const float*)d_in[2];
  const float* convw = (const float*)d_in[3];
  const float* convb = (const float*)d_in[4];
  const float* Wz    = (const float*)d_in[5];
  const float* Wb    = (const float*)d_in[6];
  const float* Wa    = (const float*)d_in[7];
  const float* dtb   = (const float*)d_in[8];
  const float* Alog  = (const float*)d_in[9];
  const float* nw    = (const float*)d_in[10];
  const float* Wout  = (const float*)d_in[11];

  const size_t MB = 1024*1024;
  char* p = (char*)d_ws;
  auto alloc = [&](size_t bytes) { char* r = p; p += (bytes + 255) & ~(size_t)255; return r; };
  bf16_t* x_bf   = (bf16_t*)alloc(16*MB);   // x_bf; later gD [1024][128][64]
  char*   bigreg = alloc(72*MB);            // wqkv@0, mixed@24MB; later cdata@0, obuf@52MB
  bf16_t* wz_bf  = (bf16_t*)alloc(10*MB);   // Wz rows + W_b/W_a rows @8MB; later Wout@0
  bf16_t* zbuf   = (bf16_t*)alloc(19*MB);   // [4096][2304]
  bf16_t* q_t    = (bf16_t*)alloc(16*MB);   // q; later og
  bf16_t* k_t    = (bf16_t*)alloc(16*MB);
  bf16_t* v_t    = (bf16_t*)alloc(16*MB);   // v; later gXq [1024][64][128]
  float2* gb_t   = (float2*)alloc((size_t)BB*HH*SS*8);
  size_t need = (size_t)(p - (char*)d_ws);
  if (ws_size < need) return;   // clean fail (absmax = poison)

  bf16_t* wqkv_bf = (bf16_t*)bigreg;
  bf16_t* mixed   = (bf16_t*)(bigreg + 24*MB);
  char*   cdata   = bigreg;                       // after GEMM1+conv consumed
  bf16_t* obuf    = (bf16_t*)(bigreg + 52*MB);    // cdata ends at ~48.5MB
  bf16_t* wout_bf = wz_bf;                        // cast after z-GEMM (rows 0..2047 only)
  bf16_t* gD      = x_bf;                         // after z-GEMM consumed x_bf
  bf16_t* gXq     = v_t;                          // after chunkA consumed v_t
  bf16_t* og      = q_t;                          // after chunkS consumed q_t

  cast_x_kernel<<<2048, 256, 0, stream>>>(hs, amask, x_bf, (long)MM*DD);
  cast_w_kernel<<<2048, 256, 0, stream>>>(Wqkv, wqkv_bf, (long)CONVC*DD);
  cast_w_kernel<<<1024, 256, 0, stream>>>(Wz,   wz_bf,   (long)DD*DD);
  cast_ba_kernel<<<64, 256, 0, stream>>>(Wb, Wa, wz_bf + (size_t)DD*DD);

  gemm256<true><<<384, 512, 131072, stream>>>(x_bf, wqkv_bf, mixed, MM, CONVC, DD, 24);

  conv_norm_kernel<<<BB*HH*SS, 128, 0, stream>>>(mixed, convw, convb, q_t, k_t, v_t);

  gemm256<true><<<144, 512, 131072, stream>>>(x_bf, wz_bf, zbuf, MM, ZN, DD, 9);
  cast_w_kernel<<<1024, 256, 0, stream>>>(Wout, wout_bf, (long)DD*DD);
  betag2_kernel<<<256, 256, 0, stream>>>(zbuf, dtb, Alog, gb_t);

  chunkA_kernel<<<BB*HH*NCH, 256, 73408, stream>>>(q_t, k_t, v_t, gb_t, cdata);
  chunkS_kernel<<<BB*HH*8, 256, 80768, stream>>>(q_t, k_t, cdata, gD, gXq);
  chunkO_kernel<<<BB*HH*NCH, 256, 0, stream>>>(cdata, gD, gXq, obuf);

  norm_gate_kernel<<<MM*HH, 128, 0, stream>>>(obuf, zbuf, nw, og);

  gemm256<false><<<128, 512, 131072, stream>>>(og, wout_bf, d_out, MM, DD, DD, 8);
}

// Round 12
// 506.540 us; speedup vs baseline: 1.6030x; 1.0191x over previous
//
#include <hip/hip_runtime.h>
#include <hip/hip_bf16.h>
#include <math.h>

// Problem constants
#define BB 2
#define SS 2048
#define DD 2048
#define HH 16
#define CONVC 6144
#define MM (BB*SS)   // 4096 tokens
#define ZN 2304      // z-GEMM N: 2048 z cols + 16 W_b + 16 W_a + 224 pad

// chunked delta-rule constants
#define CH 64        // chunk length
#define NCH 32       // chunks per sequence
#define CD_KTS 0
#define CD_TV  16384
#define CD_TP  32768
#define CD_AQ  40960
#define CD_PV  49152
#define CD_PC  49408
#define CD_STRIDE 49664

typedef __bf16 bf16_t;
typedef __bf16 bf16x8 __attribute__((ext_vector_type(8)));
typedef __bf16 bf16x4 __attribute__((ext_vector_type(4)));
typedef float  f32x4  __attribute__((ext_vector_type(4)));

#define GLOBAL_AS __attribute__((address_space(1)))
#define LDS_AS    __attribute__((address_space(3)))

#define MFMA16(a,b,c) __builtin_amdgcn_mfma_f32_16x16x32_bf16((a),(b),(c),0,0,0)

// ---------------------------------------------------------------------------
// Cast kernels
// ---------------------------------------------------------------------------
__global__ __launch_bounds__(256) void cast_x_kernel(
    const float* __restrict__ in, const float* __restrict__ mask,
    bf16_t* __restrict__ out, long n)
{
  long n4 = n >> 2;
  for (long i = (long)blockIdx.x*256 + threadIdx.x; i < n4; i += (long)gridDim.x*256) {
    float4 v = ((const float4*)in)[i];
    float m = mask[(i*4) / DD];
    bf16x4 o4;
    o4[0]=(bf16_t)(v.x*m); o4[1]=(bf16_t)(v.y*m);
    o4[2]=(bf16_t)(v.z*m); o4[3]=(bf16_t)(v.w*m);
    ((bf16x4*)out)[i] = o4;
  }
}

__global__ __launch_bounds__(256) void cast_w_kernel(
    const float* __restrict__ in, bf16_t* __restrict__ out, long n)
{
  long n4 = n >> 2;
  for (long i = (long)blockIdx.x*256 + threadIdx.x; i < n4; i += (long)gridDim.x*256) {
    float4 v = ((const float4*)in)[i];
    bf16x4 o4;
    o4[0]=(bf16_t)v.x; o4[1]=(bf16_t)v.y; o4[2]=(bf16_t)v.z; o4[3]=(bf16_t)v.w;
    ((bf16x4*)out)[i] = o4;
  }
}

// append W_b (16x2048) then W_a (16x2048) as bf16 rows after the Wz rows
__global__ __launch_bounds__(256) void cast_ba_kernel(
    const float* __restrict__ Wb, const float* __restrict__ Wa,
    bf16_t* __restrict__ out)   // out = wz_bf + 2048*2048
{
  int i = blockIdx.x*256 + threadIdx.x;   // 16384 threads, 4 elems each
  int j = i*4;
  const float* src = (j < 32768) ? (Wb + j) : (Wa + j - 32768);
  float4 v = *(const float4*)src;
  bf16x4 o4;
  o4[0]=(bf16_t)v.x; o4[1]=(bf16_t)v.y; o4[2]=(bf16_t)v.z; o4[3]=(bf16_t)v.w;
  *(bf16x4*)(out + j) = o4;
}

// ---------------------------------------------------------------------------
// 256x128 2-phase-per-K-tile bf16 GEMM: C[M,N] = A[M,K] * B[N,K]^T
// 512 thr / 8 waves (2M x 4N), wave tile 128x32 (acc[8][2]), BK=64.
// LDS 96KB: A dbuf 2x32KB @0, B dbuf 2x16KB @65536.
// Per phase: stage 3 next-tile loads (A-kh 2, B-kh 1); vmcnt(3) each phase.
// st_16x32 swizzle identical to 256^2 version (same 1024B subtile layout).
// Grid: nbm x nbn with group-of-4 bm interleave for L2 locality.
// ---------------------------------------------------------------------------
template<bool OUT_BF16>
__global__ __launch_bounds__(512) void gemm256(
    const bf16_t* __restrict__ A, const bf16_t* __restrict__ Bm,
    void* __restrict__ Cp, int M, int N, int K, int nbn)
{
  extern __shared__ char gsm[];
  const int t    = threadIdx.x;
  const int lane = t & 63;
  const int wid  = t >> 6;
  const int wm   = wid >> 2, wn = wid & 3;
  const int fr   = lane & 15, fq = lane >> 4;

  // XCD-aware swizzle + group-of-4 bm interleave
  const int nwg = gridDim.x;
  const int wg  = ((int)blockIdx.x & 7)*(nwg >> 3) + ((int)blockIdx.x >> 3);
  const int grp = wg / (nbn*4);
  const int rem = wg - grp*(nbn*4);
  const long bm = grp*4 + (rem & 3);
  const long bn = rem >> 2;

  // staging decode: linear 16B chunk L -> (row,col) via inverse st_16x32 swizzle
  int rowS[2], colS[2];
  #pragma unroll
  for (int i=0;i<2;i++) {
    int L  = (i*512 + t)*16;
    int Ls = L ^ (((L>>9)&1)<<5);
    rowS[i] = (Ls>>10)*16 + ((Ls&1023)>>6);
    colS[i] = (Ls&63)>>1;
  }
  const bf16_t* Ab = A  + (bm*256)*(long)K;
  const bf16_t* Bb = Bm + (bn*128)*(long)K;

  f32x4 acc[8][2];
  #pragma unroll
  for (int i=0;i<8;i++) { acc[i][0] = (f32x4){0,0,0,0}; acc[i][1] = (f32x4){0,0,0,0}; }

  const int aoff = fr*64 + ((fq*16) ^ ((fr&8)<<2));  // swizzled frag byte offset

  auto stageA = [&](int buf, int kh, int kt) {
    char* dst0 = gsm + buf*32768 + kh*16384 + t*16;
    #pragma unroll
    for (int i=0;i<2;i++) {
      const bf16_t* src = Ab + (long)rowS[i]*K + kt*64 + kh*32 + colS[i];
      __builtin_amdgcn_global_load_lds((const GLOBAL_AS void*)src,
          (LDS_AS void*)(dst0 + i*8192), 16, 0, 0);
    }
  };
  auto stageB = [&](int buf, int kh, int kt) {
    char* dst = gsm + 65536 + buf*16384 + kh*8192 + t*16;
    const bf16_t* src = Bb + (long)rowS[0]*K + kt*64 + kh*32 + colS[0];
    __builtin_amdgcn_global_load_lds((const GLOBAL_AS void*)src,
        (LDS_AS void*)dst, 16, 0, 0);
  };

  // prologue: stage tile 0 into buffer 0, consumption order
  stageA(0,0,0); stageB(0,0,0); stageA(0,1,0); stageB(0,1,0);

  int cb = 0;
  const int KT = K >> 6;
  for (int kt=0; kt<KT; ++kt) {
    const int ktn = (kt+1 < KT) ? kt+1 : kt;
    const char* abuf = gsm + cb*32768;
    const char* bbuf = gsm + 65536 + cb*16384;
    bf16x8 af[8], bfr[2];

    #pragma unroll
    for (int kh=0; kh<2; kh++) {
      asm volatile("s_waitcnt vmcnt(3)" ::: "memory");
      __builtin_amdgcn_sched_barrier(0);
      __builtin_amdgcn_s_barrier();
      #pragma unroll
      for (int j=0;j<8;j++)
        af[j] = *(const bf16x8*)(abuf + kh*16384 + (wm*8+j)*1024 + aoff);
      #pragma unroll
      for (int n=0;n<2;n++)
        bfr[n] = *(const bf16x8*)(bbuf + kh*8192 + (wn*2+n)*1024 + aoff);
      stageA(cb^1, kh, ktn);
      stageB(cb^1, kh, ktn);
      __builtin_amdgcn_s_setprio(1);
      #pragma unroll
      for (int j=0;j<8;j++)
        #pragma unroll
        for (int n=0;n<2;n++)
          acc[j][n] = MFMA16(af[j], bfr[n], acc[j][n]);
      __builtin_amdgcn_s_setprio(0);
    }
    cb ^= 1;
  }
  __syncthreads();   // drain outstanding staging before exit

  #pragma unroll
  for (int mi=0;mi<8;mi++) {
    #pragma unroll
    for (int ni=0;ni<2;ni++) {
      long row = bm*256 + wm*128 + mi*16 + fq*4;
      long col = bn*128 + wn*32 + ni*16 + fr;
      #pragma unroll
      for (int r=0;r<4;r++) {
        float v = acc[mi][ni][r];
        if (OUT_BF16) ((bf16_t*)Cp)[(row+r)*(long)N + col] = (bf16_t)v;
        else          ((float*)Cp)[(row+r)*(long)N + col] = v;
      }
    }
  }
}

// ---------------------------------------------------------------------------
// betag2: read pb/pa from zbuf cols 2048..2079, compute {g, beta}
// ---------------------------------------------------------------------------
__global__ __launch_bounds__(256) void betag2_kernel(
    const bf16_t* __restrict__ zfull, const float* __restrict__ dt_bias,
    const float* __restrict__ A_log, float2* __restrict__ gb_t)
{
  int idx = blockIdx.x*256 + threadIdx.x;   // 65536 = 4096 tokens * 16 heads
  int h = idx & 15, tok = idx >> 4;
  int b = tok >> 11, s = tok & (SS-1);
  float pb = (float)zfull[(long)tok*ZN + 2048 + h];
  float pa = (float)zfull[(long)tok*ZN + 2064 + h];
  float beta = 1.f/(1.f+expf(-pb));
  float tt = pa + dt_bias[h];
  float sp = (tt > 20.f) ? tt : log1pf(expf(tt));
  float g  = -expf(A_log[h]) * sp;
  gb_t[((long)b*HH + h)*SS + s] = make_float2(g, beta);
}

// ---------------------------------------------------------------------------
// conv(K=4 causal depthwise) + bias + silu + q/k l2norm + transpose to [B,H,S,128]
// ---------------------------------------------------------------------------
__global__ __launch_bounds__(128) void conv_norm_kernel(
    const bf16_t* __restrict__ mixed, const float* __restrict__ cw,
    const float* __restrict__ cb, bf16_t* __restrict__ q_t,
    bf16_t* __restrict__ k_t, bf16_t* __restrict__ v_t)
{
  const int blk = blockIdx.x;           // (b*H+h)*S + s
  const int s = blk & (SS-1);
  const int h = (blk >> 11) & (HH-1);
  const int b = blk >> 15;
  const int d = threadIdx.x;

  const int cq = h*128 + d;
  const int ck = 2048 + cq;
  const int cv = 4096 + cq;
  float aq = cb[cq], ak = cb[ck], av = cb[cv];
  const float* wq = cw + (long)cq*4;
  const float* wk = cw + (long)ck*4;
  const float* wv = cw + (long)cv*4;
  #pragma unroll
  for (int tp=0; tp<4; ++tp) {
    int s2 = s - 3 + tp;
    if (s2 >= 0) {
      const bf16_t* rowp = mixed + ((long)b*SS + s2)*CONVC;
      aq += (float)rowp[cq] * wq[tp];
      ak += (float)rowp[ck] * wk[tp];
      av += (float)rowp[cv] * wv[tp];
    }
  }
  aq = aq * (1.f/(1.f+expf(-aq)));
  ak = ak * (1.f/(1.f+expf(-ak)));
  av = av * (1.f/(1.f+expf(-av)));

  float sq = aq*aq, sk = ak*ak;
  #pragma unroll
  for (int off=32; off>=1; off>>=1) { sq += __shfl_xor(sq, off); sk += __shfl_xor(sk, off); }
  __shared__ float red[4];
  const int wv2 = d >> 6;
  if ((d & 63) == 0) { red[wv2*2] = sq; red[wv2*2+1] = sk; }
  __syncthreads();
  float sumq = red[0] + red[2];
  float sumk = red[1] + red[3];

  const long obase = ((long)(b*HH + h)*SS + s)*128 + d;
  q_t[obase] = (bf16_t)(aq * rsqrtf(sumq + 1e-6f) * 0.08838834764831845f);  // * DK^-0.5
  k_t[obase] = (bf16_t)(ak * rsqrtf(sumk + 1e-6f));
  v_t[obase] = (bf16_t)av;
}

// ---------------------------------------------------------------------------
// Phase A (per bh,chunk): build Tp/Aq/TV/KTs/pv/PC into cdata.
// Block-triangular inversion (7 barriers), staggered V^T, exp tables.
// ---------------------------------------------------------------------------
__global__ __launch_bounds__(256) void chunkA_kernel(
    const bf16_t* __restrict__ q_t, const bf16_t* __restrict__ k_t,
    const bf16_t* __restrict__ v_t, const float2* __restrict__ gb_t,
    char* __restrict__ cdata)
{
  extern __shared__ char smem[];
  bf16_t* lK  = (bf16_t*)(smem);            // [64][136]
  bf16_t* lQV = (bf16_t*)(smem + 17408);    // lQ [64][136], later lVT [128][72]
  float*  lLf = (float*)(smem + 35840);     // [64][65]   M = I + Lf (strict-lower stored)
  float*  lXf = (float*)(smem + 52480);     // [64][65]   T' = M^{-1}
  float*  gcv = (float*)(smem + 69120);     // [64]
  float*  pvv = (float*)(smem + 69376);     // [64]
  float*  bvv = (float*)(smem + 69632);     // [64]
  float*  evv = (float*)(smem + 69888);     // [64] exp(gc_63 - gc_i)
  float*  lP  = (float*)(smem + 70144);     // [3][16][17] f32 scratch

  const int cd = blockIdx.x;
  const int bh = cd >> 5, c = cd & 31;
  const int t = threadIdx.x;
  const int lane = t & 63, w = t >> 6;
  const int fr = lane & 15, fq = lane >> 4;

  const bf16_t* kg = k_t + ((long)bh*SS + c*CH)*128;
  const bf16_t* qg = q_t + ((long)bh*SS + c*CH)*128;
  const bf16_t* vg = v_t + ((long)bh*SS + c*CH)*128;
  char* cdp = cdata + (long)cd*CD_STRIDE;

  // stage K, Q (lQV as lQ)
  #pragma unroll
  for (int ib=0; ib<4; ib++) {
    int e0 = (t + 256*ib)*8;
    int r = e0 >> 7, cc = e0 & 127;
    *(bf16x8*)&lK[r*136+cc]  = *(const bf16x8*)(kg + e0);
    *(bf16x8*)&lQV[r*136+cc] = *(const bf16x8*)(qg + e0);
  }
  if (t < 64) {
    float2 gb = gb_t[(long)bh*SS + c*CH + t];
    gcv[t] = gb.x;
    bvv[t] = gb.y;
  }
  __syncthreads();
  // wave-parallel inclusive scan of gcv (wave 0)
  if (t < 64) {
    float g = gcv[t];
    #pragma unroll
    for (int off=1; off<64; off<<=1) {
      float n = __shfl_up(g, off);
      if (lane >= off) g += n;
    }
    gcv[t] = g;
  }
  __syncthreads();
  if (t < 64) {
    pvv[t] = expf(gcv[t]);
    evv[t] = expf(gcv[63] - gcv[t]);
  }

  // G = K K^T, Gq = Q K^T  (wave strip rows 16w)
  {
    f32x4 accG[4], accQ[4];
    #pragma unroll
    for (int tn=0;tn<4;tn++){ accG[tn]=(f32x4){0,0,0,0}; accQ[tn]=(f32x4){0,0,0,0}; }
    #pragma unroll
    for (int ks=0;ks<4;ks++) {
      bf16x8 aK = *(const bf16x8*)&lK[(w*16+fr)*136 + fq*8 + ks*32];
      bf16x8 aQ = *(const bf16x8*)&lQV[(w*16+fr)*136 + fq*8 + ks*32];
      #pragma unroll
      for (int tn=0;tn<4;tn++) {
        bf16x8 bK = *(const bf16x8*)&lK[(tn*16+fr)*136 + fq*8 + ks*32];
        accG[tn] = MFMA16(aK, bK, accG[tn]);
        accQ[tn] = MFMA16(aQ, bK, accQ[tn]);
      }
    }
    bf16_t* aqg = (bf16_t*)(cdp + CD_AQ);
    #pragma unroll
    for (int tn=0;tn<4;tn++) {
      #pragma unroll
      for (int r=0;r<4;r++) {
        int tt = w*16 + fq*4 + r;
        int ii = tn*16 + fr;
        float er = expf(gcv[tt] - gcv[ii]);
        lLf[tt*65 + ii] = (ii < tt) ? bvv[tt]*er*accG[tn][r] : 0.f;
        aqg[tt*64 + ii] = (bf16_t)((ii <= tt) ? er*accQ[tn][r] : 0.f);
      }
    }
  }

  // ---- phase 1 (wave-local, NO barriers): diag 16x16 unit-lower inverse ----
  {
    const int a = w;
    float* Ub = lXf + (a*16)*65 + a*16;           // U_a[i*65 + c]
    const float* Lb = lLf + (a*16)*65 + a*16;     // M_aa (unit diag implied)
    if (lane < 16) Ub[lane] = (lane == 0) ? 1.f : 0.f;   // row 0 of identity
    for (int bb = a+1; bb < 4; bb++)
      for (int e = lane; e < 256; e += 64)
        lXf[(a*16 + (e>>4))*65 + bb*16 + (e&15)] = 0.f;
    if (lane < 16) {
      const int cc = lane;   // lane owns column cc — no cross-lane deps
      for (int i=1; i<16; i++) {
        float s = 0.f;
        for (int j=0; j<i; j++) s += Lb[i*65+j] * Ub[j*65+cc];
        Ub[i*65+cc] = ((i==cc)?1.f:0.f) - s;
      }
    }
  }
  __syncthreads();   // publish lLf strips, U_a, zeros; lQV reads done

  // stage V^T into lQV with staggered element order (kills 16-way conflicts)
  bf16_t* lVT = lQV;   // [128][72]
  {
    const int m = t & 15;
    #pragma unroll
    for (int ib=0; ib<4; ib++) {
      int e0 = (t + 256*ib)*8;
      int r = e0 >> 7, cc = e0 & 127;
      bf16x8 v8 = *(const bf16x8*)(vg + e0);
      #pragma unroll
      for (int e=0;e<8;e++) {
        int ee = (e + m) & 7;
        lVT[(cc+ee)*72 + r] = v8[ee];
      }
    }
  }

  // ---- phase 2: T_ab for a=b+1 : T = -U_a (M_ab U_b) ----
  {
    const int i = t >> 4, j = t & 15;
    #pragma unroll
    for (int bb=0; bb<3; bb++) {
      float s = 0.f;
      const float* Mrow = lLf + ((bb+1)*16 + i)*65 + bb*16;
      const float* Ucol = lXf + (bb*16)*65 + bb*16 + j;
      #pragma unroll
      for (int k=0;k<16;k++) s += Mrow[k] * Ucol[k*65];
      lP[bb*272 + i*17 + j] = s;
    }
  }
  __syncthreads();
  {
    const int i = t >> 4, j = t & 15;
    #pragma unroll
    for (int bb=0; bb<3; bb++) {
      float s = 0.f;
      const float* Urow = lXf + ((bb+1)*16 + i)*65 + (bb+1)*16;
      const float* Pcol = lP + bb*272 + j;
      #pragma unroll
      for (int k=0;k<16;k++) s += Urow[k] * Pcol[k*17];
      lXf[((bb+1)*16 + i)*65 + bb*16 + j] = -s;
    }
  }
  __syncthreads();
  // ---- phase 3: a=b+2 : T = -U_a (M_ab U_b + M_a,b+1 T_{b+1,b}) ----
  {
    const int i = t >> 4, j = t & 15;
    #pragma unroll
    for (int bb=0; bb<2; bb++) {
      float s = 0.f;
      const float* M0 = lLf + ((bb+2)*16 + i)*65 + bb*16;
      const float* U0 = lXf + (bb*16)*65 + bb*16 + j;
      const float* M1 = lLf + ((bb+2)*16 + i)*65 + (bb+1)*16;
      const float* T1 = lXf + ((bb+1)*16)*65 + bb*16 + j;
      #pragma unroll
      for (int k=0;k<16;k++) s += M0[k]*U0[k*65] + M1[k]*T1[k*65];
      lP[bb*272 + i*17 + j] = s;
    }
  }
  __syncthreads();
  {
    const int i = t >> 4, j = t & 15;
    #pragma unroll
    for (int bb=0; bb<2; bb++) {
      float s = 0.f;
      const float* Urow = lXf + ((bb+2)*16 + i)*65 + (bb+2)*16;
      const float* Pcol = lP + bb*272 + j;
      #pragma unroll
      for (int k=0;k<16;k++) s += Urow[k] * Pcol[k*17];
      lXf[((bb+2)*16 + i)*65 + bb*16 + j] = -s;
    }
  }
  __syncthreads();
  // ---- phase 4: (3,0) : T = -U_3 (M_30 U_0 + M_31 T_10 + M_32 T_20) ----
  {
    const int i = t >> 4, j = t & 15;
    float s = 0.f;
    const float* M0 = lLf + (48 + i)*65 + 0;
    const float* U0 = lXf + 0*65 + j;
    const float* M1 = lLf + (48 + i)*65 + 16;
    const float* T1 = lXf + 16*65 + j;
    const float* M2 = lLf + (48 + i)*65 + 32;
    const float* T2 = lXf + 32*65 + j;
    #pragma unroll
    for (int k=0;k<16;k++) s += M0[k]*U0[k*65] + M1[k]*T1[k*65] + M2[k]*T2[k*65];
    lP[i*17 + j] = s;
  }
  __syncthreads();
  {
    const int i = t >> 4, j = t & 15;
    float s = 0.f;
    const float* Urow = lXf + (48 + i)*65 + 48;
    const float* Pcol = lP + j;
    #pragma unroll
    for (int k=0;k<16;k++) s += Urow[k] * Pcol[k*17];
    lXf[(48 + i)*65 + j] = -s;
  }
  __syncthreads();

  // Tp store + bf16 copy of Tmat = T' diag(b)  (reuse lLf region)
  bf16_t* lXb = (bf16_t*)lLf;   // [64][72]
  {
    bf16_t* tpg = (bf16_t*)(cdp + CD_TP);
    #pragma unroll
    for (int ib=0; ib<16; ib++) {
      int idx = t + ib*256; int r = idx>>6, cc = idx&63;
      float xv = lXf[r*65+cc] * bvv[cc];
      tpg[r*64+cc] = (bf16_t)(xv * pvv[cc]);
      lXb[r*72+cc] = (bf16_t)xv;
    }
  }
  __syncthreads();

  // TV = Tmat @ V : C[t][dv] = sum_i Xb[t][i] * VT[dv][i]
  {
    f32x4 acc[8];
    #pragma unroll
    for (int tn=0;tn<8;tn++) acc[tn]=(f32x4){0,0,0,0};
    #pragma unroll
    for (int ks=0;ks<2;ks++) {
      bf16x8 aX = *(const bf16x8*)&lXb[(w*16+fr)*72 + fq*8 + ks*32];
      #pragma unroll
      for (int tn=0;tn<8;tn++) {
        bf16x8 bV = *(const bf16x8*)&lVT[(tn*16+fr)*72 + fq*8 + ks*32];
        acc[tn] = MFMA16(aX, bV, acc[tn]);
      }
    }
    bf16_t* tvg = (bf16_t*)(cdp + CD_TV);
    #pragma unroll
    for (int tn=0;tn<8;tn++)
      #pragma unroll
      for (int r=0;r<4;r++) {
        int tt = w*16 + fq*4 + r, dv = tn*16 + fr;
        tvg[tt*128 + dv] = (bf16_t)acc[tn][r];
      }
  }

  // KTs[dk][i] = K[i][dk] * exp(gc_C - gc_i)   (shared exp table)
  {
    bf16_t* ktg = (bf16_t*)(cdp + CD_KTS);
    int dk = t >> 1, c0 = (t & 1)*32;
    bf16_t tmp[32];
    #pragma unroll
    for (int i2=0;i2<32;i2++) {
      int i = c0 + i2;
      tmp[i2] = (bf16_t)((float)lK[i*136 + dk] * evv[i]);
    }
    #pragma unroll
    for (int s8=0;s8<4;s8++)
      *(bf16x8*)&ktg[dk*64 + c0 + s8*8] = *(bf16x8*)&tmp[s8*8];
  }
  if (t < 64) ((float*)(cdp + CD_PV))[t] = pvv[t];
  if (t == 0) *((float*)(cdp + CD_PC)) = expf(gcv[63]);
}

// ---------------------------------------------------------------------------
// Phase S (serial over 32 chunks; 256 blocks = 32 bh x 8 dv-splits of 16):
//   X=K S; Xq=Q S (store); D = TV - Tp X (store D^T); S = PC*S + KTs D
// Pipelined: chunk c+1's K/Q/Tp/KTs loaded to regs at top of chunk c,
// written to LDS in the tail phase (staging off the serial path).
// ---------------------------------------------------------------------------
__global__ __launch_bounds__(256) void chunkS_kernel(
    const bf16_t* __restrict__ q_t, const bf16_t* __restrict__ k_t,
    const char* __restrict__ cdata, bf16_t* __restrict__ gD,
    bf16_t* __restrict__ gXq)
{
  extern __shared__ char smem[];
  float*  lS  = (float*)(smem);              // [16][129] f32  S^T slice [dv][dk]
  bf16_t* lSb = (bf16_t*)(smem + 8320);      // [16][136] bf16
  bf16_t* lK  = (bf16_t*)(smem + 12672);     // [64][136]
  bf16_t* lQ  = (bf16_t*)(smem + 30080);     // [64][136]
  bf16_t* lTp = (bf16_t*)(smem + 47488);     // [64][72]
  bf16_t* lKT = (bf16_t*)(smem + 56704);     // [128][72]
  bf16_t* lXT = (bf16_t*)(smem + 75136);     // [16][88]  X^T [dv][t]
  bf16_t* lDT = (bf16_t*)(smem + 77952);     // [16][88]  D^T [dv][t]

  const int bid = blockIdx.x;
  const int lb  = (bid & 7)*32 + (bid >> 3);   // same-bh blocks on one XCD
  const int bh = lb >> 3, sp = lb & 7;
  const int dv0 = sp*16;
  const int t = threadIdx.x, lane = t & 63, w = t >> 6;
  const int fr = lane & 15, fq = lane >> 4;

  #pragma unroll
  for (int ib=0; ib<8; ib++) {
    int idx = t + ib*256; int r = idx>>7, cc = idx&127;
    lS[r*129+cc] = 0.f;
    lSb[r*136+cc] = (bf16_t)0.f;
  }

  const bf16_t* kg = k_t + (long)bh*SS*128;
  const bf16_t* qg = q_t + (long)bh*SS*128;

  bf16x8 kr0,kr1,kr2,kr3, qr0,qr1,qr2,qr3, kt0,kt1,kt2,kt3, tp0,tp1;

#define STAGE_LOAD(CSRC)                                                       \
  {                                                                            \
    const char* cdl = cdata + (long)(bh*NCH + (CSRC))*CD_STRIDE;               \
    const bf16_t* kl = kg + (long)(CSRC)*CH*128;                               \
    const bf16_t* ql = qg + (long)(CSRC)*CH*128;                               \
    const bf16_t* ktl = (const bf16_t*)(cdl + CD_KTS);                         \
    const bf16_t* tpl = (const bf16_t*)(cdl + CD_TP);                          \
    int e0 = t*8, e1 = (t+256)*8, e2 = (t+512)*8, e3 = (t+768)*8;              \
    kr0 = *(const bf16x8*)(kl + e0); kr1 = *(const bf16x8*)(kl + e1);          \
    kr2 = *(const bf16x8*)(kl + e2); kr3 = *(const bf16x8*)(kl + e3);          \
    qr0 = *(const bf16x8*)(ql + e0); qr1 = *(const bf16x8*)(ql + e1);          \
    qr2 = *(const bf16x8*)(ql + e2); qr3 = *(const bf16x8*)(ql + e3);          \
    kt0 = *(const bf16x8*)(ktl + e0); kt1 = *(const bf16x8*)(ktl + e1);        \
    kt2 = *(const bf16x8*)(ktl + e2); kt3 = *(const bf16x8*)(ktl + e3);        \
    tp0 = *(const bf16x8*)(tpl + e0); tp1 = *(const bf16x8*)(tpl + e1);        \
  }

#define STAGE_WRITE()                                                          \
  {                                                                            \
    int e0 = t*8, e1 = (t+256)*8, e2 = (t+512)*8, e3 = (t+768)*8;              \
    *(bf16x8*)&lK[(e0>>7)*136 + (e0&127)] = kr0;                               \
    *(bf16x8*)&lK[(e1>>7)*136 + (e1&127)] = kr1;                               \
    *(bf16x8*)&lK[(e2>>7)*136 + (e2&127)] = kr2;                               \
    *(bf16x8*)&lK[(e3>>7)*136 + (e3&127)] = kr3;                               \
    *(bf16x8*)&lQ[(e0>>7)*136 + (e0&127)] = qr0;                               \
    *(bf16x8*)&lQ[(e1>>7)*136 + (e1&127)] = qr1;                               \
    *(bf16x8*)&lQ[(e2>>7)*136 + (e2&127)] = qr2;                               \
    *(bf16x8*)&lQ[(e3>>7)*136 + (e3&127)] = qr3;                               \
    *(bf16x8*)&lKT[(e0>>6)*72 + (e0&63)] = kt0;                                \
    *(bf16x8*)&lKT[(e1>>6)*72 + (e1&63)] = kt1;                                \
    *(bf16x8*)&lKT[(e2>>6)*72 + (e2&63)] = kt2;                                \
    *(bf16x8*)&lKT[(e3>>6)*72 + (e3&63)] = kt3;                                \
    *(bf16x8*)&lTp[(e0>>6)*72 + (e0&63)] = tp0;                                \
    *(bf16x8*)&lTp[(e1>>6)*72 + (e1&63)] = tp1;                                \
  }

  STAGE_LOAD(0);
  STAGE_WRITE();
  __syncthreads();

  for (int c=0; c<NCH; c++) {
    const int cd = bh*NCH + c;
    const char* cdp = cdata + (long)cd*CD_STRIDE;

    // TV quad + PC for current chunk (issued FIRST so their wait doesn't
    // drain the prefetch queue)
    float tvq0, tvq1, tvq2, tvq3, pc;
    {
      const bf16_t* tvp = (const bf16_t*)(cdp + CD_TV);
      tvq0 = (float)tvp[(w*16+fq*4+0)*128 + dv0 + fr];
      tvq1 = (float)tvp[(w*16+fq*4+1)*128 + dv0 + fr];
      tvq2 = (float)tvp[(w*16+fq*4+2)*128 + dv0 + fr];
      tvq3 = (float)tvp[(w*16+fq*4+3)*128 + dv0 + fr];
      pc = *(const float*)(cdp + CD_PC);
    }
    // issue prefetch of chunk c+1 (clamped) into regs
    const int cn = (c+1 < NCH) ? c+1 : c;
    STAGE_LOAD(cn);

    // X = K S^T-slice, Xq = Q S^T-slice  (M=64, N=16, K=128)
    f32x4 aX = {0,0,0,0}, aXq = {0,0,0,0};
    #pragma unroll
    for (int ks=0; ks<4; ks++) {
      bf16x8 bS = *(const bf16x8*)&lSb[fr*136 + fq*8 + ks*32];
      bf16x8 aK = *(const bf16x8*)&lK[(w*16+fr)*136 + fq*8 + ks*32];
      bf16x8 aQ = *(const bf16x8*)&lQ[(w*16+fr)*136 + fq*8 + ks*32];
      aX  = MFMA16(aK, bS, aX);
      aXq = MFMA16(aQ, bS, aXq);
    }
    #pragma unroll
    for (int r=0;r<4;r++)
      lXT[fr*88 + (w*16+fq*4+r)] = (bf16_t)aX[r];
    __syncthreads();   // A

    // D = TV - Tp X  (M=64, N=16, K=64); also scale lS by PC
    {
      f32x4 aD = {0,0,0,0};
      #pragma unroll
      for (int ks=0; ks<2; ks++) {
        bf16x8 aT = *(const bf16x8*)&lTp[(w*16+fr)*72 + fq*8 + ks*32];
        bf16x8 bX = *(const bf16x8*)&lXT[fr*88 + fq*8 + ks*32];
        aD = MFMA16(aT, bX, aD);
      }
      lDT[fr*88 + (w*16+fq*4+0)] = (bf16_t)(tvq0 - aD[0]);
      lDT[fr*88 + (w*16+fq*4+1)] = (bf16_t)(tvq1 - aD[1]);
      lDT[fr*88 + (w*16+fq*4+2)] = (bf16_t)(tvq2 - aD[2]);
      lDT[fr*88 + (w*16+fq*4+3)] = (bf16_t)(tvq3 - aD[3]);
    }
    #pragma unroll
    for (int ib=0; ib<8; ib++) {
      int idx = t + ib*256; int r = idx>>7, cc = idx&127;
      lS[r*129+cc] *= pc;
    }
    __syncthreads();   // B

    // S^T += D^T KTs^T : C[dv][dk] = sum_i D^T[dv][i]*KTs[dk][i]
    {
      f32x4 aS0 = {0,0,0,0}, aS1 = {0,0,0,0};
      #pragma unroll
      for (int ks=0; ks<2; ks++) {
        bf16x8 aDd = *(const bf16x8*)&lDT[fr*88 + fq*8 + ks*32];
        bf16x8 bK0 = *(const bf16x8*)&lKT[(w*32+fr)*72 + fq*8 + ks*32];
        bf16x8 bK1 = *(const bf16x8*)&lKT[(w*32+16+fr)*72 + fq*8 + ks*32];
        aS0 = MFMA16(aDd, bK0, aS0);
        aS1 = MFMA16(aDd, bK1, aS1);
      }
      #pragma unroll
      for (int r=0;r<4;r++) {
        lS[(fq*4+r)*129 + w*32 + fr]      += aS0[r];
        lS[(fq*4+r)*129 + w*32 + 16 + fr] += aS1[r];
      }
    }
    // global stores: Xq and D^T
    #pragma unroll
    for (int r=0;r<4;r++)
      gXq[((long)cd*CH + w*16+fq*4+r)*128 + dv0 + fr] = (bf16_t)aXq[r];
    {
      int dvl = t >> 4, off = (t & 15)*4;
      *(bf16x4*)(gD + ((long)cd*128 + dv0 + dvl)*64 + off) =
          *(const bf16x4*)&lDT[dvl*88 + off];
    }
    __syncthreads();   // C

    // write staged c+1 into LDS; cast lSb = bf16(lS)
    STAGE_WRITE();
    #pragma unroll
    for (int ib=0; ib<8; ib++) {
      int idx = t + ib*256; int r = idx>>7, cc = idx&127;
      lSb[r*136+cc] = (bf16_t)lS[r*129+cc];
    }
    __syncthreads();   // D
  }
#undef STAGE_LOAD
#undef STAGE_WRITE
}

// ---------------------------------------------------------------------------
// Phase O (parallel, per chunk): O = diag(p) Xq + Aq D  -> obuf
// ---------------------------------------------------------------------------
__global__ __launch_bounds__(256) void chunkO_kernel(
    const char* __restrict__ cdata, const bf16_t* __restrict__ gD,
    const bf16_t* __restrict__ gXq, bf16_t* __restrict__ obuf)
{
  const int cd = blockIdx.x;
  const int bh = cd >> 5, c = cd & 31;
  const int b = bh >> 4, h = bh & 15;
  const int t = threadIdx.x, lane = t & 63, w = t >> 6;
  const int fr = lane & 15, fq = lane >> 4;

  const char* cdp = cdata + (long)cd*CD_STRIDE;
  const bf16_t* aqp = (const bf16_t*)(cdp + CD_AQ);   // [64][64]
  const bf16_t* dp  = gD + (long)cd*128*64;           // [128 dv][64 t]
  const float*  pvp = (const float*)(cdp + CD_PV);

  f32x4 acc[8];
  #pragma unroll
  for (int tn=0;tn<8;tn++) acc[tn]=(f32x4){0,0,0,0};
  #pragma unroll
  for (int ks=0;ks<2;ks++) {
    bf16x8 aA = *(const bf16x8*)(aqp + (w*16+fr)*64 + fq*8 + ks*32);
    #pragma unroll
    for (int tn=0;tn<8;tn++) {
      bf16x8 bD = *(const bf16x8*)(dp + (tn*16+fr)*64 + fq*8 + ks*32);
      acc[tn] = MFMA16(aA, bD, acc[tn]);
    }
  }
  #pragma unroll
  for (int tn=0;tn<8;tn++)
    #pragma unroll
    for (int r=0;r<4;r++) {
      int tt = w*16+fq*4+r, dv = tn*16+fr;
      float ov = pvp[tt]*(float)gXq[((long)cd*CH + tt)*128 + dv] + acc[tn][r];
      obuf[((long)(b*SS + c*CH + tt)*HH + h)*128 + dv] = (bf16_t)ov;
    }
}

// ---------------------------------------------------------------------------
// RMSNorm over DV + (1+nw) + silu(z) gate; z from zbuf (stride ZN)
// ---------------------------------------------------------------------------
__global__ __launch_bounds__(128) void norm_gate_kernel(
    const bf16_t* __restrict__ o, const bf16_t* __restrict__ zfull,
    const float* __restrict__ nw, bf16_t* __restrict__ og)
{
  const long row = blockIdx.x;      // (b*S+s)*H + h
  const long tok = row >> 4;
  const int h = row & 15;
  const int d = threadIdx.x;
  float x = (float)o[row*128 + d];
  float ss = x*x;
  #pragma unroll
  for (int off=32; off>=1; off>>=1) ss += __shfl_xor(ss, off);
  __shared__ float red[2];
  if ((d & 63) == 0) red[d>>6] = ss;
  __syncthreads();
  float mean = (red[0] + red[1]) * (1.f/128.f);
  float zn = (float)zfull[tok*ZN + h*128 + d];
  float val = x * rsqrtf(mean + 1e-6f) * (1.f + nw[d]) * (zn * (1.f/(1.f+expf(-zn))));
  og[row*128 + d] = (bf16_t)val;
}

// ---------------------------------------------------------------------------
extern "C" void kernel_launch(void* const* d_in, const int* in_sizes, int n_in,
                              void* d_out, int out_size, void* d_ws, size_t ws_size,
                              hipStream_t stream)
{
  const float* hs    = (const float*)d_in[0];
  const float* amask = (const float*)d_in[1];
  const float* Wqkv  = (const float*)d_in[2];
  const float* convw = (const float*)d_in[3];
  const float* convb = (const float*)d_in[4];
  const float* Wz    = (const float*)d_in[5];
  const float* Wb    = (const float*)d_in[6];
  const float* Wa    = (const float*)d_in[7];
  const float* dtb   = (const float*)d_in[8];
  const float* Alog  = (const float*)d_in[9];
  const float* nw    = (const float*)d_in[10];
  const float* Wout  = (const float*)d_in[11];

  const size_t MB = 1024*1024;
  char* p = (char*)d_ws;
  auto alloc = [&](size_t bytes) { char* r = p; p += (bytes + 255) & ~(size_t)255; return r; };
  bf16_t* x_bf   = (bf16_t*)alloc(16*MB);   // x_bf; later gD [1024][128][64]
  char*   bigreg = alloc(72*MB);            // wqkv@0, mixed@24MB; later cdata@0, obuf@52MB
  bf16_t* wz_bf  = (bf16_t*)alloc(10*MB);   // Wz rows + W_b/W_a rows @8MB; later Wout@0
  bf16_t* zbuf   = (bf16_t*)alloc(19*MB);   // [4096][2304]
  bf16_t* q_t    = (bf16_t*)alloc(16*MB);   // q; later og
  bf16_t* k_t    = (bf16_t*)alloc(16*MB);
  bf16_t* v_t    = (bf16_t*)alloc(16*MB);   // v; later gXq [1024][64][128]
  float2* gb_t   = (float2*)alloc((size_t)BB*HH*SS*8);
  size_t need = (size_t)(p - (char*)d_ws);
  if (ws_size < need) return;   // clean fail (absmax = poison)

  bf16_t* wqkv_bf = (bf16_t*)bigreg;
  bf16_t* mixed   = (bf16_t*)(bigreg + 24*MB);
  char*   cdata   = bigreg;                       // after GEMM1+conv consumed
  bf16_t* obuf    = (bf16_t*)(bigreg + 52*MB);    // cdata ends at ~48.5MB
  bf16_t* wout_bf = wz_bf;                        // cast after z-GEMM (rows 0..2047 only)
  bf16_t* gD      = x_bf;                         // after z-GEMM consumed x_bf
  bf16_t* gXq     = v_t;                          // after chunkA consumed v_t
  bf16_t* og      = q_t;                          // after chunkS consumed q_t

  cast_x_kernel<<<2048, 256, 0, stream>>>(hs, amask, x_bf, (long)MM*DD);
  cast_w_kernel<<<2048, 256, 0, stream>>>(Wqkv, wqkv_bf, (long)CONVC*DD);
  cast_w_kernel<<<1024, 256, 0, stream>>>(Wz,   wz_bf,   (long)DD*DD);
  cast_ba_kernel<<<64, 256, 0, stream>>>(Wb, Wa, wz_bf + (size_t)DD*DD);

  gemm256<true><<<768, 512, 98304, stream>>>(x_bf, wqkv_bf, mixed, MM, CONVC, DD, 48);

  conv_norm_kernel<<<BB*HH*SS, 128, 0, stream>>>(mixed, convw, convb, q_t, k_t, v_t);

  gemm256<true><<<288, 512, 98304, stream>>>(x_bf, wz_bf, zbuf, MM, ZN, DD, 18);
  cast_w_kernel<<<1024, 256, 0, stream>>>(Wout, wout_bf, (long)DD*DD);
  betag2_kernel<<<256, 256, 0, stream>>>(zbuf, dtb, Alog, gb_t);

  chunkA_kernel<<<BB*HH*NCH, 256, 73408, stream>>>(q_t, k_t, v_t, gb_t, cdata);
  chunkS_kernel<<<BB*HH*8, 256, 80768, stream>>>(q_t, k_t, cdata, gD, gXq);
  chunkO_kernel<<<BB*HH*NCH, 256, 0, stream>>>(cdata, gD, gXq, obuf);

  norm_gate_kernel<<<MM*HH, 128, 0, stream>>>(obuf, zbuf, nw, og);

  gemm256<false><<<256, 512, 98304, stream>>>(og, wout_bf, d_out, MM, DD, DD, 16);
}